// Round 5
// baseline (4026.712 us; speedup 1.0000x reference)
//
#include <hip/hip_runtime.h>

#define H 128
#define Nn 100000
#define Ee 250000
#define N5c 20000
#define N6c 30000
#define Gg 512
#define Ll 3
#define AF 9
#define AV 64
#define BF 3
#define BV 8
#define BN_EPS 1e-5f

typedef __bf16 v8bf __attribute__((ext_vector_type(8)));
typedef float v4f __attribute__((ext_vector_type(4)));

struct bfpair { __bf16 h, l; };
__device__ inline bfpair split2(float v) {
    bfpair r;
    r.h = (__bf16)v;
    r.l = (__bf16)(v - (float)r.h);
    return r;
}

// ---------------- init / embedding kernels ----------------

__global__ void k_atom_enc(const int* __restrict__ xa, const float* __restrict__ emb,
                           float* __restrict__ x) {
    int idx = blockIdx.x * blockDim.x + threadIdx.x;
    if (idx >= Nn * H) return;
    int n = idx >> 7, h = idx & 127;
    float s = 0.f;
#pragma unroll
    for (int f = 0; f < AF; ++f) {
        int a = xa[n * AF + f];
        s += emb[(f * AV + a) * H + h];
    }
    x[idx] = s;
}

__global__ void k_cyc_init(const int* __restrict__ xc, const float* __restrict__ emb,
                           float* __restrict__ xo, int M) {
    int idx = blockIdx.x * blockDim.x + threadIdx.x;
    if (idx >= M * H) return;
    int m = idx >> 7, h = idx & 127;
    xo[idx] = emb[xc[m] * H + h];
}

// weight pre-split: (L,K,N) fp32 row-major -> per-layer transposed [n][k] bf16 hi/lo
__global__ void k_split(const float* __restrict__ src, __bf16* __restrict__ dh,
                        __bf16* __restrict__ dl, int L, int K, int N) {
    int idx = blockIdx.x * blockDim.x + threadIdx.x;
    int tot = L * K * N;
    if (idx >= tot) return;
    int l = idx / (K * N);
    int r = idx - l * (K * N);
    int k = r / N;
    int n = r - k * N;
    bfpair p = split2(src[idx]);
    size_t d = (size_t)l * K * N + (size_t)n * K + k;
    dh[d] = p.h;
    dl[d] = p.l;
}

// ---------------- CSR build (per launch; edge structure is static) ----------------

__global__ void k_deg(const int* __restrict__ ei, int* __restrict__ deg) {
    int e = blockIdx.x * blockDim.x + threadIdx.x;
    if (e >= Ee) return;
    atomicAdd(&deg[ei[Ee + e]], 1);
}

__global__ void k_scan(const int* __restrict__ deg, int* __restrict__ rowptr, int n) {
    __shared__ int s[1024];
    int tid = threadIdx.x;
    int carry = 0;
    for (int base = 0; base < n; base += 1024) {
        int i = base + tid;
        int v = (i < n) ? deg[i] : 0;
        s[tid] = v;
        __syncthreads();
        for (int off = 1; off < 1024; off <<= 1) {
            int u = (tid >= off) ? s[tid - off] : 0;
            __syncthreads();
            s[tid] += u;
            __syncthreads();
        }
        if (i < n) rowptr[i] = carry + s[tid] - v;  // exclusive
        carry += s[1023];
        __syncthreads();
    }
    if (tid == 0) rowptr[n] = carry;
}

__global__ void k_fill(const int* __restrict__ ei, const int* __restrict__ eattr,
                       int* __restrict__ woff, unsigned int* __restrict__ elist) {
    int e = blockIdx.x * blockDim.x + threadIdx.x;
    if (e >= Ee) return;
    int src = ei[e], dst = ei[Ee + e];
    int code = eattr[e * BF + 0] * 64 + eattr[e * BF + 1] * 8 + eattr[e * BF + 2];
    int p = atomicAdd(&woff[dst], 1);
    elist[p] = ((unsigned int)code << 17) | (unsigned int)src;
}

__global__ void k_cnt(const int* __restrict__ row, float* __restrict__ cnt, int M) {
    int m = blockIdx.x * blockDim.x + threadIdx.x;
    if (m >= M) return;
    atomicAdd(&cnt[row[m]], 1.f);
}

__global__ void k_inv(const float* __restrict__ cnt, float* __restrict__ rscale) {
    int r = blockIdx.x * blockDim.x + threadIdx.x;
    if (r >= Nn) return;
    rscale[r] = 1.f / fmaxf(cnt[r], 1.f);
}

// per-layer bond-embedding bank: 512 codes x 128
__global__ void k_ebank(const float* __restrict__ bemb, float* __restrict__ ebank) {
    int idx = blockIdx.x * blockDim.x + threadIdx.x;
    if (idx >= 512 * H) return;
    int code = idx >> 7, h = idx & 127;
    int f0 = code >> 6, f1 = (code >> 3) & 7, f2 = code & 7;
    ebank[idx] = bemb[(0 * BV + f0) * H + h] + bemb[(1 * BV + f1) * H + h]
               + bemb[(2 * BV + f2) * H + h];
}

// GINE aggregation, gather form: agg[a] = (1+eps)x[a] + sum_{e in in(a)} relu(x[src]+ea)
__global__ __launch_bounds__(256) void k_agg_csr(
    const float* __restrict__ x, const int* __restrict__ rowptr,
    const unsigned int* __restrict__ elist, const float* __restrict__ ebank,
    const float* __restrict__ eps, int layer, float* __restrict__ agg)
{
    int a = blockIdx.x * 2 + (threadIdx.x >> 7);
    int h = threadIdx.x & 127;
    float acc = (1.f + eps[layer]) * x[(size_t)a * H + h];
    int j0 = rowptr[a], j1 = rowptr[a + 1];
    for (int j = j0; j < j1; ++j) {
        unsigned int u = elist[j];
        int src = u & 0x1FFFF;
        int code = u >> 17;
        acc += fmaxf(x[(size_t)src * H + h] + ebank[code * H + h], 0.f);
    }
    agg[(size_t)a * H + h] = acc;
}

// ---------------- misc elementwise ----------------

__global__ void k_bn_stats(const float* __restrict__ h, float* __restrict__ stats,
                           int M, int C, int rpb) {
    int c = threadIdx.x;
    int r0 = blockIdx.x * rpb;
    int r1 = min(r0 + rpb, M);
    float s = 0.f, sq = 0.f;
    for (int r = r0; r < r1; ++r) {
        float v = h[(size_t)r * C + c];
        s += v;
        sq += v * v;
    }
    atomicAdd(&stats[c], s);
    atomicAdd(&stats[C + c], sq);
}

__global__ void k_bn_apply(float* __restrict__ h, const float* __restrict__ stats,
                           const float* __restrict__ g, const float* __restrict__ b,
                           int M, int C) {
    int idx = blockIdx.x * blockDim.x + threadIdx.x;
    if (idx >= M * C) return;
    int c = idx & (C - 1);
    float mean = stats[c] / (float)M;
    float var = stats[C + c] / (float)M - mean * mean;
    float v = (h[idx] - mean) * rsqrtf(var + BN_EPS) * g[c] + b[c];
    h[idx] = fmaxf(v, 0.f);
}

// scatter-mean with pre-baked 1/cnt scale
__global__ void k_scatter_add(const float* __restrict__ xc, const int* __restrict__ row,
                              const float* __restrict__ rscale, float* __restrict__ sum,
                              int M) {
    int idx = blockIdx.x * blockDim.x + threadIdx.x;
    if (idx >= M * H) return;
    int m = idx >> 7, h = idx & 127;
    int r = row[m];
    atomicAdd(&sum[r * H + h], xc[idx] * rscale[r]);
}

// ---------------- generic MFMA GEMM (bf16x3 split, pre-split B) ----------------
// out[m,n] = maybe_relu( sum_k A'[m,k]*B[k,n] + bias[n] ) (+ res[row0+m,n]); Ncol==128.
// B given as transposed bf16 planes Bth/Btl: [n][k], row stride K.

__global__ __launch_bounds__(256) void k_mgemm(
    const float* __restrict__ A, const __bf16* __restrict__ Bth,
    const __bf16* __restrict__ Btl, const float* __restrict__ bias,
    const float* __restrict__ res, float* __restrict__ out,
    const int* __restrict__ rowidx,
    int M, int K, int pathk, int relu_flag, int row0)
{
    __shared__ __bf16 Ah[128 * 40], Al[128 * 40];
    __shared__ __bf16 Bh[128 * 40], Bl[128 * 40];

    int t = threadIdx.x;
    int m0 = blockIdx.x * 128;
    int lane = t & 63;
    int q = lane >> 4;
    int lr = lane & 15;
    int wrow = (t >> 6) * 32;

    v4f acc[2][8] = {};

    int ar = t >> 1;          // A row 0..127
    int akq = (t & 1) * 16;   // A k sub-block 0/16
    int bn = t & 127;         // B col (n) 0..127
    int bkb = (t >> 7) * 16;  // B k sub-block 0/16

    for (int k0 = 0; k0 < K; k0 += 32) {
        // stage A (fp32 -> hi/lo)
        {
            float va[16];
            int gm = m0 + ar;
            if (gm < M) {
                int kk = k0 + akq;
                const float* ap;
                if (pathk) {
                    int g = row0 + gm;
                    int cyc = g / pathk;
                    int p = g - cyc * pathk;
                    int sel = kk >> 7;
                    int pp = p + sel - 1;
                    if (pp < 0) pp += pathk;
                    if (pp >= pathk) pp -= pathk;
                    ap = A + (size_t)(cyc * pathk + pp) * H + (kk & 127);
                } else if (rowidx) {
                    ap = A + (size_t)rowidx[gm] * H + kk;
                } else {
                    ap = A + (size_t)gm * K + kk;
                }
#pragma unroll
                for (int i = 0; i < 4; ++i) {
                    float4 f = *(const float4*)(ap + i * 4);
                    va[i * 4 + 0] = f.x; va[i * 4 + 1] = f.y;
                    va[i * 4 + 2] = f.z; va[i * 4 + 3] = f.w;
                }
            } else {
#pragma unroll
                for (int i = 0; i < 16; ++i) va[i] = 0.f;
            }
            v8bf h0, h1, l0, l1;
#pragma unroll
            for (int i = 0; i < 8; ++i) {
                bfpair p0 = split2(va[i]);
                bfpair p1 = split2(va[8 + i]);
                h0[i] = p0.h; l0[i] = p0.l;
                h1[i] = p1.h; l1[i] = p1.l;
            }
            *(v8bf*)&Ah[ar * 40 + akq] = h0;
            *(v8bf*)&Ah[ar * 40 + akq + 8] = h1;
            *(v8bf*)&Al[ar * 40 + akq] = l0;
            *(v8bf*)&Al[ar * 40 + akq + 8] = l1;
        }
        // stage B (pre-split bf16, direct copy)
        {
            const __bf16* sh = Bth + (size_t)bn * K + k0 + bkb;
            const __bf16* sl = Btl + (size_t)bn * K + k0 + bkb;
            *(v8bf*)&Bh[bn * 40 + bkb] = *(const v8bf*)sh;
            *(v8bf*)&Bh[bn * 40 + bkb + 8] = *(const v8bf*)(sh + 8);
            *(v8bf*)&Bl[bn * 40 + bkb] = *(const v8bf*)sl;
            *(v8bf*)&Bl[bn * 40 + bkb + 8] = *(const v8bf*)(sl + 8);
        }
        __syncthreads();

        v8bf ah[2], al2[2], bh[8], bl2[8];
#pragma unroll
        for (int mt = 0; mt < 2; ++mt) {
            ah[mt] = *(v8bf*)&Ah[(wrow + mt * 16 + lr) * 40 + q * 8];
            al2[mt] = *(v8bf*)&Al[(wrow + mt * 16 + lr) * 40 + q * 8];
        }
#pragma unroll
        for (int nt = 0; nt < 8; ++nt) {
            bh[nt] = *(v8bf*)&Bh[(nt * 16 + lr) * 40 + q * 8];
            bl2[nt] = *(v8bf*)&Bl[(nt * 16 + lr) * 40 + q * 8];
        }
#pragma unroll
        for (int mt = 0; mt < 2; ++mt)
#pragma unroll
            for (int nt = 0; nt < 8; ++nt) {
                v4f a = acc[mt][nt];
                a = __builtin_amdgcn_mfma_f32_16x16x32_bf16(al2[mt], bh[nt], a, 0, 0, 0);
                a = __builtin_amdgcn_mfma_f32_16x16x32_bf16(ah[mt], bl2[nt], a, 0, 0, 0);
                a = __builtin_amdgcn_mfma_f32_16x16x32_bf16(ah[mt], bh[nt], a, 0, 0, 0);
                acc[mt][nt] = a;
            }
        __syncthreads();
    }

    float bcol[8];
#pragma unroll
    for (int nt = 0; nt < 8; ++nt) bcol[nt] = bias[nt * 16 + lr];
#pragma unroll
    for (int mt = 0; mt < 2; ++mt)
#pragma unroll
        for (int reg = 0; reg < 4; ++reg) {
            int rm = m0 + wrow + mt * 16 + q * 4 + reg;
            if (rm < M) {
#pragma unroll
                for (int nt = 0; nt < 8; ++nt) {
                    int cn = nt * 16 + lr;
                    float v = acc[mt][nt][reg] + bcol[nt];
                    if (relu_flag) v = fmaxf(v, 0.f);
                    if (res) v += res[(size_t)(row0 + rm) * H + cn];
                    out[(size_t)rm * H + cn] = v;
                }
            }
        }
}

// ---------------- Gram matrix S = hin^T hin (128x128, K=Nn) ----------------
#define GR 512

__global__ __launch_bounds__(256) void k_gram(const float* __restrict__ A,
                                              float* __restrict__ S, int M)
{
    __shared__ __bf16 Hh[128 * 40], Hl[128 * 40];
    int t = threadIdx.x;
    int lane = t & 63, q = lane >> 4, lr = lane & 15, w = t >> 6;
    int rbase = blockIdx.x * GR;
    v4f acc[2][8] = {};

    for (int k0 = 0; k0 < GR; k0 += 32) {
        int rr = t >> 3;             // 0..31 (row in chunk)
        int cg = (t & 7) * 16;       // col group base
        int r = rbase + k0 + rr;
        float va[16];
        if (r < M) {
#pragma unroll
            for (int i = 0; i < 4; ++i) {
                float4 f = *(const float4*)(A + (size_t)r * H + cg + i * 4);
                va[i * 4 + 0] = f.x; va[i * 4 + 1] = f.y;
                va[i * 4 + 2] = f.z; va[i * 4 + 3] = f.w;
            }
        } else {
#pragma unroll
            for (int i = 0; i < 16; ++i) va[i] = 0.f;
        }
#pragma unroll
        for (int i = 0; i < 16; ++i) {
            bfpair p = split2(va[i]);
            Hh[(cg + i) * 40 + rr] = p.h;
            Hl[(cg + i) * 40 + rr] = p.l;
        }
        __syncthreads();

        v8bf Fh[8], Fl[8];
#pragma unroll
        for (int g = 0; g < 8; ++g) {
            Fh[g] = *(v8bf*)&Hh[(g * 16 + lr) * 40 + q * 8];
            Fl[g] = *(v8bf*)&Hl[(g * 16 + lr) * 40 + q * 8];
        }
#pragma unroll
        for (int mt = 0; mt < 2; ++mt) {
            int mtile = w * 2 + mt;
#pragma unroll
            for (int nt = 0; nt < 8; ++nt) {
                v4f a = acc[mt][nt];
                a = __builtin_amdgcn_mfma_f32_16x16x32_bf16(Fh[mtile], Fl[nt], a, 0, 0, 0);
                a = __builtin_amdgcn_mfma_f32_16x16x32_bf16(Fl[mtile], Fh[nt], a, 0, 0, 0);
                a = __builtin_amdgcn_mfma_f32_16x16x32_bf16(Fh[mtile], Fh[nt], a, 0, 0, 0);
                acc[mt][nt] = a;
            }
        }
        __syncthreads();
    }
#pragma unroll
    for (int mt = 0; mt < 2; ++mt)
#pragma unroll
        for (int nt = 0; nt < 8; ++nt)
#pragma unroll
            for (int reg = 0; reg < 4; ++reg) {
                int row = (w * 2 + mt) * 16 + q * 4 + reg;
                int col = nt * 16 + lr;
                atomicAdd(&S[row * 128 + col], acc[mt][nt][reg]);
            }
}

__global__ void k_colsum(const float* __restrict__ agg, float* __restrict__ colsum, int M) {
    __shared__ float red[2][128];
    int t = threadIdx.x;
    int c = t & 127, g = t >> 7;
    int r0 = blockIdx.x * 512;
    int r1 = min(r0 + 512, M);
    float s = 0.f;
    for (int r = r0 + g; r < r1; r += 2) s += agg[(size_t)r * H + c];
    red[g][c] = s;
    __syncthreads();
    if (g == 0) atomicAdd(&colsum[c], red[0][c] + red[1][c]);
}

// BN1 stats from Gram: stats[c] = sum h1_c, stats[256+c] = sum h1_c^2
__global__ __launch_bounds__(512) void k_bnstats1(
    const float* __restrict__ S, const float* __restrict__ colsum,
    const float* __restrict__ gw1, const float* __restrict__ gb1,
    float* __restrict__ stats)
{
    __shared__ float Sl[128 * 128];
    __shared__ float Wl[128 * 64];
    __shared__ float red[8][64];
    int t = threadIdx.x;
    int c0 = blockIdx.x * 64;
    for (int i = t; i < 4096; i += 512) ((float4*)Sl)[i] = ((const float4*)S)[i];
    {
        int cl = t & 63;
        for (int k = t >> 6; k < 128; k += 8)
            Wl[k * 64 + cl] = gw1[(size_t)k * 256 + c0 + cl];
    }
    __syncthreads();
    int cl = t & 63;
    int jg = t >> 6;  // 0..7
    float acc = 0.f;
    for (int j = jg * 16; j < jg * 16 + 16; ++j) {
        float wj = Wl[j * 64 + cl];
        float p = 0.f;
        for (int k = 0; k < 128; ++k) p += Sl[j * 128 + k] * Wl[k * 64 + cl];
        acc += wj * p;
    }
    red[jg][cl] = acc;
    __syncthreads();
    if (jg == 0) {
        float sumsq_u = 0.f;
#pragma unroll
        for (int g = 0; g < 8; ++g) sumsq_u += red[g][cl];
        float su = 0.f;
        for (int j = 0; j < 128; ++j) su += colsum[j] * Wl[j * 64 + cl];
        int c = c0 + cl;
        float b = gb1[c];
        stats[c] = su + (float)Nn * b;
        stats[256 + c] = sumsq_u + 2.f * b * su + (float)Nn * b * b;
    }
}

// ---------------- fused GINE MLP via MFMA (pre-split weights) ----------------

__global__ __launch_bounds__(256) void k_mlp_mfma(
    const float* __restrict__ hin,
    const __bf16* __restrict__ g1h, const __bf16* __restrict__ g1l,
    const float* __restrict__ gb1, const float* __restrict__ gbn_g,
    const float* __restrict__ gbn_b,
    const __bf16* __restrict__ g2h, const __bf16* __restrict__ g2l,
    const float* __restrict__ gb2, const float* __restrict__ stats,
    float* __restrict__ xout)
{
    __shared__ __bf16 Ah[32 * 136], Al[32 * 136];
    __shared__ __bf16 Bh[128 * 40], Bl[128 * 40];
    __shared__ __bf16 Th[32 * 264], Tl[32 * 264];
    __shared__ float sc[256], sh[256];

    int t = threadIdx.x;
    int r0 = blockIdx.x * 32;
    int lane = t & 63;
    int q = lane >> 4;
    int lr = lane & 15;
    int w = t >> 6;

    {
        float mean = stats[t] * (1.f / (float)Nn);
        float var = stats[256 + t] * (1.f / (float)Nn) - mean * mean;
        float s = gbn_g[t] * rsqrtf(var + BN_EPS);
        sc[t] = s;
        sh[t] = (gb1[t] - mean) * s + gbn_b[t];
    }
    {
        int r = t >> 3;
        int kq = (t & 7) * 16;
        const float* ap = hin + (size_t)(r0 + r) * H + kq;
        v8bf h0, h1, l0, l1;
#pragma unroll
        for (int i = 0; i < 8; ++i) {
            bfpair p0 = split2(ap[i]);
            bfpair p1 = split2(ap[8 + i]);
            h0[i] = p0.h; l0[i] = p0.l;
            h1[i] = p1.h; l1[i] = p1.l;
        }
        *(v8bf*)&Ah[r * 136 + kq] = h0;
        *(v8bf*)&Ah[r * 136 + kq + 8] = h1;
        *(v8bf*)&Al[r * 136 + kq] = l0;
        *(v8bf*)&Al[r * 136 + kq + 8] = l1;
    }

    int bn = t & 127;
    int bkb = (t >> 7) * 16;

    // stage 1: T = relu(BN1(hin@gw1)), two 128-col panels; g1 planes are [n=256][k=128]
    for (int p = 0; p < 2; ++p) {
        v4f acc[2][2] = {};
        for (int k0 = 0; k0 < 128; k0 += 32) {
            {
                const __bf16* shp = g1h + (size_t)(p * 128 + bn) * 128 + k0 + bkb;
                const __bf16* slp = g1l + (size_t)(p * 128 + bn) * 128 + k0 + bkb;
                *(v8bf*)&Bh[bn * 40 + bkb] = *(const v8bf*)shp;
                *(v8bf*)&Bh[bn * 40 + bkb + 8] = *(const v8bf*)(shp + 8);
                *(v8bf*)&Bl[bn * 40 + bkb] = *(const v8bf*)slp;
                *(v8bf*)&Bl[bn * 40 + bkb + 8] = *(const v8bf*)(slp + 8);
            }
            __syncthreads();
            v8bf ah[2], al2[2], bh[2], bl2[2];
#pragma unroll
            for (int mt = 0; mt < 2; ++mt) {
                ah[mt] = *(v8bf*)&Ah[(mt * 16 + lr) * 136 + k0 + q * 8];
                al2[mt] = *(v8bf*)&Al[(mt * 16 + lr) * 136 + k0 + q * 8];
            }
#pragma unroll
            for (int nt = 0; nt < 2; ++nt) {
                bh[nt] = *(v8bf*)&Bh[(w * 32 + nt * 16 + lr) * 40 + q * 8];
                bl2[nt] = *(v8bf*)&Bl[(w * 32 + nt * 16 + lr) * 40 + q * 8];
            }
#pragma unroll
            for (int mt = 0; mt < 2; ++mt)
#pragma unroll
                for (int nt = 0; nt < 2; ++nt) {
                    v4f a = acc[mt][nt];
                    a = __builtin_amdgcn_mfma_f32_16x16x32_bf16(al2[mt], bh[nt], a, 0, 0, 0);
                    a = __builtin_amdgcn_mfma_f32_16x16x32_bf16(ah[mt], bl2[nt], a, 0, 0, 0);
                    a = __builtin_amdgcn_mfma_f32_16x16x32_bf16(ah[mt], bh[nt], a, 0, 0, 0);
                    acc[mt][nt] = a;
                }
            __syncthreads();
        }
#pragma unroll
        for (int mt = 0; mt < 2; ++mt)
#pragma unroll
            for (int nt = 0; nt < 2; ++nt)
#pragma unroll
                for (int reg = 0; reg < 4; ++reg) {
                    int row = mt * 16 + q * 4 + reg;
                    int col = p * 128 + w * 32 + nt * 16 + lr;
                    float v = fmaxf(acc[mt][nt][reg] * sc[col] + sh[col], 0.f);
                    bfpair pr = split2(v);
                    Th[row * 264 + col] = pr.h;
                    Tl[row * 264 + col] = pr.l;
                }
    }
    __syncthreads();

    // stage 2: x = T @ gw2 + gb2; g2 planes are [n=128][k=256]
    v4f acc2[2][2] = {};
    for (int k0 = 0; k0 < 256; k0 += 32) {
        {
            const __bf16* shp = g2h + (size_t)bn * 256 + k0 + bkb;
            const __bf16* slp = g2l + (size_t)bn * 256 + k0 + bkb;
            *(v8bf*)&Bh[bn * 40 + bkb] = *(const v8bf*)shp;
            *(v8bf*)&Bh[bn * 40 + bkb + 8] = *(const v8bf*)(shp + 8);
            *(v8bf*)&Bl[bn * 40 + bkb] = *(const v8bf*)slp;
            *(v8bf*)&Bl[bn * 40 + bkb + 8] = *(const v8bf*)(slp + 8);
        }
        __syncthreads();
        v8bf ah[2], al2[2], bh[2], bl2[2];
#pragma unroll
        for (int mt = 0; mt < 2; ++mt) {
            ah[mt] = *(v8bf*)&Th[(mt * 16 + lr) * 264 + k0 + q * 8];
            al2[mt] = *(v8bf*)&Tl[(mt * 16 + lr) * 264 + k0 + q * 8];
        }
#pragma unroll
        for (int nt = 0; nt < 2; ++nt) {
            bh[nt] = *(v8bf*)&Bh[(w * 32 + nt * 16 + lr) * 40 + q * 8];
            bl2[nt] = *(v8bf*)&Bl[(w * 32 + nt * 16 + lr) * 40 + q * 8];
        }
#pragma unroll
        for (int mt = 0; mt < 2; ++mt)
#pragma unroll
            for (int nt = 0; nt < 2; ++nt) {
                v4f a = acc2[mt][nt];
                a = __builtin_amdgcn_mfma_f32_16x16x32_bf16(al2[mt], bh[nt], a, 0, 0, 0);
                a = __builtin_amdgcn_mfma_f32_16x16x32_bf16(ah[mt], bl2[nt], a, 0, 0, 0);
                a = __builtin_amdgcn_mfma_f32_16x16x32_bf16(ah[mt], bh[nt], a, 0, 0, 0);
                acc2[mt][nt] = a;
            }
        __syncthreads();
    }
#pragma unroll
    for (int mt = 0; mt < 2; ++mt)
#pragma unroll
        for (int nt = 0; nt < 2; ++nt)
#pragma unroll
            for (int reg = 0; reg < 4; ++reg) {
                int row = mt * 16 + q * 4 + reg;
                int col = w * 32 + nt * 16 + lr;
                xout[(size_t)(r0 + row) * H + col] = acc2[mt][nt][reg] + gb2[col];
            }
}

// ---------------- readout ----------------

__global__ void k_seg_batch(const float* __restrict__ x, const int* __restrict__ batch,
                            float* __restrict__ xgsum, float* __restrict__ gcnt) {
    int h = threadIdx.x;
    int r0 = blockIdx.x * 256;
    if (r0 >= Nn) return;
    int r1 = min(r0 + 256, Nn);
    int cur = batch[r0];
    float acc = 0.f, c = 0.f;
    for (int r = r0; r < r1; ++r) {
        int b = batch[r];
        if (b != cur) {
            atomicAdd(&xgsum[cur * H + h], acc);
            if (h == 0) atomicAdd(&gcnt[cur], c);
            acc = 0.f;
            c = 0.f;
            cur = b;
        }
        acc += x[r * H + h];
        c += 1.f;
    }
    atomicAdd(&xgsum[cur * H + h], acc);
    if (h == 0) atomicAdd(&gcnt[cur], c);
}

__global__ void k_head(const float* __restrict__ xgsum, const float* __restrict__ gcnt,
                       const float* __restrict__ alw, const float* __restrict__ alb,
                       const float* __restrict__ lw, const float* __restrict__ lb,
                       float* __restrict__ out) {
    __shared__ float mean[H];
    __shared__ float red[H];
    int g = blockIdx.x, j = threadIdx.x;
    mean[j] = xgsum[g * H + j] / fmaxf(gcnt[g], 1.f);
    __syncthreads();
    float acc = alb[j];
    for (int k = 0; k < H; ++k) acc += mean[k] * alw[k * H + j];
    acc = fmaxf(acc, 0.f) * lw[j];
    red[j] = acc;
    __syncthreads();
    for (int s = 64; s > 0; s >>= 1) {
        if (j < s) red[j] += red[j + s];
        __syncthreads();
    }
    if (j == 0) out[g] = red[0] + lb[0];
}

// ---------------- host ----------------

extern "C" void kernel_launch(void* const* d_in, const int* in_sizes, int n_in,
                              void* d_out, int out_size, void* d_ws, size_t ws_size,
                              hipStream_t stream) {
    const int* x_atom = (const int*)d_in[0];
    const int* ei = (const int*)d_in[1];
    const int* eattr = (const int*)d_in[2];
    const int* batch = (const int*)d_in[3];
    const int* xc5 = (const int*)d_in[4];
    const int* xc6 = (const int*)d_in[5];
    const int* a2c5_row = (const int*)d_in[6];
    const int* a2c6_row = (const int*)d_in[8];
    const float* atom_emb = (const float*)d_in[10];
    const float* bond_emb = (const float*)d_in[11];
    const float* cyc5 = (const float*)d_in[12];
    const float* cyc6 = (const float*)d_in[13];
    const float* eps = (const float*)d_in[14];
    const float* gw1 = (const float*)d_in[15];
    const float* gb1 = (const float*)d_in[16];
    const float* gbn_g = (const float*)d_in[17];
    const float* gbn_b = (const float*)d_in[18];
    const float* gw2 = (const float*)d_in[19];
    const float* gb2 = (const float*)d_in[20];
    const float* bn_g = (const float*)d_in[21];
    const float* bn_b = (const float*)d_in[22];
    const float* a2c5_w = (const float*)d_in[23];
    const float* a2c5_b = (const float*)d_in[24];
    const float* a2c6_w = (const float*)d_in[25];
    const float* a2c6_b = (const float*)d_in[26];
    const float* c2a5_w = (const float*)d_in[27];
    const float* c2a5_b = (const float*)d_in[28];
    const float* c2a6_w = (const float*)d_in[29];
    const float* c2a6_b = (const float*)d_in[30];
    const float* p5_w = (const float*)d_in[31];
    const float* p5_b = (const float*)d_in[32];
    const float* p6_w = (const float*)d_in[33];
    const float* p6_b = (const float*)d_in[34];
    const float* alw = (const float*)d_in[35];
    const float* alb = (const float*)d_in[36];
    const float* lw = (const float*)d_in[37];
    const float* lb = (const float*)d_in[38];
    float* out = (float*)d_out;

    float* w = (float*)d_ws;
    size_t o = 0;
    auto alloc = [&](size_t nf) {
        float* p = w + o;
        o += (nf + 63) & ~(size_t)63;
        return p;
    };
    auto allocb = [&](size_t nbf) {  // bf16 elems
        return (__bf16*)alloc((nbf + 1) / 2);
    };
    float* x = alloc((size_t)Nn * H);
    float* x5 = alloc((size_t)N5c * 5 * H);
    float* x6 = alloc((size_t)N6c * 6 * H);
    float* agg = alloc((size_t)Nn * H);
    float* S = alloc(128 * 128);
    float* colsum = alloc(128);
    float* stats = alloc(512);
    float* xgsum = alloc((size_t)Gg * H);
    float* gcnt = alloc(Gg);
    float* cnt = alloc(Nn);
    float* rscale5 = alloc(Nn);
    float* rscale6 = alloc(Nn);
    int* deg = (int*)alloc(Nn);
    int* rowptr = (int*)alloc(Nn + 1);
    int* woff = (int*)alloc(Nn);
    unsigned int* elist = (unsigned int*)alloc(Ee);
    float* ebank = alloc(512 * H);
    __bf16 *g1h = allocb(3 * 128 * 256), *g1l = allocb(3 * 128 * 256);
    __bf16 *g2h = allocb(3 * 256 * 128), *g2l = allocb(3 * 256 * 128);
    __bf16 *a5h = allocb(3 * 128 * 128), *a5l = allocb(3 * 128 * 128);
    __bf16 *a6h = allocb(3 * 128 * 128), *a6l = allocb(3 * 128 * 128);
    __bf16 *c5h = allocb(3 * 128 * 128), *c5l = allocb(3 * 128 * 128);
    __bf16 *c6h = allocb(3 * 128 * 128), *c6l = allocb(3 * 128 * 128);
    __bf16 *p5h = allocb(3 * 384 * 128), *p5l = allocb(3 * 384 * 128);
    __bf16 *p6h = allocb(3 * 384 * 128), *p6l = allocb(3 * 384 * 128);

    // optional ping-pong path buffers
    size_t extra = (((size_t)N5c * 5 * H + 63) & ~(size_t)63) +
                   (((size_t)N6c * 6 * H + 63) & ~(size_t)63);
    bool pp = (o + extra) * sizeof(float) <= ws_size;
    float* x5b = nullptr;
    float* x6b = nullptr;
    if (pp) {
        x5b = alloc((size_t)N5c * 5 * H);
        x6b = alloc((size_t)N6c * 6 * H);
    }

    const int TPB = 256;
    auto cdiv = [](int a, int b) { return (a + b - 1) / b; };

    // weight pre-split (transposed bf16 hi/lo)
    k_split<<<cdiv(3 * 128 * 256, TPB), TPB, 0, stream>>>(gw1, g1h, g1l, 3, 128, 256);
    k_split<<<cdiv(3 * 256 * 128, TPB), TPB, 0, stream>>>(gw2, g2h, g2l, 3, 256, 128);
    k_split<<<cdiv(3 * 128 * 128, TPB), TPB, 0, stream>>>(a2c5_w, a5h, a5l, 3, 128, 128);
    k_split<<<cdiv(3 * 128 * 128, TPB), TPB, 0, stream>>>(a2c6_w, a6h, a6l, 3, 128, 128);
    k_split<<<cdiv(3 * 128 * 128, TPB), TPB, 0, stream>>>(c2a5_w, c5h, c5l, 3, 128, 128);
    k_split<<<cdiv(3 * 128 * 128, TPB), TPB, 0, stream>>>(c2a6_w, c6h, c6l, 3, 128, 128);
    k_split<<<cdiv(3 * 384 * 128, TPB), TPB, 0, stream>>>(p5_w, p5h, p5l, 3, 384, 128);
    k_split<<<cdiv(3 * 384 * 128, TPB), TPB, 0, stream>>>(p6_w, p6h, p6l, 3, 384, 128);

    // CSR build
    hipMemsetAsync(deg, 0, Nn * 4, stream);
    k_deg<<<cdiv(Ee, TPB), TPB, 0, stream>>>(ei, deg);
    k_scan<<<1, 1024, 0, stream>>>(deg, rowptr, Nn);
    hipMemcpyAsync(woff, rowptr, Nn * 4, hipMemcpyDeviceToDevice, stream);
    k_fill<<<cdiv(Ee, TPB), TPB, 0, stream>>>(ei, eattr, woff, elist);

    // static scatter-mean scales
    hipMemsetAsync(cnt, 0, Nn * 4, stream);
    k_cnt<<<cdiv(N5c * 5, TPB), TPB, 0, stream>>>(a2c5_row, cnt, N5c * 5);
    k_inv<<<cdiv(Nn, TPB), TPB, 0, stream>>>(cnt, rscale5);
    hipMemsetAsync(cnt, 0, Nn * 4, stream);
    k_cnt<<<cdiv(N6c * 6, TPB), TPB, 0, stream>>>(a2c6_row, cnt, N6c * 6);
    k_inv<<<cdiv(Nn, TPB), TPB, 0, stream>>>(cnt, rscale6);

    k_atom_enc<<<cdiv(Nn * H, TPB), TPB, 0, stream>>>(x_atom, atom_emb, x);
    k_cyc_init<<<cdiv(N5c * 5 * H, TPB), TPB, 0, stream>>>(xc5, cyc5, x5, N5c * 5);
    k_cyc_init<<<cdiv(N6c * 6 * H, TPB), TPB, 0, stream>>>(xc6, cyc6, x6, N6c * 6);

    float* x5c = x5;
    float* x6c = x6;
    for (int i = 0; i < Ll; ++i) {
        // GINE aggregation (gather)
        k_ebank<<<cdiv(512 * H, TPB), TPB, 0, stream>>>(
            bond_emb + (size_t)i * BF * BV * H, ebank);
        k_agg_csr<<<Nn / 2, 256, 0, stream>>>(x, rowptr, elist, ebank, eps, i, agg);

        // BN1 stats via Gram matrix
        hipMemsetAsync(S, 0, 128 * 128 * 4, stream);
        k_gram<<<cdiv(Nn, GR), 256, 0, stream>>>(agg, S, Nn);
        hipMemsetAsync(colsum, 0, 128 * 4, stream);
        k_colsum<<<cdiv(Nn, 512), 256, 0, stream>>>(agg, colsum, Nn);
        k_bnstats1<<<4, 512, 0, stream>>>(S, colsum, gw1 + (size_t)i * 128 * 256,
                                          gb1 + (size_t)i * 256, stats);

        // fused MLP -> x (pre-BN2)
        k_mlp_mfma<<<Nn / 32, 256, 0, stream>>>(
            agg, g1h + (size_t)i * 128 * 256, g1l + (size_t)i * 128 * 256,
            gb1 + (size_t)i * 256, gbn_g + (size_t)i * 256, gbn_b + (size_t)i * 256,
            g2h + (size_t)i * 256 * 128, g2l + (size_t)i * 256 * 128,
            gb2 + (size_t)i * H, stats, x);

        // BN2 + relu
        hipMemsetAsync(stats, 0, 512 * 4, stream);
        k_bn_stats<<<cdiv(Nn, 64), H, 0, stream>>>(x, stats, Nn, H, 64);
        k_bn_apply<<<cdiv(Nn * H, TPB), TPB, 0, stream>>>(
            x, stats, bn_g + (size_t)i * H, bn_b + (size_t)i * H, Nn, H);

        // atoms -> cycles
        k_mgemm<<<cdiv(N5c * 5, 128), 256, 0, stream>>>(
            x, a5h + (size_t)i * 128 * 128, a5l + (size_t)i * 128 * 128,
            a2c5_b + (size_t)i * H, x5c, x5c, a2c5_row, N5c * 5, 128, 0, 1, 0);
        k_mgemm<<<cdiv(N6c * 6, 128), 256, 0, stream>>>(
            x, a6h + (size_t)i * 128 * 128, a6l + (size_t)i * 128 * 128,
            a2c6_b + (size_t)i * H, x6c, x6c, a2c6_row, N6c * 6, 128, 0, 1, 0);

        // cyclic path blocks
        if (pp) {
            float* x5n = (x5c == x5) ? x5b : x5;
            k_mgemm<<<cdiv(N5c * 5, 128), 256, 0, stream>>>(
                x5c, p5h + (size_t)i * 384 * 128, p5l + (size_t)i * 384 * 128,
                p5_b + (size_t)i * H, x5c, x5n, nullptr, N5c * 5, 384, 5, 1, 0);
            x5c = x5n;
            float* x6n = (x6c == x6) ? x6b : x6;
            k_mgemm<<<cdiv(N6c * 6, 128), 256, 0, stream>>>(
                x6c, p6h + (size_t)i * 384 * 128, p6l + (size_t)i * 384 * 128,
                p6_b + (size_t)i * H, x6c, x6n, nullptr, N6c * 6, 384, 6, 1, 0);
            x6c = x6n;
        } else {
            k_mgemm<<<cdiv(N5c * 5, 128), 256, 0, stream>>>(
                x5c, p5h + (size_t)i * 384 * 128, p5l + (size_t)i * 384 * 128,
                p5_b + (size_t)i * H, x5c, agg, nullptr, N5c * 5, 384, 5, 1, 0);
            hipMemcpyAsync(x5c, agg, (size_t)N5c * 5 * H * 4, hipMemcpyDeviceToDevice, stream);
            const int C6 = (N6c / 2) * 6;
            for (int ch = 0; ch < 2; ++ch) {
                k_mgemm<<<cdiv(C6, 128), 256, 0, stream>>>(
                    x6c, p6h + (size_t)i * 384 * 128, p6l + (size_t)i * 384 * 128,
                    p6_b + (size_t)i * H, x6c, agg, nullptr, C6, 384, 6, 1, ch * C6);
                hipMemcpyAsync(x6c + (size_t)ch * C6 * H, agg, (size_t)C6 * H * 4,
                               hipMemcpyDeviceToDevice, stream);
            }
        }

        // cycles -> atoms
        hipMemsetAsync(agg, 0, (size_t)Nn * H * 4, stream);
        k_scatter_add<<<cdiv(N5c * 5 * H, TPB), TPB, 0, stream>>>(
            x5c, a2c5_row, rscale5, agg, N5c * 5);
        k_mgemm<<<cdiv(Nn, 128), 256, 0, stream>>>(
            agg, c5h + (size_t)i * 128 * 128, c5l + (size_t)i * 128 * 128,
            c2a5_b + (size_t)i * H, x, x, nullptr, Nn, 128, 0, 1, 0);
        hipMemsetAsync(agg, 0, (size_t)Nn * H * 4, stream);
        k_scatter_add<<<cdiv(N6c * 6 * H, TPB), TPB, 0, stream>>>(
            x6c, a2c6_row, rscale6, agg, N6c * 6);
        k_mgemm<<<cdiv(Nn, 128), 256, 0, stream>>>(
            agg, c6h + (size_t)i * 128 * 128, c6l + (size_t)i * 128 * 128,
            c2a6_b + (size_t)i * H, x, x, nullptr, Nn, 128, 0, 1, 0);
    }

    // readout
    hipMemsetAsync(xgsum, 0, (size_t)Gg * H * 4, stream);
    hipMemsetAsync(gcnt, 0, (size_t)Gg * 4, stream);
    k_seg_batch<<<cdiv(Nn, 256), H, 0, stream>>>(x, batch, xgsum, gcnt);
    k_head<<<Gg, H, 0, stream>>>(xgsum, gcnt, alw, alb, lw, lb, out);
}

// Round 6
// 3417.805 us; speedup vs baseline: 1.1782x; 1.1782x over previous
//
#include <hip/hip_runtime.h>

#define H 128
#define Nn 100000
#define Ee 250000
#define N5c 20000
#define N6c 30000
#define Gg 512
#define Ll 3
#define AF 9
#define AV 64
#define BF 3
#define BV 8
#define BN_EPS 1e-5f

typedef __bf16 v8bf __attribute__((ext_vector_type(8)));
typedef float v4f __attribute__((ext_vector_type(4)));

struct bfpair { __bf16 h, l; };
__device__ inline bfpair split2(float v) {
    bfpair r;
    r.h = (__bf16)v;
    r.l = (__bf16)(v - (float)r.h);
    return r;
}

// ---------------- init / embedding kernels ----------------

__global__ void k_atom_enc(const int* __restrict__ xa, const float* __restrict__ emb,
                           float* __restrict__ x) {
    int idx = blockIdx.x * blockDim.x + threadIdx.x;
    if (idx >= Nn * H) return;
    int n = idx >> 7, h = idx & 127;
    float s = 0.f;
#pragma unroll
    for (int f = 0; f < AF; ++f) {
        int a = xa[n * AF + f];
        s += emb[(f * AV + a) * H + h];
    }
    x[idx] = s;
}

__global__ void k_cyc_init(const int* __restrict__ xc, const float* __restrict__ emb,
                           float* __restrict__ xo, int M) {
    int idx = blockIdx.x * blockDim.x + threadIdx.x;
    if (idx >= M * H) return;
    int m = idx >> 7, h = idx & 127;
    xo[idx] = emb[xc[m] * H + h];
}

// weight pre-split: (L,K,N) fp32 row-major -> per-layer transposed [n][k] bf16 hi/lo
__global__ void k_split(const float* __restrict__ src, __bf16* __restrict__ dh,
                        __bf16* __restrict__ dl, int L, int K, int N) {
    int idx = blockIdx.x * blockDim.x + threadIdx.x;
    int tot = L * K * N;
    if (idx >= tot) return;
    int l = idx / (K * N);
    int r = idx - l * (K * N);
    int k = r / N;
    int n = r - k * N;
    bfpair p = split2(src[idx]);
    size_t d = (size_t)l * K * N + (size_t)n * K + k;
    dh[d] = p.h;
    dl[d] = p.l;
}

// ---------------- CSR build (per launch; edge structure is static) ----------------

__global__ void k_deg(const int* __restrict__ ei, int* __restrict__ deg) {
    int e = blockIdx.x * blockDim.x + threadIdx.x;
    if (e >= Ee) return;
    atomicAdd(&deg[ei[Ee + e]], 1);
}

// hierarchical scan: 1024 elems per block, 256 threads x 4 elems
__global__ void k_scan1(const int* __restrict__ deg, int* __restrict__ rp,
                        int* __restrict__ bsum, int n) {
    __shared__ int s[256];
    int tid = threadIdx.x;
    int base = blockIdx.x * 1024 + tid * 4;
    int v0 = (base < n) ? deg[base] : 0;
    int v1 = (base + 1 < n) ? deg[base + 1] : 0;
    int v2 = (base + 2 < n) ? deg[base + 2] : 0;
    int v3 = (base + 3 < n) ? deg[base + 3] : 0;
    int tsum = v0 + v1 + v2 + v3;
    s[tid] = tsum;
    __syncthreads();
    for (int off = 1; off < 256; off <<= 1) {
        int u = (tid >= off) ? s[tid - off] : 0;
        __syncthreads();
        s[tid] += u;
        __syncthreads();
    }
    int exc = s[tid] - tsum;
    if (base < n) rp[base] = exc;
    if (base + 1 < n) rp[base + 1] = exc + v0;
    if (base + 2 < n) rp[base + 2] = exc + v0 + v1;
    if (base + 3 < n) rp[base + 3] = exc + v0 + v1 + v2;
    if (tid == 255) bsum[blockIdx.x] = s[255];
}

__global__ void k_scan2(const int* __restrict__ bsum, int* __restrict__ boff,
                        int* __restrict__ rp, int nb, int n) {
    __shared__ int s[128];
    int tid = threadIdx.x;
    int v = (tid < nb) ? bsum[tid] : 0;
    s[tid] = v;
    __syncthreads();
    for (int off = 1; off < 128; off <<= 1) {
        int u = (tid >= off) ? s[tid - off] : 0;
        __syncthreads();
        s[tid] += u;
        __syncthreads();
    }
    if (tid < nb) boff[tid] = s[tid] - v;
    if (tid == 127) rp[n] = s[127];
}

__global__ void k_scan3(int* __restrict__ rp, const int* __restrict__ boff, int n) {
    int idx = blockIdx.x * blockDim.x + threadIdx.x;
    if (idx < n) rp[idx] += boff[idx >> 10];
}

__global__ void k_fill(const int* __restrict__ ei, const int* __restrict__ eattr,
                       int* __restrict__ woff, unsigned int* __restrict__ elist) {
    int e = blockIdx.x * blockDim.x + threadIdx.x;
    if (e >= Ee) return;
    int src = ei[e], dst = ei[Ee + e];
    int code = eattr[e * BF + 0] * 64 + eattr[e * BF + 1] * 8 + eattr[e * BF + 2];
    int p = atomicAdd(&woff[dst], 1);
    elist[p] = ((unsigned int)code << 17) | (unsigned int)src;
}

__global__ void k_cnt(const int* __restrict__ row, float* __restrict__ cnt, int M) {
    int m = blockIdx.x * blockDim.x + threadIdx.x;
    if (m >= M) return;
    atomicAdd(&cnt[row[m]], 1.f);
}

__global__ void k_inv(const float* __restrict__ cnt, float* __restrict__ rscale) {
    int r = blockIdx.x * blockDim.x + threadIdx.x;
    if (r >= Nn) return;
    rscale[r] = 1.f / fmaxf(cnt[r], 1.f);
}

// per-layer bond-embedding bank: 512 codes x 128
__global__ void k_ebank(const float* __restrict__ bemb, float* __restrict__ ebank) {
    int idx = blockIdx.x * blockDim.x + threadIdx.x;
    if (idx >= 512 * H) return;
    int code = idx >> 7, h = idx & 127;
    int f0 = code >> 6, f1 = (code >> 3) & 7, f2 = code & 7;
    ebank[idx] = bemb[(0 * BV + f0) * H + h] + bemb[(1 * BV + f1) * H + h]
               + bemb[(2 * BV + f2) * H + h];
}

// GINE aggregation, gather form
__global__ __launch_bounds__(256) void k_agg_csr(
    const float* __restrict__ x, const int* __restrict__ rowptr,
    const unsigned int* __restrict__ elist, const float* __restrict__ ebank,
    const float* __restrict__ eps, int layer, float* __restrict__ agg)
{
    int a = blockIdx.x * 2 + (threadIdx.x >> 7);
    int h = threadIdx.x & 127;
    float acc = (1.f + eps[layer]) * x[(size_t)a * H + h];
    int j0 = rowptr[a], j1 = rowptr[a + 1];
    for (int j = j0; j < j1; ++j) {
        unsigned int u = elist[j];
        int src = u & 0x1FFFF;
        int code = u >> 17;
        acc += fmaxf(x[(size_t)src * H + h] + ebank[code * H + h], 0.f);
    }
    agg[(size_t)a * H + h] = acc;
}

// ---------------- misc elementwise ----------------

__global__ void k_bn_stats(const float* __restrict__ h, float* __restrict__ stats,
                           int M, int C, int rpb) {
    int c = threadIdx.x;
    int r0 = blockIdx.x * rpb;
    int r1 = min(r0 + rpb, M);
    float s = 0.f, sq = 0.f;
    for (int r = r0; r < r1; ++r) {
        float v = h[(size_t)r * C + c];
        s += v;
        sq += v * v;
    }
    atomicAdd(&stats[c], s);
    atomicAdd(&stats[C + c], sq);
}

__global__ void k_bn_apply(float* __restrict__ h, const float* __restrict__ stats,
                           const float* __restrict__ g, const float* __restrict__ b,
                           int M, int C) {
    int idx = blockIdx.x * blockDim.x + threadIdx.x;
    if (idx >= M * C) return;
    int c = idx & (C - 1);
    float mean = stats[c] / (float)M;
    float var = stats[C + c] / (float)M - mean * mean;
    float v = (h[idx] - mean) * rsqrtf(var + BN_EPS) * g[c] + b[c];
    h[idx] = fmaxf(v, 0.f);
}

// scatter-mean with pre-baked 1/cnt scale
__global__ void k_scatter_add(const float* __restrict__ xc, const int* __restrict__ row,
                              const float* __restrict__ rscale, float* __restrict__ sum,
                              int M) {
    int idx = blockIdx.x * blockDim.x + threadIdx.x;
    if (idx >= M * H) return;
    int m = idx >> 7, h = idx & 127;
    int r = row[m];
    atomicAdd(&sum[r * H + h], xc[idx] * rscale[r]);
}

// ---------------- generic MFMA GEMM (bf16x3 split, pre-split B) ----------------
// out[m,n] = maybe_relu( sum_k A'[m,k]*B[k,n] + bias[n0+n] ) (+ res[row0+m,n])
// epi==1: accumulate column sum/sumsq of (acc+bias) into stats[n0+n], stats[Ncol+n0+n]
// B planes Bth/Btl: [n][k] transposed, row stride K; n indexed by n0+bn.

__global__ __launch_bounds__(256) void k_mgemm(
    const float* __restrict__ A, const __bf16* __restrict__ Bth,
    const __bf16* __restrict__ Btl, const float* __restrict__ bias,
    const float* __restrict__ res, float* __restrict__ out,
    const int* __restrict__ rowidx, float* __restrict__ stats,
    int M, int K, int Ncol, int pathk, int relu_flag, int row0, int epi)
{
    __shared__ __bf16 Ah[128 * 40], Al[128 * 40];
    __shared__ __bf16 Bh[128 * 40], Bl[128 * 40];
    __shared__ float sS[128], sQ[128];

    int t = threadIdx.x;
    int m0 = blockIdx.x * 128;
    int n0 = blockIdx.y * 128;
    int lane = t & 63;
    int q = lane >> 4;
    int lr = lane & 15;
    int wrow = (t >> 6) * 32;

    v4f acc[2][8] = {};

    int ar = t >> 1;
    int akq = (t & 1) * 16;
    int bn = t & 127;
    int bkb = (t >> 7) * 16;

    for (int k0 = 0; k0 < K; k0 += 32) {
        // stage A (fp32 -> hi/lo)
        {
            float va[16];
            int gm = m0 + ar;
            if (gm < M) {
                int kk = k0 + akq;
                const float* ap;
                if (pathk) {
                    int g = row0 + gm;
                    int cyc = g / pathk;
                    int p = g - cyc * pathk;
                    int sel = kk >> 7;
                    int pp = p + sel - 1;
                    if (pp < 0) pp += pathk;
                    if (pp >= pathk) pp -= pathk;
                    ap = A + (size_t)(cyc * pathk + pp) * H + (kk & 127);
                } else if (rowidx) {
                    ap = A + (size_t)rowidx[gm] * H + kk;
                } else {
                    ap = A + (size_t)gm * K + kk;
                }
#pragma unroll
                for (int i = 0; i < 4; ++i) {
                    float4 f = *(const float4*)(ap + i * 4);
                    va[i * 4 + 0] = f.x; va[i * 4 + 1] = f.y;
                    va[i * 4 + 2] = f.z; va[i * 4 + 3] = f.w;
                }
            } else {
#pragma unroll
                for (int i = 0; i < 16; ++i) va[i] = 0.f;
            }
            v8bf h0, h1, l0, l1;
#pragma unroll
            for (int i = 0; i < 8; ++i) {
                bfpair p0 = split2(va[i]);
                bfpair p1 = split2(va[8 + i]);
                h0[i] = p0.h; l0[i] = p0.l;
                h1[i] = p1.h; l1[i] = p1.l;
            }
            *(v8bf*)&Ah[ar * 40 + akq] = h0;
            *(v8bf*)&Ah[ar * 40 + akq + 8] = h1;
            *(v8bf*)&Al[ar * 40 + akq] = l0;
            *(v8bf*)&Al[ar * 40 + akq + 8] = l1;
        }
        // stage B (pre-split bf16, direct copy)
        {
            const __bf16* sh = Bth + (size_t)(n0 + bn) * K + k0 + bkb;
            const __bf16* sl = Btl + (size_t)(n0 + bn) * K + k0 + bkb;
            *(v8bf*)&Bh[bn * 40 + bkb] = *(const v8bf*)sh;
            *(v8bf*)&Bh[bn * 40 + bkb + 8] = *(const v8bf*)(sh + 8);
            *(v8bf*)&Bl[bn * 40 + bkb] = *(const v8bf*)sl;
            *(v8bf*)&Bl[bn * 40 + bkb + 8] = *(const v8bf*)(sl + 8);
        }
        __syncthreads();

        v8bf ah[2], al2[2], bh[8], bl2[8];
#pragma unroll
        for (int mt = 0; mt < 2; ++mt) {
            ah[mt] = *(v8bf*)&Ah[(wrow + mt * 16 + lr) * 40 + q * 8];
            al2[mt] = *(v8bf*)&Al[(wrow + mt * 16 + lr) * 40 + q * 8];
        }
#pragma unroll
        for (int nt = 0; nt < 8; ++nt) {
            bh[nt] = *(v8bf*)&Bh[(nt * 16 + lr) * 40 + q * 8];
            bl2[nt] = *(v8bf*)&Bl[(nt * 16 + lr) * 40 + q * 8];
        }
#pragma unroll
        for (int mt = 0; mt < 2; ++mt)
#pragma unroll
            for (int nt = 0; nt < 8; ++nt) {
                v4f a = acc[mt][nt];
                a = __builtin_amdgcn_mfma_f32_16x16x32_bf16(al2[mt], bh[nt], a, 0, 0, 0);
                a = __builtin_amdgcn_mfma_f32_16x16x32_bf16(ah[mt], bl2[nt], a, 0, 0, 0);
                a = __builtin_amdgcn_mfma_f32_16x16x32_bf16(ah[mt], bh[nt], a, 0, 0, 0);
                acc[mt][nt] = a;
            }
        __syncthreads();
    }

    if (epi == 0) {
        float bcol[8];
#pragma unroll
        for (int nt = 0; nt < 8; ++nt) bcol[nt] = bias[n0 + nt * 16 + lr];
#pragma unroll
        for (int mt = 0; mt < 2; ++mt)
#pragma unroll
            for (int reg = 0; reg < 4; ++reg) {
                int rm = m0 + wrow + mt * 16 + q * 4 + reg;
                if (rm < M) {
#pragma unroll
                    for (int nt = 0; nt < 8; ++nt) {
                        int cn = nt * 16 + lr;
                        float v = acc[mt][nt][reg] + bcol[nt];
                        if (relu_flag) v = fmaxf(v, 0.f);
                        if (res) v += res[(size_t)(row0 + rm) * Ncol + n0 + cn];
                        out[(size_t)rm * Ncol + n0 + cn] = v;
                    }
                }
            }
    } else {
        if (t < 128) { sS[t] = 0.f; sQ[t] = 0.f; }
        __syncthreads();
        float bcol[8];
#pragma unroll
        for (int nt = 0; nt < 8; ++nt) bcol[nt] = bias[n0 + nt * 16 + lr];
#pragma unroll
        for (int nt = 0; nt < 8; ++nt) {
            float s = 0.f, q2 = 0.f;
#pragma unroll
            for (int mt = 0; mt < 2; ++mt)
#pragma unroll
                for (int reg = 0; reg < 4; ++reg) {
                    int rm = m0 + wrow + mt * 16 + q * 4 + reg;
                    if (rm < M) {
                        float v = acc[mt][nt][reg] + bcol[nt];
                        s += v;
                        q2 += v * v;
                    }
                }
            atomicAdd(&sS[nt * 16 + lr], s);
            atomicAdd(&sQ[nt * 16 + lr], q2);
        }
        __syncthreads();
        if (t < 128) {
            atomicAdd(&stats[n0 + t], sS[t]);
            atomicAdd(&stats[Ncol + n0 + t], sQ[t]);
        }
    }
}

// ---------------- fused GINE MLP via MFMA (pre-split weights) ----------------

__global__ __launch_bounds__(256) void k_mlp_mfma(
    const float* __restrict__ hin,
    const __bf16* __restrict__ g1h, const __bf16* __restrict__ g1l,
    const float* __restrict__ gb1, const float* __restrict__ gbn_g,
    const float* __restrict__ gbn_b,
    const __bf16* __restrict__ g2h, const __bf16* __restrict__ g2l,
    const float* __restrict__ gb2, const float* __restrict__ stats,
    float* __restrict__ xout)
{
    __shared__ __bf16 Ah[32 * 136], Al[32 * 136];
    __shared__ __bf16 Bh[128 * 40], Bl[128 * 40];
    __shared__ __bf16 Th[32 * 264], Tl[32 * 264];
    __shared__ float sc[256], sh[256];

    int t = threadIdx.x;
    int r0 = blockIdx.x * 32;
    int lane = t & 63;
    int q = lane >> 4;
    int lr = lane & 15;
    int w = t >> 6;

    {
        float mean = stats[t] * (1.f / (float)Nn);
        float var = stats[256 + t] * (1.f / (float)Nn) - mean * mean;
        float s = gbn_g[t] * rsqrtf(var + BN_EPS);
        sc[t] = s;
        sh[t] = (gb1[t] - mean) * s + gbn_b[t];
    }
    {
        int r = t >> 3;
        int kq = (t & 7) * 16;
        const float* ap = hin + (size_t)(r0 + r) * H + kq;
        v8bf h0, h1, l0, l1;
#pragma unroll
        for (int i = 0; i < 8; ++i) {
            bfpair p0 = split2(ap[i]);
            bfpair p1 = split2(ap[8 + i]);
            h0[i] = p0.h; l0[i] = p0.l;
            h1[i] = p1.h; l1[i] = p1.l;
        }
        *(v8bf*)&Ah[r * 136 + kq] = h0;
        *(v8bf*)&Ah[r * 136 + kq + 8] = h1;
        *(v8bf*)&Al[r * 136 + kq] = l0;
        *(v8bf*)&Al[r * 136 + kq + 8] = l1;
    }

    int bn = t & 127;
    int bkb = (t >> 7) * 16;

    // stage 1: T = relu(BN1(hin@gw1)), two 128-col panels; g1 planes [n=256][k=128]
    for (int p = 0; p < 2; ++p) {
        v4f acc[2][2] = {};
        for (int k0 = 0; k0 < 128; k0 += 32) {
            {
                const __bf16* shp = g1h + (size_t)(p * 128 + bn) * 128 + k0 + bkb;
                const __bf16* slp = g1l + (size_t)(p * 128 + bn) * 128 + k0 + bkb;
                *(v8bf*)&Bh[bn * 40 + bkb] = *(const v8bf*)shp;
                *(v8bf*)&Bh[bn * 40 + bkb + 8] = *(const v8bf*)(shp + 8);
                *(v8bf*)&Bl[bn * 40 + bkb] = *(const v8bf*)slp;
                *(v8bf*)&Bl[bn * 40 + bkb + 8] = *(const v8bf*)(slp + 8);
            }
            __syncthreads();
            v8bf ah[2], al2[2], bh[2], bl2[2];
#pragma unroll
            for (int mt = 0; mt < 2; ++mt) {
                ah[mt] = *(v8bf*)&Ah[(mt * 16 + lr) * 136 + k0 + q * 8];
                al2[mt] = *(v8bf*)&Al[(mt * 16 + lr) * 136 + k0 + q * 8];
            }
#pragma unroll
            for (int nt = 0; nt < 2; ++nt) {
                bh[nt] = *(v8bf*)&Bh[(w * 32 + nt * 16 + lr) * 40 + q * 8];
                bl2[nt] = *(v8bf*)&Bl[(w * 32 + nt * 16 + lr) * 40 + q * 8];
            }
#pragma unroll
            for (int mt = 0; mt < 2; ++mt)
#pragma unroll
                for (int nt = 0; nt < 2; ++nt) {
                    v4f a = acc[mt][nt];
                    a = __builtin_amdgcn_mfma_f32_16x16x32_bf16(al2[mt], bh[nt], a, 0, 0, 0);
                    a = __builtin_amdgcn_mfma_f32_16x16x32_bf16(ah[mt], bl2[nt], a, 0, 0, 0);
                    a = __builtin_amdgcn_mfma_f32_16x16x32_bf16(ah[mt], bh[nt], a, 0, 0, 0);
                    acc[mt][nt] = a;
                }
            __syncthreads();
        }
#pragma unroll
        for (int mt = 0; mt < 2; ++mt)
#pragma unroll
            for (int nt = 0; nt < 2; ++nt)
#pragma unroll
                for (int reg = 0; reg < 4; ++reg) {
                    int row = mt * 16 + q * 4 + reg;
                    int col = p * 128 + w * 32 + nt * 16 + lr;
                    float v = fmaxf(acc[mt][nt][reg] * sc[col] + sh[col], 0.f);
                    bfpair pr = split2(v);
                    Th[row * 264 + col] = pr.h;
                    Tl[row * 264 + col] = pr.l;
                }
    }
    __syncthreads();

    // stage 2: x = T @ gw2 + gb2; g2 planes [n=128][k=256]
    v4f acc2[2][2] = {};
    for (int k0 = 0; k0 < 256; k0 += 32) {
        {
            const __bf16* shp = g2h + (size_t)bn * 256 + k0 + bkb;
            const __bf16* slp = g2l + (size_t)bn * 256 + k0 + bkb;
            *(v8bf*)&Bh[bn * 40 + bkb] = *(const v8bf*)shp;
            *(v8bf*)&Bh[bn * 40 + bkb + 8] = *(const v8bf*)(shp + 8);
            *(v8bf*)&Bl[bn * 40 + bkb] = *(const v8bf*)slp;
            *(v8bf*)&Bl[bn * 40 + bkb + 8] = *(const v8bf*)(slp + 8);
        }
        __syncthreads();
        v8bf ah[2], al2[2], bh[2], bl2[2];
#pragma unroll
        for (int mt = 0; mt < 2; ++mt) {
            ah[mt] = *(v8bf*)&Th[(mt * 16 + lr) * 264 + k0 + q * 8];
            al2[mt] = *(v8bf*)&Tl[(mt * 16 + lr) * 264 + k0 + q * 8];
        }
#pragma unroll
        for (int nt = 0; nt < 2; ++nt) {
            bh[nt] = *(v8bf*)&Bh[(w * 32 + nt * 16 + lr) * 40 + q * 8];
            bl2[nt] = *(v8bf*)&Bl[(w * 32 + nt * 16 + lr) * 40 + q * 8];
        }
#pragma unroll
        for (int mt = 0; mt < 2; ++mt)
#pragma unroll
            for (int nt = 0; nt < 2; ++nt) {
                v4f a = acc2[mt][nt];
                a = __builtin_amdgcn_mfma_f32_16x16x32_bf16(al2[mt], bh[nt], a, 0, 0, 0);
                a = __builtin_amdgcn_mfma_f32_16x16x32_bf16(ah[mt], bl2[nt], a, 0, 0, 0);
                a = __builtin_amdgcn_mfma_f32_16x16x32_bf16(ah[mt], bh[nt], a, 0, 0, 0);
                acc2[mt][nt] = a;
            }
        __syncthreads();
    }
#pragma unroll
    for (int mt = 0; mt < 2; ++mt)
#pragma unroll
        for (int nt = 0; nt < 2; ++nt)
#pragma unroll
            for (int reg = 0; reg < 4; ++reg) {
                int row = mt * 16 + q * 4 + reg;
                int col = w * 32 + nt * 16 + lr;
                xout[(size_t)(r0 + row) * H + col] = acc2[mt][nt][reg] + gb2[col];
            }
}

// ---------------- readout ----------------

__global__ void k_seg_batch(const float* __restrict__ x, const int* __restrict__ batch,
                            float* __restrict__ xgsum, float* __restrict__ gcnt) {
    int h = threadIdx.x;
    int r0 = blockIdx.x * 256;
    if (r0 >= Nn) return;
    int r1 = min(r0 + 256, Nn);
    int cur = batch[r0];
    float acc = 0.f, c = 0.f;
    for (int r = r0; r < r1; ++r) {
        int b = batch[r];
        if (b != cur) {
            atomicAdd(&xgsum[cur * H + h], acc);
            if (h == 0) atomicAdd(&gcnt[cur], c);
            acc = 0.f;
            c = 0.f;
            cur = b;
        }
        acc += x[r * H + h];
        c += 1.f;
    }
    atomicAdd(&xgsum[cur * H + h], acc);
    if (h == 0) atomicAdd(&gcnt[cur], c);
}

__global__ void k_head(const float* __restrict__ xgsum, const float* __restrict__ gcnt,
                       const float* __restrict__ alw, const float* __restrict__ alb,
                       const float* __restrict__ lw, const float* __restrict__ lb,
                       float* __restrict__ out) {
    __shared__ float mean[H];
    __shared__ float red[H];
    int g = blockIdx.x, j = threadIdx.x;
    mean[j] = xgsum[g * H + j] / fmaxf(gcnt[g], 1.f);
    __syncthreads();
    float acc = alb[j];
    for (int k = 0; k < H; ++k) acc += mean[k] * alw[k * H + j];
    acc = fmaxf(acc, 0.f) * lw[j];
    red[j] = acc;
    __syncthreads();
    for (int s = 64; s > 0; s >>= 1) {
        if (j < s) red[j] += red[j + s];
        __syncthreads();
    }
    if (j == 0) out[g] = red[0] + lb[0];
}

// ---------------- host ----------------

extern "C" void kernel_launch(void* const* d_in, const int* in_sizes, int n_in,
                              void* d_out, int out_size, void* d_ws, size_t ws_size,
                              hipStream_t stream) {
    const int* x_atom = (const int*)d_in[0];
    const int* ei = (const int*)d_in[1];
    const int* eattr = (const int*)d_in[2];
    const int* batch = (const int*)d_in[3];
    const int* xc5 = (const int*)d_in[4];
    const int* xc6 = (const int*)d_in[5];
    const int* a2c5_row = (const int*)d_in[6];
    const int* a2c6_row = (const int*)d_in[8];
    const float* atom_emb = (const float*)d_in[10];
    const float* bond_emb = (const float*)d_in[11];
    const float* cyc5 = (const float*)d_in[12];
    const float* cyc6 = (const float*)d_in[13];
    const float* eps = (const float*)d_in[14];
    const float* gw1 = (const float*)d_in[15];
    const float* gb1 = (const float*)d_in[16];
    const float* gbn_g = (const float*)d_in[17];
    const float* gbn_b = (const float*)d_in[18];
    const float* gw2 = (const float*)d_in[19];
    const float* gb2 = (const float*)d_in[20];
    const float* bn_g = (const float*)d_in[21];
    const float* bn_b = (const float*)d_in[22];
    const float* a2c5_w = (const float*)d_in[23];
    const float* a2c5_b = (const float*)d_in[24];
    const float* a2c6_w = (const float*)d_in[25];
    const float* a2c6_b = (const float*)d_in[26];
    const float* c2a5_w = (const float*)d_in[27];
    const float* c2a5_b = (const float*)d_in[28];
    const float* c2a6_w = (const float*)d_in[29];
    const float* c2a6_b = (const float*)d_in[30];
    const float* p5_w = (const float*)d_in[31];
    const float* p5_b = (const float*)d_in[32];
    const float* p6_w = (const float*)d_in[33];
    const float* p6_b = (const float*)d_in[34];
    const float* alw = (const float*)d_in[35];
    const float* alb = (const float*)d_in[36];
    const float* lw = (const float*)d_in[37];
    const float* lb = (const float*)d_in[38];
    float* out = (float*)d_out;

    float* w = (float*)d_ws;
    size_t o = 0;
    auto alloc = [&](size_t nf) {
        float* p = w + o;
        o += (nf + 63) & ~(size_t)63;
        return p;
    };
    auto allocb = [&](size_t nbf) { return (__bf16*)alloc((nbf + 1) / 2); };
    float* x = alloc((size_t)Nn * H);
    float* x5 = alloc((size_t)N5c * 5 * H);
    float* x6 = alloc((size_t)N6c * 6 * H);
    float* agg = alloc((size_t)Nn * H);
    float* stats = alloc(512);
    float* xgsum = alloc((size_t)Gg * H);
    float* gcnt = alloc(Gg);
    float* cnt = alloc(Nn);
    float* rscale5 = alloc(Nn);
    float* rscale6 = alloc(Nn);
    int* deg = (int*)alloc(Nn);
    int* rowptr = (int*)alloc(Nn + 1);
    int* woff = (int*)alloc(Nn);
    int* bsum = (int*)alloc(256);
    int* boff = (int*)alloc(256);
    unsigned int* elist = (unsigned int*)alloc(Ee);
    float* ebank = alloc(512 * H);
    __bf16 *g1h = allocb(3 * 128 * 256), *g1l = allocb(3 * 128 * 256);
    __bf16 *g2h = allocb(3 * 256 * 128), *g2l = allocb(3 * 256 * 128);
    __bf16 *a5h = allocb(3 * 128 * 128), *a5l = allocb(3 * 128 * 128);
    __bf16 *a6h = allocb(3 * 128 * 128), *a6l = allocb(3 * 128 * 128);
    __bf16 *c5h = allocb(3 * 128 * 128), *c5l = allocb(3 * 128 * 128);
    __bf16 *c6h = allocb(3 * 128 * 128), *c6l = allocb(3 * 128 * 128);
    __bf16 *p5h = allocb(3 * 384 * 128), *p5l = allocb(3 * 384 * 128);
    __bf16 *p6h = allocb(3 * 384 * 128), *p6l = allocb(3 * 384 * 128);

    const int TPB = 256;
    auto cdiv = [](int a, int b) { return (a + b - 1) / b; };

    // weight pre-split (transposed bf16 hi/lo)
    k_split<<<cdiv(3 * 128 * 256, TPB), TPB, 0, stream>>>(gw1, g1h, g1l, 3, 128, 256);
    k_split<<<cdiv(3 * 256 * 128, TPB), TPB, 0, stream>>>(gw2, g2h, g2l, 3, 256, 128);
    k_split<<<cdiv(3 * 128 * 128, TPB), TPB, 0, stream>>>(a2c5_w, a5h, a5l, 3, 128, 128);
    k_split<<<cdiv(3 * 128 * 128, TPB), TPB, 0, stream>>>(a2c6_w, a6h, a6l, 3, 128, 128);
    k_split<<<cdiv(3 * 128 * 128, TPB), TPB, 0, stream>>>(c2a5_w, c5h, c5l, 3, 128, 128);
    k_split<<<cdiv(3 * 128 * 128, TPB), TPB, 0, stream>>>(c2a6_w, c6h, c6l, 3, 128, 128);
    k_split<<<cdiv(3 * 384 * 128, TPB), TPB, 0, stream>>>(p5_w, p5h, p5l, 3, 384, 128);
    k_split<<<cdiv(3 * 384 * 128, TPB), TPB, 0, stream>>>(p6_w, p6h, p6l, 3, 384, 128);

    // CSR build (hierarchical scan)
    hipMemsetAsync(deg, 0, Nn * 4, stream);
    k_deg<<<cdiv(Ee, TPB), TPB, 0, stream>>>(ei, deg);
    int nsb = cdiv(Nn, 1024);  // 98
    k_scan1<<<nsb, 256, 0, stream>>>(deg, rowptr, bsum, Nn);
    k_scan2<<<1, 128, 0, stream>>>(bsum, boff, rowptr, nsb, Nn);
    k_scan3<<<cdiv(Nn, TPB), TPB, 0, stream>>>(rowptr, boff, Nn);
    hipMemcpyAsync(woff, rowptr, Nn * 4, hipMemcpyDeviceToDevice, stream);
    k_fill<<<cdiv(Ee, TPB), TPB, 0, stream>>>(ei, eattr, woff, elist);

    // static scatter-mean scales
    hipMemsetAsync(cnt, 0, Nn * 4, stream);
    k_cnt<<<cdiv(N5c * 5, TPB), TPB, 0, stream>>>(a2c5_row, cnt, N5c * 5);
    k_inv<<<cdiv(Nn, TPB), TPB, 0, stream>>>(cnt, rscale5);
    hipMemsetAsync(cnt, 0, Nn * 4, stream);
    k_cnt<<<cdiv(N6c * 6, TPB), TPB, 0, stream>>>(a2c6_row, cnt, N6c * 6);
    k_inv<<<cdiv(Nn, TPB), TPB, 0, stream>>>(cnt, rscale6);

    k_atom_enc<<<cdiv(Nn * H, TPB), TPB, 0, stream>>>(x_atom, atom_emb, x);
    k_cyc_init<<<cdiv(N5c * 5 * H, TPB), TPB, 0, stream>>>(xc5, cyc5, x5, N5c * 5);
    k_cyc_init<<<cdiv(N6c * 6 * H, TPB), TPB, 0, stream>>>(xc6, cyc6, x6, N6c * 6);

    for (int i = 0; i < Ll; ++i) {
        // GINE aggregation (gather)
        k_ebank<<<cdiv(512 * H, TPB), TPB, 0, stream>>>(
            bond_emb + (size_t)i * BF * BV * H, ebank);
        k_agg_csr<<<Nn / 2, 256, 0, stream>>>(x, rowptr, elist, ebank, eps, i, agg);

        // BN1 stats via epi-GEMM (h1 never materialized)
        hipMemsetAsync(stats, 0, 512 * 4, stream);
        dim3 gst(cdiv(Nn, 128), 2);
        k_mgemm<<<gst, 256, 0, stream>>>(agg, g1h + (size_t)i * 128 * 256,
                                         g1l + (size_t)i * 128 * 256,
                                         gb1 + (size_t)i * 256, nullptr, nullptr,
                                         nullptr, stats, Nn, 128, 256, 0, 0, 0, 1);

        // fused MLP -> x (pre-BN2)
        k_mlp_mfma<<<Nn / 32, 256, 0, stream>>>(
            agg, g1h + (size_t)i * 128 * 256, g1l + (size_t)i * 128 * 256,
            gb1 + (size_t)i * 256, gbn_g + (size_t)i * 256, gbn_b + (size_t)i * 256,
            g2h + (size_t)i * 256 * 128, g2l + (size_t)i * 256 * 128,
            gb2 + (size_t)i * H, stats, x);

        // BN2 + relu
        hipMemsetAsync(stats, 0, 512 * 4, stream);
        k_bn_stats<<<cdiv(Nn, 64), H, 0, stream>>>(x, stats, Nn, H, 64);
        k_bn_apply<<<cdiv(Nn * H, TPB), TPB, 0, stream>>>(
            x, stats, bn_g + (size_t)i * H, bn_b + (size_t)i * H, Nn, H);

        // atoms -> cycles
        k_mgemm<<<dim3(cdiv(N5c * 5, 128), 1), 256, 0, stream>>>(
            x, a5h + (size_t)i * 128 * 128, a5l + (size_t)i * 128 * 128,
            a2c5_b + (size_t)i * H, x5, x5, a2c5_row, nullptr,
            N5c * 5, 128, 128, 0, 1, 0, 0);
        k_mgemm<<<dim3(cdiv(N6c * 6, 128), 1), 256, 0, stream>>>(
            x, a6h + (size_t)i * 128 * 128, a6l + (size_t)i * 128 * 128,
            a2c6_b + (size_t)i * H, x6, x6, a2c6_row, nullptr,
            N6c * 6, 128, 128, 0, 1, 0, 0);

        // cyclic path blocks -> agg (tmp), copy back; x6 in 2 chunks
        k_mgemm<<<dim3(cdiv(N5c * 5, 128), 1), 256, 0, stream>>>(
            x5, p5h + (size_t)i * 384 * 128, p5l + (size_t)i * 384 * 128,
            p5_b + (size_t)i * H, x5, agg, nullptr, nullptr,
            N5c * 5, 384, 128, 5, 1, 0, 0);
        hipMemcpyAsync(x5, agg, (size_t)N5c * 5 * H * 4, hipMemcpyDeviceToDevice, stream);
        const int C6 = (N6c / 2) * 6;
        for (int ch = 0; ch < 2; ++ch) {
            k_mgemm<<<dim3(cdiv(C6, 128), 1), 256, 0, stream>>>(
                x6, p6h + (size_t)i * 384 * 128, p6l + (size_t)i * 384 * 128,
                p6_b + (size_t)i * H, x6, agg, nullptr, nullptr,
                C6, 384, 128, 6, 1, ch * C6, 0);
            hipMemcpyAsync(x6 + (size_t)ch * C6 * H, agg, (size_t)C6 * H * 4,
                           hipMemcpyDeviceToDevice, stream);
        }

        // cycles -> atoms
        hipMemsetAsync(agg, 0, (size_t)Nn * H * 4, stream);
        k_scatter_add<<<cdiv(N5c * 5 * H, TPB), TPB, 0, stream>>>(
            x5, a2c5_row, rscale5, agg, N5c * 5);
        k_mgemm<<<dim3(cdiv(Nn, 128), 1), 256, 0, stream>>>(
            agg, c5h + (size_t)i * 128 * 128, c5l + (size_t)i * 128 * 128,
            c2a5_b + (size_t)i * H, x, x, nullptr, nullptr,
            Nn, 128, 128, 0, 1, 0, 0);
        hipMemsetAsync(agg, 0, (size_t)Nn * H * 4, stream);
        k_scatter_add<<<cdiv(N6c * 6 * H, TPB), TPB, 0, stream>>>(
            x6, a2c6_row, rscale6, agg, N6c * 6);
        k_mgemm<<<dim3(cdiv(Nn, 128), 1), 256, 0, stream>>>(
            agg, c6h + (size_t)i * 128 * 128, c6l + (size_t)i * 128 * 128,
            c2a6_b + (size_t)i * H, x, x, nullptr, nullptr,
            Nn, 128, 128, 0, 1, 0, 0);
    }

    // readout
    hipMemsetAsync(xgsum, 0, (size_t)Gg * H * 4, stream);
    hipMemsetAsync(gcnt, 0, (size_t)Gg * 4, stream);
    k_seg_batch<<<cdiv(Nn, 256), H, 0, stream>>>(x, batch, xgsum, gcnt);
    k_head<<<Gg, H, 0, stream>>>(xgsum, gcnt, alw, alb, lw, lb, out);
}

// Round 7
// 3165.433 us; speedup vs baseline: 1.2721x; 1.0797x over previous
//
#include <hip/hip_runtime.h>

#define H 128
#define Nn 100000
#define Ee 250000
#define N5c 20000
#define N6c 30000
#define Gg 512
#define Ll 3
#define AF 9
#define AV 64
#define BF 3
#define BV 8
#define BN_EPS 1e-5f

typedef __bf16 v8bf __attribute__((ext_vector_type(8)));
typedef float v4f __attribute__((ext_vector_type(4)));

struct bfpair { __bf16 h, l; };
__device__ inline bfpair split2(float v) {
    bfpair r;
    r.h = (__bf16)v;
    r.l = (__bf16)(v - (float)r.h);
    return r;
}

// ---------------- init / embedding kernels ----------------

__global__ void k_atom_enc(const int* __restrict__ xa, const float* __restrict__ emb,
                           float* __restrict__ x) {
    int idx = blockIdx.x * blockDim.x + threadIdx.x;
    if (idx >= Nn * H) return;
    int n = idx >> 7, h = idx & 127;
    float s = 0.f;
#pragma unroll
    for (int f = 0; f < AF; ++f) {
        int a = xa[n * AF + f];
        s += emb[(f * AV + a) * H + h];
    }
    x[idx] = s;
}

__global__ void k_cyc_init(const int* __restrict__ xc, const float* __restrict__ emb,
                           float* __restrict__ xo, int M) {
    int idx = blockIdx.x * blockDim.x + threadIdx.x;
    if (idx >= M * H) return;
    int m = idx >> 7, h = idx & 127;
    xo[idx] = emb[xc[m] * H + h];
}

// weight pre-split: (L,K,N) fp32 row-major -> per-layer transposed [n][k] bf16 hi/lo
__global__ void k_split(const float* __restrict__ src, __bf16* __restrict__ dh,
                        __bf16* __restrict__ dl, int L, int K, int N) {
    int idx = blockIdx.x * blockDim.x + threadIdx.x;
    int tot = L * K * N;
    if (idx >= tot) return;
    int l = idx / (K * N);
    int r = idx - l * (K * N);
    int k = r / N;
    int n = r - k * N;
    bfpair p = split2(src[idx]);
    size_t d = (size_t)l * K * N + (size_t)n * K + k;
    dh[d] = p.h;
    dl[d] = p.l;
}

// ---------------- CSR build ----------------

__global__ void k_deg(const int* __restrict__ ei, int* __restrict__ deg) {
    int e = blockIdx.x * blockDim.x + threadIdx.x;
    if (e >= Ee) return;
    atomicAdd(&deg[ei[Ee + e]], 1);
}

__global__ void k_scan1(const int* __restrict__ deg, int* __restrict__ rp,
                        int* __restrict__ bsum, int n) {
    __shared__ int s[256];
    int tid = threadIdx.x;
    int base = blockIdx.x * 1024 + tid * 4;
    int v0 = (base < n) ? deg[base] : 0;
    int v1 = (base + 1 < n) ? deg[base + 1] : 0;
    int v2 = (base + 2 < n) ? deg[base + 2] : 0;
    int v3 = (base + 3 < n) ? deg[base + 3] : 0;
    int tsum = v0 + v1 + v2 + v3;
    s[tid] = tsum;
    __syncthreads();
    for (int off = 1; off < 256; off <<= 1) {
        int u = (tid >= off) ? s[tid - off] : 0;
        __syncthreads();
        s[tid] += u;
        __syncthreads();
    }
    int exc = s[tid] - tsum;
    if (base < n) rp[base] = exc;
    if (base + 1 < n) rp[base + 1] = exc + v0;
    if (base + 2 < n) rp[base + 2] = exc + v0 + v1;
    if (base + 3 < n) rp[base + 3] = exc + v0 + v1 + v2;
    if (tid == 255) bsum[blockIdx.x] = s[255];
}

__global__ void k_scan2(const int* __restrict__ bsum, int* __restrict__ boff,
                        int* __restrict__ rp, int nb, int n) {
    __shared__ int s[128];
    int tid = threadIdx.x;
    int v = (tid < nb) ? bsum[tid] : 0;
    s[tid] = v;
    __syncthreads();
    for (int off = 1; off < 128; off <<= 1) {
        int u = (tid >= off) ? s[tid - off] : 0;
        __syncthreads();
        s[tid] += u;
        __syncthreads();
    }
    if (tid < nb) boff[tid] = s[tid] - v;
    if (tid == 127) rp[n] = s[127];
}

__global__ void k_scan3(int* __restrict__ rp, const int* __restrict__ boff, int n) {
    int idx = blockIdx.x * blockDim.x + threadIdx.x;
    if (idx < n) rp[idx] += boff[idx >> 10];
}

__global__ void k_fill(const int* __restrict__ ei, const int* __restrict__ eattr,
                       int* __restrict__ woff, unsigned int* __restrict__ elist) {
    int e = blockIdx.x * blockDim.x + threadIdx.x;
    if (e >= Ee) return;
    int src = ei[e], dst = ei[Ee + e];
    int code = eattr[e * BF + 0] * 64 + eattr[e * BF + 1] * 8 + eattr[e * BF + 2];
    int p = atomicAdd(&woff[dst], 1);
    elist[p] = ((unsigned int)code << 17) | (unsigned int)src;
}

__global__ void k_cnt(const int* __restrict__ row, float* __restrict__ cnt, int M) {
    int m = blockIdx.x * blockDim.x + threadIdx.x;
    if (m >= M) return;
    atomicAdd(&cnt[row[m]], 1.f);
}

__global__ void k_inv(const float* __restrict__ cnt, float* __restrict__ rscale) {
    int r = blockIdx.x * blockDim.x + threadIdx.x;
    if (r >= Nn) return;
    rscale[r] = 1.f / fmaxf(cnt[r], 1.f);
}

__global__ void k_ebank(const float* __restrict__ bemb, float* __restrict__ ebank) {
    int idx = blockIdx.x * blockDim.x + threadIdx.x;
    if (idx >= 512 * H) return;
    int code = idx >> 7, h = idx & 127;
    int f0 = code >> 6, f1 = (code >> 3) & 7, f2 = code & 7;
    ebank[idx] = bemb[(0 * BV + f0) * H + h] + bemb[(1 * BV + f1) * H + h]
               + bemb[(2 * BV + f2) * H + h];
}

// GINE aggregation, gather form
__global__ __launch_bounds__(256) void k_agg_csr(
    const float* __restrict__ x, const int* __restrict__ rowptr,
    const unsigned int* __restrict__ elist, const float* __restrict__ ebank,
    const float* __restrict__ eps, int layer, float* __restrict__ agg)
{
    int a = blockIdx.x * 2 + (threadIdx.x >> 7);
    int h = threadIdx.x & 127;
    float acc = (1.f + eps[layer]) * x[(size_t)a * H + h];
    int j0 = rowptr[a], j1 = rowptr[a + 1];
    for (int j = j0; j < j1; ++j) {
        unsigned int u = elist[j];
        int src = u & 0x1FFFF;
        int code = u >> 17;
        acc += fmaxf(x[(size_t)src * H + h] + ebank[code * H + h], 0.f);
    }
    agg[(size_t)a * H + h] = acc;
}

// ---------------- misc elementwise ----------------

__global__ void k_bn_stats(const float* __restrict__ h, float* __restrict__ stats,
                           int M, int C, int rpb) {
    int c = threadIdx.x;
    int r0 = blockIdx.x * rpb;
    int r1 = min(r0 + rpb, M);
    float s = 0.f, sq = 0.f;
    for (int r = r0; r < r1; ++r) {
        float v = h[(size_t)r * C + c];
        s += v;
        sq += v * v;
    }
    atomicAdd(&stats[c], s);
    atomicAdd(&stats[C + c], sq);
}

__global__ void k_bn_apply(float* __restrict__ h, const float* __restrict__ stats,
                           const float* __restrict__ g, const float* __restrict__ b,
                           int M, int C) {
    int idx = blockIdx.x * blockDim.x + threadIdx.x;
    if (idx >= M * C) return;
    int c = idx & (C - 1);
    float mean = stats[c] / (float)M;
    float var = stats[C + c] / (float)M - mean * mean;
    float v = (h[idx] - mean) * rsqrtf(var + BN_EPS) * g[c] + b[c];
    h[idx] = fmaxf(v, 0.f);
}

__global__ void k_scatter_add(const float* __restrict__ xc, const int* __restrict__ row,
                              const float* __restrict__ rscale, float* __restrict__ sum,
                              int M) {
    int idx = blockIdx.x * blockDim.x + threadIdx.x;
    if (idx >= M * H) return;
    int m = idx >> 7, h = idx & 127;
    int r = row[m];
    atomicAdd(&sum[r * H + h], xc[idx] * rscale[r]);
}

// ---------------- generic MFMA GEMM (bf16x3, register-prefetch pipeline) ----------------
// out[m,n] = maybe_relu( sum_k A'[m,k]*B[k,n] + bias[n0+n] ) (+ res[row0+m,*])
// epi==1: accumulate column sum/sumsq into stats[n0+n], stats[Ncol+n0+n]

__global__ __launch_bounds__(256) void k_mgemm(
    const float* __restrict__ A, const __bf16* __restrict__ Bth,
    const __bf16* __restrict__ Btl, const float* __restrict__ bias,
    const float* __restrict__ res, float* __restrict__ out,
    const int* __restrict__ rowidx, float* __restrict__ stats,
    int M, int K, int Ncol, int pathk, int relu_flag, int row0, int epi)
{
    __shared__ __bf16 Ah[128 * 40], Al[128 * 40];
    __shared__ __bf16 Bh[128 * 40], Bl[128 * 40];
    __shared__ float sS[128], sQ[128];

    int t = threadIdx.x;
    int m0 = blockIdx.x * 128;
    int n0 = blockIdx.y * 128;
    int lane = t & 63;
    int q = lane >> 4;
    int lr = lane & 15;
    int wrow = (t >> 6) * 32;

    v4f acc[2][8] = {};

    int ar = t >> 1;
    int akq = (t & 1) * 16;
    int bn = t & 127;
    int bkb = (t >> 7) * 16;
    int gm = m0 + ar;

    float va[16];
    v8bf vbh0, vbh1, vbl0, vbl1;

    auto loadA = [&](int k0) {
        if (gm < M) {
            int kk = k0 + akq;
            const float* ap;
            if (pathk) {
                int g = row0 + gm;
                int cyc = g / pathk;
                int p = g - cyc * pathk;
                int sel = kk >> 7;
                int pp = p + sel - 1;
                if (pp < 0) pp += pathk;
                if (pp >= pathk) pp -= pathk;
                ap = A + (size_t)(cyc * pathk + pp) * H + (kk & 127);
            } else if (rowidx) {
                ap = A + (size_t)rowidx[gm] * H + kk;
            } else {
                ap = A + (size_t)gm * K + kk;
            }
#pragma unroll
            for (int i = 0; i < 4; ++i) {
                float4 f = *(const float4*)(ap + i * 4);
                va[i * 4 + 0] = f.x; va[i * 4 + 1] = f.y;
                va[i * 4 + 2] = f.z; va[i * 4 + 3] = f.w;
            }
        } else {
#pragma unroll
            for (int i = 0; i < 16; ++i) va[i] = 0.f;
        }
    };
    auto loadB = [&](int k0) {
        const __bf16* sh = Bth + (size_t)(n0 + bn) * K + k0 + bkb;
        const __bf16* sl = Btl + (size_t)(n0 + bn) * K + k0 + bkb;
        vbh0 = *(const v8bf*)sh;
        vbh1 = *(const v8bf*)(sh + 8);
        vbl0 = *(const v8bf*)sl;
        vbl1 = *(const v8bf*)(sl + 8);
    };

    loadA(0);
    loadB(0);
    int nk = K >> 5;
    for (int ki = 0; ki < nk; ++ki) {
        __syncthreads();  // prior tile's LDS reads complete
        {
            v8bf h0, h1, l0, l1;
#pragma unroll
            for (int i = 0; i < 8; ++i) {
                bfpair p0 = split2(va[i]);
                bfpair p1 = split2(va[8 + i]);
                h0[i] = p0.h; l0[i] = p0.l;
                h1[i] = p1.h; l1[i] = p1.l;
            }
            *(v8bf*)&Ah[ar * 40 + akq] = h0;
            *(v8bf*)&Ah[ar * 40 + akq + 8] = h1;
            *(v8bf*)&Al[ar * 40 + akq] = l0;
            *(v8bf*)&Al[ar * 40 + akq + 8] = l1;
            *(v8bf*)&Bh[bn * 40 + bkb] = vbh0;
            *(v8bf*)&Bh[bn * 40 + bkb + 8] = vbh1;
            *(v8bf*)&Bl[bn * 40 + bkb] = vbl0;
            *(v8bf*)&Bl[bn * 40 + bkb + 8] = vbl1;
        }
        __syncthreads();  // LDS tile ready
        if (ki + 1 < nk) {  // prefetch next tile; latency hides behind MFMA
            loadA((ki + 1) * 32);
            loadB((ki + 1) * 32);
        }
        v8bf ah[2], al2[2];
#pragma unroll
        for (int mt = 0; mt < 2; ++mt) {
            ah[mt] = *(v8bf*)&Ah[(wrow + mt * 16 + lr) * 40 + q * 8];
            al2[mt] = *(v8bf*)&Al[(wrow + mt * 16 + lr) * 40 + q * 8];
        }
#pragma unroll
        for (int nt = 0; nt < 8; ++nt) {
            v8bf bh = *(v8bf*)&Bh[(nt * 16 + lr) * 40 + q * 8];
            v8bf bl = *(v8bf*)&Bl[(nt * 16 + lr) * 40 + q * 8];
#pragma unroll
            for (int mt = 0; mt < 2; ++mt) {
                v4f a = acc[mt][nt];
                a = __builtin_amdgcn_mfma_f32_16x16x32_bf16(al2[mt], bh, a, 0, 0, 0);
                a = __builtin_amdgcn_mfma_f32_16x16x32_bf16(ah[mt], bl, a, 0, 0, 0);
                a = __builtin_amdgcn_mfma_f32_16x16x32_bf16(ah[mt], bh, a, 0, 0, 0);
                acc[mt][nt] = a;
            }
        }
    }

    if (epi == 0) {
        float bcol[8];
#pragma unroll
        for (int nt = 0; nt < 8; ++nt) bcol[nt] = bias[n0 + nt * 16 + lr];
#pragma unroll
        for (int mt = 0; mt < 2; ++mt)
#pragma unroll
            for (int reg = 0; reg < 4; ++reg) {
                int rm = m0 + wrow + mt * 16 + q * 4 + reg;
                if (rm < M) {
#pragma unroll
                    for (int nt = 0; nt < 8; ++nt) {
                        int cn = nt * 16 + lr;
                        float v = acc[mt][nt][reg] + bcol[nt];
                        if (relu_flag) v = fmaxf(v, 0.f);
                        if (res) v += res[(size_t)(row0 + rm) * Ncol + n0 + cn];
                        out[(size_t)rm * Ncol + n0 + cn] = v;
                    }
                }
            }
    } else {
        if (t < 128) { sS[t] = 0.f; sQ[t] = 0.f; }
        __syncthreads();
        float bcol[8];
#pragma unroll
        for (int nt = 0; nt < 8; ++nt) bcol[nt] = bias[n0 + nt * 16 + lr];
#pragma unroll
        for (int nt = 0; nt < 8; ++nt) {
            float s = 0.f, q2 = 0.f;
#pragma unroll
            for (int mt = 0; mt < 2; ++mt)
#pragma unroll
                for (int reg = 0; reg < 4; ++reg) {
                    int rm = m0 + wrow + mt * 16 + q * 4 + reg;
                    if (rm < M) {
                        float v = acc[mt][nt][reg] + bcol[nt];
                        s += v;
                        q2 += v * v;
                    }
                }
            atomicAdd(&sS[nt * 16 + lr], s);
            atomicAdd(&sQ[nt * 16 + lr], q2);
        }
        __syncthreads();
        if (t < 128) {
            atomicAdd(&stats[n0 + t], sS[t]);
            atomicAdd(&stats[Ncol + n0 + t], sQ[t]);
        }
    }
}

// ---------------- fused GINE MLP via MFMA (register-prefetch) ----------------

__global__ __launch_bounds__(256) void k_mlp_mfma(
    const float* __restrict__ hin,
    const __bf16* __restrict__ g1h, const __bf16* __restrict__ g1l,
    const float* __restrict__ gb1, const float* __restrict__ gbn_g,
    const float* __restrict__ gbn_b,
    const __bf16* __restrict__ g2h, const __bf16* __restrict__ g2l,
    const float* __restrict__ gb2, const float* __restrict__ stats,
    float* __restrict__ xout)
{
    __shared__ __bf16 Ah[32 * 136], Al[32 * 136];
    __shared__ __bf16 Bh[128 * 40], Bl[128 * 40];
    __shared__ __bf16 Th[32 * 264], Tl[32 * 264];
    __shared__ float sc[256], sh[256];

    int t = threadIdx.x;
    int r0 = blockIdx.x * 32;
    int lane = t & 63;
    int q = lane >> 4;
    int lr = lane & 15;
    int w = t >> 6;

    {
        float mean = stats[t] * (1.f / (float)Nn);
        float var = stats[256 + t] * (1.f / (float)Nn) - mean * mean;
        float s = gbn_g[t] * rsqrtf(var + BN_EPS);
        sc[t] = s;
        sh[t] = (gb1[t] - mean) * s + gbn_b[t];
    }
    {
        int r = t >> 3;
        int kq = (t & 7) * 16;
        const float* ap = hin + (size_t)(r0 + r) * H + kq;
        v8bf h0, h1, l0, l1;
#pragma unroll
        for (int i = 0; i < 8; ++i) {
            bfpair p0 = split2(ap[i]);
            bfpair p1 = split2(ap[8 + i]);
            h0[i] = p0.h; l0[i] = p0.l;
            h1[i] = p1.h; l1[i] = p1.l;
        }
        *(v8bf*)&Ah[r * 136 + kq] = h0;
        *(v8bf*)&Ah[r * 136 + kq + 8] = h1;
        *(v8bf*)&Al[r * 136 + kq] = l0;
        *(v8bf*)&Al[r * 136 + kq + 8] = l1;
    }

    int bn = t & 127;
    int bkb = (t >> 7) * 16;
    v8bf vbh0, vbh1, vbl0, vbl1;

    auto load1 = [&](int p, int k0) {  // gw1 slab; planes [n=256][k=128]
        const __bf16* shp = g1h + (size_t)(p * 128 + bn) * 128 + k0 + bkb;
        const __bf16* slp = g1l + (size_t)(p * 128 + bn) * 128 + k0 + bkb;
        vbh0 = *(const v8bf*)shp;
        vbh1 = *(const v8bf*)(shp + 8);
        vbl0 = *(const v8bf*)slp;
        vbl1 = *(const v8bf*)(slp + 8);
    };
    auto load2 = [&](int k0) {  // gw2 slab; planes [n=128][k=256]
        const __bf16* shp = g2h + (size_t)bn * 256 + k0 + bkb;
        const __bf16* slp = g2l + (size_t)bn * 256 + k0 + bkb;
        vbh0 = *(const v8bf*)shp;
        vbh1 = *(const v8bf*)(shp + 8);
        vbl0 = *(const v8bf*)slp;
        vbl1 = *(const v8bf*)(slp + 8);
    };
    auto storeB = [&]() {
        *(v8bf*)&Bh[bn * 40 + bkb] = vbh0;
        *(v8bf*)&Bh[bn * 40 + bkb + 8] = vbh1;
        *(v8bf*)&Bl[bn * 40 + bkb] = vbl0;
        *(v8bf*)&Bl[bn * 40 + bkb + 8] = vbl1;
    };

    load1(0, 0);
    // stage 1: T = relu(BN1(hin@gw1)), two 128-col panels
    for (int p = 0; p < 2; ++p) {
        v4f acc[2][2] = {};
        for (int k0 = 0; k0 < 128; k0 += 32) {
            __syncthreads();
            storeB();
            __syncthreads();
            int s = p * 4 + (k0 >> 5) + 1;
            if (s < 8) load1(s >> 2, (s & 3) * 32);
            else load2(0);
            v8bf ah[2], al2[2], bh[2], bl2[2];
#pragma unroll
            for (int mt = 0; mt < 2; ++mt) {
                ah[mt] = *(v8bf*)&Ah[(mt * 16 + lr) * 136 + k0 + q * 8];
                al2[mt] = *(v8bf*)&Al[(mt * 16 + lr) * 136 + k0 + q * 8];
            }
#pragma unroll
            for (int nt = 0; nt < 2; ++nt) {
                bh[nt] = *(v8bf*)&Bh[(w * 32 + nt * 16 + lr) * 40 + q * 8];
                bl2[nt] = *(v8bf*)&Bl[(w * 32 + nt * 16 + lr) * 40 + q * 8];
            }
#pragma unroll
            for (int mt = 0; mt < 2; ++mt)
#pragma unroll
                for (int nt = 0; nt < 2; ++nt) {
                    v4f a = acc[mt][nt];
                    a = __builtin_amdgcn_mfma_f32_16x16x32_bf16(al2[mt], bh[nt], a, 0, 0, 0);
                    a = __builtin_amdgcn_mfma_f32_16x16x32_bf16(ah[mt], bl2[nt], a, 0, 0, 0);
                    a = __builtin_amdgcn_mfma_f32_16x16x32_bf16(ah[mt], bh[nt], a, 0, 0, 0);
                    acc[mt][nt] = a;
                }
        }
#pragma unroll
        for (int mt = 0; mt < 2; ++mt)
#pragma unroll
            for (int nt = 0; nt < 2; ++nt)
#pragma unroll
                for (int reg = 0; reg < 4; ++reg) {
                    int row = mt * 16 + q * 4 + reg;
                    int col = p * 128 + w * 32 + nt * 16 + lr;
                    float v = fmaxf(acc[mt][nt][reg] * sc[col] + sh[col], 0.f);
                    bfpair pr = split2(v);
                    Th[row * 264 + col] = pr.h;
                    Tl[row * 264 + col] = pr.l;
                }
    }

    // stage 2: x = T @ gw2 + gb2
    v4f acc2[2][2] = {};
    for (int k0 = 0; k0 < 256; k0 += 32) {
        __syncthreads();  // also covers T-panel writes on first iter
        storeB();
        __syncthreads();
        if (k0 + 32 < 256) load2(k0 + 32);
        v8bf ah[2], al2[2], bh[2], bl2[2];
#pragma unroll
        for (int mt = 0; mt < 2; ++mt) {
            ah[mt] = *(v8bf*)&Th[(mt * 16 + lr) * 264 + k0 + q * 8];
            al2[mt] = *(v8bf*)&Tl[(mt * 16 + lr) * 264 + k0 + q * 8];
        }
#pragma unroll
        for (int nt = 0; nt < 2; ++nt) {
            bh[nt] = *(v8bf*)&Bh[(w * 32 + nt * 16 + lr) * 40 + q * 8];
            bl2[nt] = *(v8bf*)&Bl[(w * 32 + nt * 16 + lr) * 40 + q * 8];
        }
#pragma unroll
        for (int mt = 0; mt < 2; ++mt)
#pragma unroll
            for (int nt = 0; nt < 2; ++nt) {
                v4f a = acc2[mt][nt];
                a = __builtin_amdgcn_mfma_f32_16x16x32_bf16(al2[mt], bh[nt], a, 0, 0, 0);
                a = __builtin_amdgcn_mfma_f32_16x16x32_bf16(ah[mt], bl2[nt], a, 0, 0, 0);
                a = __builtin_amdgcn_mfma_f32_16x16x32_bf16(ah[mt], bh[nt], a, 0, 0, 0);
                acc2[mt][nt] = a;
            }
    }
#pragma unroll
    for (int mt = 0; mt < 2; ++mt)
#pragma unroll
        for (int nt = 0; nt < 2; ++nt)
#pragma unroll
            for (int reg = 0; reg < 4; ++reg) {
                int row = mt * 16 + q * 4 + reg;
                int col = w * 32 + nt * 16 + lr;
                xout[(size_t)(r0 + row) * H + col] = acc2[mt][nt][reg] + gb2[col];
            }
}

// ---------------- readout ----------------

__global__ void k_seg_batch(const float* __restrict__ x, const int* __restrict__ batch,
                            float* __restrict__ xgsum, float* __restrict__ gcnt) {
    int h = threadIdx.x;
    int r0 = blockIdx.x * 256;
    if (r0 >= Nn) return;
    int r1 = min(r0 + 256, Nn);
    int cur = batch[r0];
    float acc = 0.f, c = 0.f;
    for (int r = r0; r < r1; ++r) {
        int b = batch[r];
        if (b != cur) {
            atomicAdd(&xgsum[cur * H + h], acc);
            if (h == 0) atomicAdd(&gcnt[cur], c);
            acc = 0.f;
            c = 0.f;
            cur = b;
        }
        acc += x[r * H + h];
        c += 1.f;
    }
    atomicAdd(&xgsum[cur * H + h], acc);
    if (h == 0) atomicAdd(&gcnt[cur], c);
}

__global__ void k_head(const float* __restrict__ xgsum, const float* __restrict__ gcnt,
                       const float* __restrict__ alw, const float* __restrict__ alb,
                       const float* __restrict__ lw, const float* __restrict__ lb,
                       float* __restrict__ out) {
    __shared__ float mean[H];
    __shared__ float red[H];
    int g = blockIdx.x, j = threadIdx.x;
    mean[j] = xgsum[g * H + j] / fmaxf(gcnt[g], 1.f);
    __syncthreads();
    float acc = alb[j];
    for (int k = 0; k < H; ++k) acc += mean[k] * alw[k * H + j];
    acc = fmaxf(acc, 0.f) * lw[j];
    red[j] = acc;
    __syncthreads();
    for (int s = 64; s > 0; s >>= 1) {
        if (j < s) red[j] += red[j + s];
        __syncthreads();
    }
    if (j == 0) out[g] = red[0] + lb[0];
}

// ---------------- host ----------------

extern "C" void kernel_launch(void* const* d_in, const int* in_sizes, int n_in,
                              void* d_out, int out_size, void* d_ws, size_t ws_size,
                              hipStream_t stream) {
    const int* x_atom = (const int*)d_in[0];
    const int* ei = (const int*)d_in[1];
    const int* eattr = (const int*)d_in[2];
    const int* batch = (const int*)d_in[3];
    const int* xc5 = (const int*)d_in[4];
    const int* xc6 = (const int*)d_in[5];
    const int* a2c5_row = (const int*)d_in[6];
    const int* a2c6_row = (const int*)d_in[8];
    const float* atom_emb = (const float*)d_in[10];
    const float* bond_emb = (const float*)d_in[11];
    const float* cyc5 = (const float*)d_in[12];
    const float* cyc6 = (const float*)d_in[13];
    const float* eps = (const float*)d_in[14];
    const float* gw1 = (const float*)d_in[15];
    const float* gb1 = (const float*)d_in[16];
    const float* gbn_g = (const float*)d_in[17];
    const float* gbn_b = (const float*)d_in[18];
    const float* gw2 = (const float*)d_in[19];
    const float* gb2 = (const float*)d_in[20];
    const float* bn_g = (const float*)d_in[21];
    const float* bn_b = (const float*)d_in[22];
    const float* a2c5_w = (const float*)d_in[23];
    const float* a2c5_b = (const float*)d_in[24];
    const float* a2c6_w = (const float*)d_in[25];
    const float* a2c6_b = (const float*)d_in[26];
    const float* c2a5_w = (const float*)d_in[27];
    const float* c2a5_b = (const float*)d_in[28];
    const float* c2a6_w = (const float*)d_in[29];
    const float* c2a6_b = (const float*)d_in[30];
    const float* p5_w = (const float*)d_in[31];
    const float* p5_b = (const float*)d_in[32];
    const float* p6_w = (const float*)d_in[33];
    const float* p6_b = (const float*)d_in[34];
    const float* alw = (const float*)d_in[35];
    const float* alb = (const float*)d_in[36];
    const float* lw = (const float*)d_in[37];
    const float* lb = (const float*)d_in[38];
    float* out = (float*)d_out;

    float* w = (float*)d_ws;
    size_t o = 0;
    auto alloc = [&](size_t nf) {
        float* p = w + o;
        o += (nf + 63) & ~(size_t)63;
        return p;
    };
    auto allocb = [&](size_t nbf) { return (__bf16*)alloc((nbf + 1) / 2); };
    float* x = alloc((size_t)Nn * H);
    float* x5 = alloc((size_t)N5c * 5 * H);
    float* x6 = alloc((size_t)N6c * 6 * H);
    float* agg = alloc((size_t)Nn * H);
    float* stats = alloc(512);
    float* xgsum = alloc((size_t)Gg * H);
    float* gcnt = alloc(Gg);
    float* cnt = alloc(Nn);
    float* rscale5 = alloc(Nn);
    float* rscale6 = alloc(Nn);
    int* deg = (int*)alloc(Nn);
    int* rowptr = (int*)alloc(Nn + 1);
    int* woff = (int*)alloc(Nn);
    int* bsum = (int*)alloc(256);
    int* boff = (int*)alloc(256);
    unsigned int* elist = (unsigned int*)alloc(Ee);
    float* ebank = alloc(512 * H);
    __bf16 *g1h = allocb(3 * 128 * 256), *g1l = allocb(3 * 128 * 256);
    __bf16 *g2h = allocb(3 * 256 * 128), *g2l = allocb(3 * 256 * 128);
    __bf16 *a5h = allocb(3 * 128 * 128), *a5l = allocb(3 * 128 * 128);
    __bf16 *a6h = allocb(3 * 128 * 128), *a6l = allocb(3 * 128 * 128);
    __bf16 *c5h = allocb(3 * 128 * 128), *c5l = allocb(3 * 128 * 128);
    __bf16 *c6h = allocb(3 * 128 * 128), *c6l = allocb(3 * 128 * 128);
    __bf16 *p5h = allocb(3 * 384 * 128), *p5l = allocb(3 * 384 * 128);
    __bf16 *p6h = allocb(3 * 384 * 128), *p6l = allocb(3 * 384 * 128);

    // optional ping-pong path buffers (runtime ws check; fallback = chunked memcpy)
    size_t extra = (((size_t)N5c * 5 * H + 63) & ~(size_t)63) +
                   (((size_t)N6c * 6 * H + 63) & ~(size_t)63);
    bool pp = (o + extra) * sizeof(float) <= ws_size;
    float* x5b = nullptr;
    float* x6b = nullptr;
    if (pp) {
        x5b = alloc((size_t)N5c * 5 * H);
        x6b = alloc((size_t)N6c * 6 * H);
    }

    const int TPB = 256;
    auto cdiv = [](int a, int b) { return (a + b - 1) / b; };

    // weight pre-split
    k_split<<<cdiv(3 * 128 * 256, TPB), TPB, 0, stream>>>(gw1, g1h, g1l, 3, 128, 256);
    k_split<<<cdiv(3 * 256 * 128, TPB), TPB, 0, stream>>>(gw2, g2h, g2l, 3, 256, 128);
    k_split<<<cdiv(3 * 128 * 128, TPB), TPB, 0, stream>>>(a2c5_w, a5h, a5l, 3, 128, 128);
    k_split<<<cdiv(3 * 128 * 128, TPB), TPB, 0, stream>>>(a2c6_w, a6h, a6l, 3, 128, 128);
    k_split<<<cdiv(3 * 128 * 128, TPB), TPB, 0, stream>>>(c2a5_w, c5h, c5l, 3, 128, 128);
    k_split<<<cdiv(3 * 128 * 128, TPB), TPB, 0, stream>>>(c2a6_w, c6h, c6l, 3, 128, 128);
    k_split<<<cdiv(3 * 384 * 128, TPB), TPB, 0, stream>>>(p5_w, p5h, p5l, 3, 384, 128);
    k_split<<<cdiv(3 * 384 * 128, TPB), TPB, 0, stream>>>(p6_w, p6h, p6l, 3, 384, 128);

    // CSR build (hierarchical scan)
    hipMemsetAsync(deg, 0, Nn * 4, stream);
    k_deg<<<cdiv(Ee, TPB), TPB, 0, stream>>>(ei, deg);
    int nsb = cdiv(Nn, 1024);
    k_scan1<<<nsb, 256, 0, stream>>>(deg, rowptr, bsum, Nn);
    k_scan2<<<1, 128, 0, stream>>>(bsum, boff, rowptr, nsb, Nn);
    k_scan3<<<cdiv(Nn, TPB), TPB, 0, stream>>>(rowptr, boff, Nn);
    hipMemcpyAsync(woff, rowptr, Nn * 4, hipMemcpyDeviceToDevice, stream);
    k_fill<<<cdiv(Ee, TPB), TPB, 0, stream>>>(ei, eattr, woff, elist);

    // static scatter-mean scales
    hipMemsetAsync(cnt, 0, Nn * 4, stream);
    k_cnt<<<cdiv(N5c * 5, TPB), TPB, 0, stream>>>(a2c5_row, cnt, N5c * 5);
    k_inv<<<cdiv(Nn, TPB), TPB, 0, stream>>>(cnt, rscale5);
    hipMemsetAsync(cnt, 0, Nn * 4, stream);
    k_cnt<<<cdiv(N6c * 6, TPB), TPB, 0, stream>>>(a2c6_row, cnt, N6c * 6);
    k_inv<<<cdiv(Nn, TPB), TPB, 0, stream>>>(cnt, rscale6);

    k_atom_enc<<<cdiv(Nn * H, TPB), TPB, 0, stream>>>(x_atom, atom_emb, x);
    k_cyc_init<<<cdiv(N5c * 5 * H, TPB), TPB, 0, stream>>>(xc5, cyc5, x5, N5c * 5);
    k_cyc_init<<<cdiv(N6c * 6 * H, TPB), TPB, 0, stream>>>(xc6, cyc6, x6, N6c * 6);

    float* x5c = x5;
    float* x6c = x6;
    for (int i = 0; i < Ll; ++i) {
        // GINE aggregation (gather)
        k_ebank<<<cdiv(512 * H, TPB), TPB, 0, stream>>>(
            bond_emb + (size_t)i * BF * BV * H, ebank);
        k_agg_csr<<<Nn / 2, 256, 0, stream>>>(x, rowptr, elist, ebank, eps, i, agg);

        // BN1 stats via epi-GEMM
        hipMemsetAsync(stats, 0, 512 * 4, stream);
        dim3 gst(cdiv(Nn, 128), 2);
        k_mgemm<<<gst, 256, 0, stream>>>(agg, g1h + (size_t)i * 128 * 256,
                                         g1l + (size_t)i * 128 * 256,
                                         gb1 + (size_t)i * 256, nullptr, nullptr,
                                         nullptr, stats, Nn, 128, 256, 0, 0, 0, 1);

        // fused MLP -> x (pre-BN2)
        k_mlp_mfma<<<Nn / 32, 256, 0, stream>>>(
            agg, g1h + (size_t)i * 128 * 256, g1l + (size_t)i * 128 * 256,
            gb1 + (size_t)i * 256, gbn_g + (size_t)i * 256, gbn_b + (size_t)i * 256,
            g2h + (size_t)i * 256 * 128, g2l + (size_t)i * 256 * 128,
            gb2 + (size_t)i * H, stats, x);

        // BN2 + relu
        hipMemsetAsync(stats, 0, 512 * 4, stream);
        k_bn_stats<<<cdiv(Nn, 64), H, 0, stream>>>(x, stats, Nn, H, 64);
        k_bn_apply<<<cdiv(Nn * H, TPB), TPB, 0, stream>>>(
            x, stats, bn_g + (size_t)i * H, bn_b + (size_t)i * H, Nn, H);

        // atoms -> cycles
        k_mgemm<<<dim3(cdiv(N5c * 5, 128), 1), 256, 0, stream>>>(
            x, a5h + (size_t)i * 128 * 128, a5l + (size_t)i * 128 * 128,
            a2c5_b + (size_t)i * H, x5c, x5c, a2c5_row, nullptr,
            N5c * 5, 128, 128, 0, 1, 0, 0);
        k_mgemm<<<dim3(cdiv(N6c * 6, 128), 1), 256, 0, stream>>>(
            x, a6h + (size_t)i * 128 * 128, a6l + (size_t)i * 128 * 128,
            a2c6_b + (size_t)i * H, x6c, x6c, a2c6_row, nullptr,
            N6c * 6, 128, 128, 0, 1, 0, 0);

        // cyclic path blocks
        if (pp) {
            float* x5n = (x5c == x5) ? x5b : x5;
            k_mgemm<<<dim3(cdiv(N5c * 5, 128), 1), 256, 0, stream>>>(
                x5c, p5h + (size_t)i * 384 * 128, p5l + (size_t)i * 384 * 128,
                p5_b + (size_t)i * H, x5c, x5n, nullptr, nullptr,
                N5c * 5, 384, 128, 5, 1, 0, 0);
            x5c = x5n;
            float* x6n = (x6c == x6) ? x6b : x6;
            k_mgemm<<<dim3(cdiv(N6c * 6, 128), 1), 256, 0, stream>>>(
                x6c, p6h + (size_t)i * 384 * 128, p6l + (size_t)i * 384 * 128,
                p6_b + (size_t)i * H, x6c, x6n, nullptr, nullptr,
                N6c * 6, 384, 128, 6, 1, 0, 0);
            x6c = x6n;
        } else {
            k_mgemm<<<dim3(cdiv(N5c * 5, 128), 1), 256, 0, stream>>>(
                x5c, p5h + (size_t)i * 384 * 128, p5l + (size_t)i * 384 * 128,
                p5_b + (size_t)i * H, x5c, agg, nullptr, nullptr,
                N5c * 5, 384, 128, 5, 1, 0, 0);
            hipMemcpyAsync(x5c, agg, (size_t)N5c * 5 * H * 4, hipMemcpyDeviceToDevice, stream);
            const int C6 = (N6c / 2) * 6;
            for (int ch = 0; ch < 2; ++ch) {
                k_mgemm<<<dim3(cdiv(C6, 128), 1), 256, 0, stream>>>(
                    x6c, p6h + (size_t)i * 384 * 128, p6l + (size_t)i * 384 * 128,
                    p6_b + (size_t)i * H, x6c, agg, nullptr, nullptr,
                    C6, 384, 128, 6, 1, ch * C6, 0);
                hipMemcpyAsync(x6c + (size_t)ch * C6 * H, agg, (size_t)C6 * H * 4,
                               hipMemcpyDeviceToDevice, stream);
            }
        }

        // cycles -> atoms
        hipMemsetAsync(agg, 0, (size_t)Nn * H * 4, stream);
        k_scatter_add<<<cdiv(N5c * 5 * H, TPB), TPB, 0, stream>>>(
            x5c, a2c5_row, rscale5, agg, N5c * 5);
        k_mgemm<<<dim3(cdiv(Nn, 128), 1), 256, 0, stream>>>(
            agg, c5h + (size_t)i * 128 * 128, c5l + (size_t)i * 128 * 128,
            c2a5_b + (size_t)i * H, x, x, nullptr, nullptr,
            Nn, 128, 128, 0, 1, 0, 0);
        hipMemsetAsync(agg, 0, (size_t)Nn * H * 4, stream);
        k_scatter_add<<<cdiv(N6c * 6 * H, TPB), TPB, 0, stream>>>(
            x6c, a2c6_row, rscale6, agg, N6c * 6);
        k_mgemm<<<dim3(cdiv(Nn, 128), 1), 256, 0, stream>>>(
            agg, c6h + (size_t)i * 128 * 128, c6l + (size_t)i * 128 * 128,
            c2a6_b + (size_t)i * H, x, x, nullptr, nullptr,
            Nn, 128, 128, 0, 1, 0, 0);
    }

    // readout
    hipMemsetAsync(xgsum, 0, (size_t)Gg * H * 4, stream);
    hipMemsetAsync(gcnt, 0, (size_t)Gg * 4, stream);
    k_seg_batch<<<cdiv(Nn, 256), H, 0, stream>>>(x, batch, xgsum, gcnt);
    k_head<<<Gg, H, 0, stream>>>(xgsum, gcnt, alw, alb, lw, lb, out);
}

// Round 8
// 2750.802 us; speedup vs baseline: 1.4638x; 1.1507x over previous
//
#include <hip/hip_runtime.h>

#define H 128
#define Nn 100000
#define Ee 250000
#define N5c 20000
#define N6c 30000
#define Gg 512
#define Ll 3
#define AF 9
#define AV 64
#define BF 3
#define BV 8
#define BN_EPS 1e-5f

typedef __bf16 v8bf __attribute__((ext_vector_type(8)));
typedef float v4f __attribute__((ext_vector_type(4)));

struct bfpair { __bf16 h, l; };
__device__ inline bfpair split2(float v) {
    bfpair r;
    r.h = (__bf16)v;
    r.l = (__bf16)(v - (float)r.h);
    return r;
}

// ---------------- init / embedding kernels ----------------

__global__ void k_atom_enc(const int* __restrict__ xa, const float* __restrict__ emb,
                           float* __restrict__ x) {
    int idx = blockIdx.x * blockDim.x + threadIdx.x;
    if (idx >= Nn * H) return;
    int n = idx >> 7, h = idx & 127;
    float s = 0.f;
#pragma unroll
    for (int f = 0; f < AF; ++f) {
        int a = xa[n * AF + f];
        s += emb[(f * AV + a) * H + h];
    }
    x[idx] = s;
}

__global__ void k_cyc_init(const int* __restrict__ xc, const float* __restrict__ emb,
                           float* __restrict__ xo, int M) {
    int idx = blockIdx.x * blockDim.x + threadIdx.x;
    if (idx >= M * H) return;
    int m = idx >> 7, h = idx & 127;
    xo[idx] = emb[xc[m] * H + h];
}

// weight pre-split: (L,K,N) fp32 row-major -> per-layer transposed [n][k] bf16 hi/lo
__global__ void k_split(const float* __restrict__ src, __bf16* __restrict__ dh,
                        __bf16* __restrict__ dl, int L, int K, int N) {
    int idx = blockIdx.x * blockDim.x + threadIdx.x;
    int tot = L * K * N;
    if (idx >= tot) return;
    int l = idx / (K * N);
    int r = idx - l * (K * N);
    int k = r / N;
    int n = r - k * N;
    bfpair p = split2(src[idx]);
    size_t d = (size_t)l * K * N + (size_t)n * K + k;
    dh[d] = p.h;
    dl[d] = p.l;
}

// ---------------- CSR build helpers (edge + cycle maps; all static) ----------------

__global__ void k_degi(const int* __restrict__ row, int* __restrict__ deg, int M) {
    int m = blockIdx.x * blockDim.x + threadIdx.x;
    if (m >= M) return;
    atomicAdd(&deg[row[m]], 1);
}

__global__ void k_scan1(const int* __restrict__ deg, int* __restrict__ rp,
                        int* __restrict__ bsum, int n) {
    __shared__ int s[256];
    int tid = threadIdx.x;
    int base = blockIdx.x * 1024 + tid * 4;
    int v0 = (base < n) ? deg[base] : 0;
    int v1 = (base + 1 < n) ? deg[base + 1] : 0;
    int v2 = (base + 2 < n) ? deg[base + 2] : 0;
    int v3 = (base + 3 < n) ? deg[base + 3] : 0;
    int tsum = v0 + v1 + v2 + v3;
    s[tid] = tsum;
    __syncthreads();
    for (int off = 1; off < 256; off <<= 1) {
        int u = (tid >= off) ? s[tid - off] : 0;
        __syncthreads();
        s[tid] += u;
        __syncthreads();
    }
    int exc = s[tid] - tsum;
    if (base < n) rp[base] = exc;
    if (base + 1 < n) rp[base + 1] = exc + v0;
    if (base + 2 < n) rp[base + 2] = exc + v0 + v1;
    if (base + 3 < n) rp[base + 3] = exc + v0 + v1 + v2;
    if (tid == 255) bsum[blockIdx.x] = s[255];
}

__global__ void k_scan2(const int* __restrict__ bsum, int* __restrict__ boff,
                        int* __restrict__ rp, int nb, int n) {
    __shared__ int s[128];
    int tid = threadIdx.x;
    int v = (tid < nb) ? bsum[tid] : 0;
    s[tid] = v;
    __syncthreads();
    for (int off = 1; off < 128; off <<= 1) {
        int u = (tid >= off) ? s[tid - off] : 0;
        __syncthreads();
        s[tid] += u;
        __syncthreads();
    }
    if (tid < nb) boff[tid] = s[tid] - v;
    if (tid == 127) rp[n] = s[127];
}

__global__ void k_scan3(int* __restrict__ rp, const int* __restrict__ boff, int n) {
    int idx = blockIdx.x * blockDim.x + threadIdx.x;
    if (idx < n) rp[idx] += boff[idx >> 10];
}

__global__ void k_fill(const int* __restrict__ ei, const int* __restrict__ eattr,
                       int* __restrict__ woff, unsigned int* __restrict__ elist) {
    int e = blockIdx.x * blockDim.x + threadIdx.x;
    if (e >= Ee) return;
    int src = ei[e], dst = ei[Ee + e];
    int code = eattr[e * BF + 0] * 64 + eattr[e * BF + 1] * 8 + eattr[e * BF + 2];
    int p = atomicAdd(&woff[dst], 1);
    elist[p] = ((unsigned int)code << 17) | (unsigned int)src;
}

__global__ void k_fill_idx(const int* __restrict__ row, int* __restrict__ woff,
                           int* __restrict__ cidx, int M) {
    int m = blockIdx.x * blockDim.x + threadIdx.x;
    if (m >= M) return;
    int p = atomicAdd(&woff[row[m]], 1);
    cidx[p] = m;
}

__global__ void k_inv_int(const int* __restrict__ deg, float* __restrict__ rscale) {
    int r = blockIdx.x * blockDim.x + threadIdx.x;
    if (r >= Nn) return;
    rscale[r] = 1.f / fmaxf((float)deg[r], 1.f);
}

__global__ void k_ebank(const float* __restrict__ bemb, float* __restrict__ ebank) {
    int idx = blockIdx.x * blockDim.x + threadIdx.x;
    if (idx >= 512 * H) return;
    int code = idx >> 7, h = idx & 127;
    int f0 = code >> 6, f1 = (code >> 3) & 7, f2 = code & 7;
    ebank[idx] = bemb[(0 * BV + f0) * H + h] + bemb[(1 * BV + f1) * H + h]
               + bemb[(2 * BV + f2) * H + h];
}

// GINE aggregation, gather form
__global__ __launch_bounds__(256) void k_agg_csr(
    const float* __restrict__ x, const int* __restrict__ rowptr,
    const unsigned int* __restrict__ elist, const float* __restrict__ ebank,
    const float* __restrict__ eps, int layer, float* __restrict__ agg)
{
    int a = blockIdx.x * 2 + (threadIdx.x >> 7);
    int h = threadIdx.x & 127;
    float acc = (1.f + eps[layer]) * x[(size_t)a * H + h];
    int j0 = rowptr[a], j1 = rowptr[a + 1];
    for (int j = j0; j < j1; ++j) {
        unsigned int u = elist[j];
        int src = u & 0x1FFFF;
        int code = u >> 17;
        acc += fmaxf(x[(size_t)src * H + h] + ebank[code * H + h], 0.f);
    }
    agg[(size_t)a * H + h] = acc;
}

// ---------------- misc elementwise ----------------

__global__ void k_bn_stats(const float* __restrict__ h, float* __restrict__ stats,
                           int M, int C, int rpb) {
    int c = threadIdx.x;
    int r0 = blockIdx.x * rpb;
    int r1 = min(r0 + rpb, M);
    float s = 0.f, sq = 0.f;
    for (int r = r0; r < r1; ++r) {
        float v = h[(size_t)r * C + c];
        s += v;
        sq += v * v;
    }
    atomicAdd(&stats[c], s);
    atomicAdd(&stats[C + c], sq);
}

__global__ void k_bn_apply(float* __restrict__ h, const float* __restrict__ stats,
                           const float* __restrict__ g, const float* __restrict__ b,
                           int M, int C) {
    int idx = blockIdx.x * blockDim.x + threadIdx.x;
    if (idx >= M * C) return;
    int c = idx & (C - 1);
    float mean = stats[c] / (float)M;
    float var = stats[C + c] / (float)M - mean * mean;
    float v = (h[idx] - mean) * rsqrtf(var + BN_EPS) * g[c] + b[c];
    h[idx] = fmaxf(v, 0.f);
}

// ---------------- generic MFMA GEMM (bf16x3, register-prefetch pipeline) ----------------
// A-modes: pathk>0 = cyclic-conv gather (block covers whole cycles; mtile rows/block,
//          in-place safe); grp/gcol/gscale = CSR mean-gather; rowidx = row gather;
//          else direct. epi==1 accumulates BN stats instead of writing out.

__global__ __launch_bounds__(256) void k_mgemm(
    const float* __restrict__ A, const __bf16* __restrict__ Bth,
    const __bf16* __restrict__ Btl, const float* __restrict__ bias,
    const float* __restrict__ res, float* __restrict__ out,
    const int* __restrict__ rowidx, const int* __restrict__ grp,
    const int* __restrict__ gcol, const float* __restrict__ gscale,
    float* __restrict__ stats,
    int M, int K, int Ncol, int pathk, int mtile, int relu_flag, int epi)
{
    __shared__ __bf16 Ah[128 * 40], Al[128 * 40];
    __shared__ __bf16 Bh[128 * 40], Bl[128 * 40];
    __shared__ float sS[128], sQ[128];

    int t = threadIdx.x;
    int m0 = blockIdx.x * mtile;
    int n0 = blockIdx.y * 128;
    int lane = t & 63;
    int q = lane >> 4;
    int lr = lane & 15;
    int wrow = (t >> 6) * 32;

    v4f acc[2][8] = {};

    int ar = t >> 1;
    int akq = (t & 1) * 16;
    int bn = t & 127;
    int bkb = (t >> 7) * 16;
    int gm = m0 + ar;
    bool av = (ar < mtile) && (gm < M);

    float va[16];
    v8bf vbh0, vbh1, vbl0, vbl1;

    auto loadA = [&](int k0) {
#pragma unroll
        for (int i = 0; i < 16; ++i) va[i] = 0.f;
        if (av) {
            int kk = k0 + akq;
            if (grp) {
                int j0 = grp[gm], j1 = grp[gm + 1];
                for (int j = j0; j < j1; ++j) {
                    const float* ap = A + (size_t)gcol[j] * H + kk;
#pragma unroll
                    for (int i = 0; i < 4; ++i) {
                        float4 f = *(const float4*)(ap + i * 4);
                        va[i * 4 + 0] += f.x; va[i * 4 + 1] += f.y;
                        va[i * 4 + 2] += f.z; va[i * 4 + 3] += f.w;
                    }
                }
                float s = gscale[gm];
#pragma unroll
                for (int i = 0; i < 16; ++i) va[i] *= s;
            } else {
                const float* ap;
                if (pathk) {
                    int cyc = gm / pathk;
                    int p = gm - cyc * pathk;
                    int sel = kk >> 7;
                    int pp = p + sel - 1;
                    if (pp < 0) pp += pathk;
                    if (pp >= pathk) pp -= pathk;
                    ap = A + (size_t)(cyc * pathk + pp) * H + (kk & 127);
                } else if (rowidx) {
                    ap = A + (size_t)rowidx[gm] * H + kk;
                } else {
                    ap = A + (size_t)gm * K + kk;
                }
#pragma unroll
                for (int i = 0; i < 4; ++i) {
                    float4 f = *(const float4*)(ap + i * 4);
                    va[i * 4 + 0] = f.x; va[i * 4 + 1] = f.y;
                    va[i * 4 + 2] = f.z; va[i * 4 + 3] = f.w;
                }
            }
        }
    };
    auto loadB = [&](int k0) {
        const __bf16* sh = Bth + (size_t)(n0 + bn) * K + k0 + bkb;
        const __bf16* sl = Btl + (size_t)(n0 + bn) * K + k0 + bkb;
        vbh0 = *(const v8bf*)sh;
        vbh1 = *(const v8bf*)(sh + 8);
        vbl0 = *(const v8bf*)sl;
        vbl1 = *(const v8bf*)(sl + 8);
    };

    loadA(0);
    loadB(0);
    int nk = K >> 5;
    for (int ki = 0; ki < nk; ++ki) {
        __syncthreads();
        {
            v8bf h0, h1, l0, l1;
#pragma unroll
            for (int i = 0; i < 8; ++i) {
                bfpair p0 = split2(va[i]);
                bfpair p1 = split2(va[8 + i]);
                h0[i] = p0.h; l0[i] = p0.l;
                h1[i] = p1.h; l1[i] = p1.l;
            }
            *(v8bf*)&Ah[ar * 40 + akq] = h0;
            *(v8bf*)&Ah[ar * 40 + akq + 8] = h1;
            *(v8bf*)&Al[ar * 40 + akq] = l0;
            *(v8bf*)&Al[ar * 40 + akq + 8] = l1;
            *(v8bf*)&Bh[bn * 40 + bkb] = vbh0;
            *(v8bf*)&Bh[bn * 40 + bkb + 8] = vbh1;
            *(v8bf*)&Bl[bn * 40 + bkb] = vbl0;
            *(v8bf*)&Bl[bn * 40 + bkb + 8] = vbl1;
        }
        __syncthreads();
        if (ki + 1 < nk) {
            loadA((ki + 1) * 32);
            loadB((ki + 1) * 32);
        }
        v8bf ah[2], al2[2];
#pragma unroll
        for (int mt = 0; mt < 2; ++mt) {
            ah[mt] = *(v8bf*)&Ah[(wrow + mt * 16 + lr) * 40 + q * 8];
            al2[mt] = *(v8bf*)&Al[(wrow + mt * 16 + lr) * 40 + q * 8];
        }
#pragma unroll
        for (int nt = 0; nt < 8; ++nt) {
            v8bf bh = *(v8bf*)&Bh[(nt * 16 + lr) * 40 + q * 8];
            v8bf bl = *(v8bf*)&Bl[(nt * 16 + lr) * 40 + q * 8];
#pragma unroll
            for (int mt = 0; mt < 2; ++mt) {
                v4f a = acc[mt][nt];
                a = __builtin_amdgcn_mfma_f32_16x16x32_bf16(al2[mt], bh, a, 0, 0, 0);
                a = __builtin_amdgcn_mfma_f32_16x16x32_bf16(ah[mt], bl, a, 0, 0, 0);
                a = __builtin_amdgcn_mfma_f32_16x16x32_bf16(ah[mt], bh, a, 0, 0, 0);
                acc[mt][nt] = a;
            }
        }
    }

    if (epi == 0) {
        float bcol[8];
#pragma unroll
        for (int nt = 0; nt < 8; ++nt) bcol[nt] = bias[n0 + nt * 16 + lr];
#pragma unroll
        for (int mt = 0; mt < 2; ++mt)
#pragma unroll
            for (int reg = 0; reg < 4; ++reg) {
                int rloc = wrow + mt * 16 + q * 4 + reg;
                int rm = m0 + rloc;
                if (rloc < mtile && rm < M) {
#pragma unroll
                    for (int nt = 0; nt < 8; ++nt) {
                        int cn = nt * 16 + lr;
                        float v = acc[mt][nt][reg] + bcol[nt];
                        if (relu_flag) v = fmaxf(v, 0.f);
                        if (res) v += res[(size_t)rm * Ncol + n0 + cn];
                        out[(size_t)rm * Ncol + n0 + cn] = v;
                    }
                }
            }
    } else {
        if (t < 128) { sS[t] = 0.f; sQ[t] = 0.f; }
        __syncthreads();
        float bcol[8];
#pragma unroll
        for (int nt = 0; nt < 8; ++nt) bcol[nt] = bias[n0 + nt * 16 + lr];
#pragma unroll
        for (int nt = 0; nt < 8; ++nt) {
            float s = 0.f, q2 = 0.f;
#pragma unroll
            for (int mt = 0; mt < 2; ++mt)
#pragma unroll
                for (int reg = 0; reg < 4; ++reg) {
                    int rloc = wrow + mt * 16 + q * 4 + reg;
                    int rm = m0 + rloc;
                    if (rloc < mtile && rm < M) {
                        float v = acc[mt][nt][reg] + bcol[nt];
                        s += v;
                        q2 += v * v;
                    }
                }
            atomicAdd(&sS[nt * 16 + lr], s);
            atomicAdd(&sQ[nt * 16 + lr], q2);
        }
        __syncthreads();
        if (t < 128) {
            atomicAdd(&stats[n0 + t], sS[t]);
            atomicAdd(&stats[Ncol + n0 + t], sQ[t]);
        }
    }
}

// ---------------- fused GINE MLP via MFMA (register-prefetch) ----------------

__global__ __launch_bounds__(256) void k_mlp_mfma(
    const float* __restrict__ hin,
    const __bf16* __restrict__ g1h, const __bf16* __restrict__ g1l,
    const float* __restrict__ gb1, const float* __restrict__ gbn_g,
    const float* __restrict__ gbn_b,
    const __bf16* __restrict__ g2h, const __bf16* __restrict__ g2l,
    const float* __restrict__ gb2, const float* __restrict__ stats,
    float* __restrict__ xout)
{
    __shared__ __bf16 Ah[32 * 136], Al[32 * 136];
    __shared__ __bf16 Bh[128 * 40], Bl[128 * 40];
    __shared__ __bf16 Th[32 * 264], Tl[32 * 264];
    __shared__ float sc[256], sh[256];

    int t = threadIdx.x;
    int r0 = blockIdx.x * 32;
    int lane = t & 63;
    int q = lane >> 4;
    int lr = lane & 15;
    int w = t >> 6;

    {
        float mean = stats[t] * (1.f / (float)Nn);
        float var = stats[256 + t] * (1.f / (float)Nn) - mean * mean;
        float s = gbn_g[t] * rsqrtf(var + BN_EPS);
        sc[t] = s;
        sh[t] = (gb1[t] - mean) * s + gbn_b[t];
    }
    {
        int r = t >> 3;
        int kq = (t & 7) * 16;
        const float* ap = hin + (size_t)(r0 + r) * H + kq;
        v8bf h0, h1, l0, l1;
#pragma unroll
        for (int i = 0; i < 8; ++i) {
            bfpair p0 = split2(ap[i]);
            bfpair p1 = split2(ap[8 + i]);
            h0[i] = p0.h; l0[i] = p0.l;
            h1[i] = p1.h; l1[i] = p1.l;
        }
        *(v8bf*)&Ah[r * 136 + kq] = h0;
        *(v8bf*)&Ah[r * 136 + kq + 8] = h1;
        *(v8bf*)&Al[r * 136 + kq] = l0;
        *(v8bf*)&Al[r * 136 + kq + 8] = l1;
    }

    int bn = t & 127;
    int bkb = (t >> 7) * 16;
    v8bf vbh0, vbh1, vbl0, vbl1;

    auto load1 = [&](int p, int k0) {
        const __bf16* shp = g1h + (size_t)(p * 128 + bn) * 128 + k0 + bkb;
        const __bf16* slp = g1l + (size_t)(p * 128 + bn) * 128 + k0 + bkb;
        vbh0 = *(const v8bf*)shp;
        vbh1 = *(const v8bf*)(shp + 8);
        vbl0 = *(const v8bf*)slp;
        vbl1 = *(const v8bf*)(slp + 8);
    };
    auto load2 = [&](int k0) {
        const __bf16* shp = g2h + (size_t)bn * 256 + k0 + bkb;
        const __bf16* slp = g2l + (size_t)bn * 256 + k0 + bkb;
        vbh0 = *(const v8bf*)shp;
        vbh1 = *(const v8bf*)(shp + 8);
        vbl0 = *(const v8bf*)slp;
        vbl1 = *(const v8bf*)(slp + 8);
    };
    auto storeB = [&]() {
        *(v8bf*)&Bh[bn * 40 + bkb] = vbh0;
        *(v8bf*)&Bh[bn * 40 + bkb + 8] = vbh1;
        *(v8bf*)&Bl[bn * 40 + bkb] = vbl0;
        *(v8bf*)&Bl[bn * 40 + bkb + 8] = vbl1;
    };

    load1(0, 0);
    for (int p = 0; p < 2; ++p) {
        v4f acc[2][2] = {};
        for (int k0 = 0; k0 < 128; k0 += 32) {
            __syncthreads();
            storeB();
            __syncthreads();
            int s = p * 4 + (k0 >> 5) + 1;
            if (s < 8) load1(s >> 2, (s & 3) * 32);
            else load2(0);
            v8bf ah[2], al2[2], bh[2], bl2[2];
#pragma unroll
            for (int mt = 0; mt < 2; ++mt) {
                ah[mt] = *(v8bf*)&Ah[(mt * 16 + lr) * 136 + k0 + q * 8];
                al2[mt] = *(v8bf*)&Al[(mt * 16 + lr) * 136 + k0 + q * 8];
            }
#pragma unroll
            for (int nt = 0; nt < 2; ++nt) {
                bh[nt] = *(v8bf*)&Bh[(w * 32 + nt * 16 + lr) * 40 + q * 8];
                bl2[nt] = *(v8bf*)&Bl[(w * 32 + nt * 16 + lr) * 40 + q * 8];
            }
#pragma unroll
            for (int mt = 0; mt < 2; ++mt)
#pragma unroll
                for (int nt = 0; nt < 2; ++nt) {
                    v4f a = acc[mt][nt];
                    a = __builtin_amdgcn_mfma_f32_16x16x32_bf16(al2[mt], bh[nt], a, 0, 0, 0);
                    a = __builtin_amdgcn_mfma_f32_16x16x32_bf16(ah[mt], bl2[nt], a, 0, 0, 0);
                    a = __builtin_amdgcn_mfma_f32_16x16x32_bf16(ah[mt], bh[nt], a, 0, 0, 0);
                    acc[mt][nt] = a;
                }
        }
#pragma unroll
        for (int mt = 0; mt < 2; ++mt)
#pragma unroll
            for (int nt = 0; nt < 2; ++nt)
#pragma unroll
                for (int reg = 0; reg < 4; ++reg) {
                    int row = mt * 16 + q * 4 + reg;
                    int col = p * 128 + w * 32 + nt * 16 + lr;
                    float v = fmaxf(acc[mt][nt][reg] * sc[col] + sh[col], 0.f);
                    bfpair pr = split2(v);
                    Th[row * 264 + col] = pr.h;
                    Tl[row * 264 + col] = pr.l;
                }
    }

    v4f acc2[2][2] = {};
    for (int k0 = 0; k0 < 256; k0 += 32) {
        __syncthreads();
        storeB();
        __syncthreads();
        if (k0 + 32 < 256) load2(k0 + 32);
        v8bf ah[2], al2[2], bh[2], bl2[2];
#pragma unroll
        for (int mt = 0; mt < 2; ++mt) {
            ah[mt] = *(v8bf*)&Th[(mt * 16 + lr) * 264 + k0 + q * 8];
            al2[mt] = *(v8bf*)&Tl[(mt * 16 + lr) * 264 + k0 + q * 8];
        }
#pragma unroll
        for (int nt = 0; nt < 2; ++nt) {
            bh[nt] = *(v8bf*)&Bh[(w * 32 + nt * 16 + lr) * 40 + q * 8];
            bl2[nt] = *(v8bf*)&Bl[(w * 32 + nt * 16 + lr) * 40 + q * 8];
        }
#pragma unroll
        for (int mt = 0; mt < 2; ++mt)
#pragma unroll
            for (int nt = 0; nt < 2; ++nt) {
                v4f a = acc2[mt][nt];
                a = __builtin_amdgcn_mfma_f32_16x16x32_bf16(al2[mt], bh[nt], a, 0, 0, 0);
                a = __builtin_amdgcn_mfma_f32_16x16x32_bf16(ah[mt], bl2[nt], a, 0, 0, 0);
                a = __builtin_amdgcn_mfma_f32_16x16x32_bf16(ah[mt], bh[nt], a, 0, 0, 0);
                acc2[mt][nt] = a;
            }
    }
#pragma unroll
    for (int mt = 0; mt < 2; ++mt)
#pragma unroll
        for (int nt = 0; nt < 2; ++nt)
#pragma unroll
            for (int reg = 0; reg < 4; ++reg) {
                int row = mt * 16 + q * 4 + reg;
                int col = w * 32 + nt * 16 + lr;
                xout[(size_t)(r0 + row) * H + col] = acc2[mt][nt][reg] + gb2[col];
            }
}

// ---------------- readout ----------------

__global__ void k_seg_batch(const float* __restrict__ x, const int* __restrict__ batch,
                            float* __restrict__ xgsum, float* __restrict__ gcnt) {
    int h = threadIdx.x;
    int r0 = blockIdx.x * 256;
    if (r0 >= Nn) return;
    int r1 = min(r0 + 256, Nn);
    int cur = batch[r0];
    float acc = 0.f, c = 0.f;
    for (int r = r0; r < r1; ++r) {
        int b = batch[r];
        if (b != cur) {
            atomicAdd(&xgsum[cur * H + h], acc);
            if (h == 0) atomicAdd(&gcnt[cur], c);
            acc = 0.f;
            c = 0.f;
            cur = b;
        }
        acc += x[r * H + h];
        c += 1.f;
    }
    atomicAdd(&xgsum[cur * H + h], acc);
    if (h == 0) atomicAdd(&gcnt[cur], c);
}

__global__ void k_head(const float* __restrict__ xgsum, const float* __restrict__ gcnt,
                       const float* __restrict__ alw, const float* __restrict__ alb,
                       const float* __restrict__ lw, const float* __restrict__ lb,
                       float* __restrict__ out) {
    __shared__ float mean[H];
    __shared__ float red[H];
    int g = blockIdx.x, j = threadIdx.x;
    mean[j] = xgsum[g * H + j] / fmaxf(gcnt[g], 1.f);
    __syncthreads();
    float acc = alb[j];
    for (int k = 0; k < H; ++k) acc += mean[k] * alw[k * H + j];
    acc = fmaxf(acc, 0.f) * lw[j];
    red[j] = acc;
    __syncthreads();
    for (int s = 64; s > 0; s >>= 1) {
        if (j < s) red[j] += red[j + s];
        __syncthreads();
    }
    if (j == 0) out[g] = red[0] + lb[0];
}

// ---------------- host ----------------

extern "C" void kernel_launch(void* const* d_in, const int* in_sizes, int n_in,
                              void* d_out, int out_size, void* d_ws, size_t ws_size,
                              hipStream_t stream) {
    const int* x_atom = (const int*)d_in[0];
    const int* ei = (const int*)d_in[1];
    const int* eattr = (const int*)d_in[2];
    const int* batch = (const int*)d_in[3];
    const int* xc5 = (const int*)d_in[4];
    const int* xc6 = (const int*)d_in[5];
    const int* a2c5_row = (const int*)d_in[6];
    const int* a2c6_row = (const int*)d_in[8];
    const float* atom_emb = (const float*)d_in[10];
    const float* bond_emb = (const float*)d_in[11];
    const float* cyc5 = (const float*)d_in[12];
    const float* cyc6 = (const float*)d_in[13];
    const float* eps = (const float*)d_in[14];
    const float* gw1 = (const float*)d_in[15];
    const float* gb1 = (const float*)d_in[16];
    const float* gbn_g = (const float*)d_in[17];
    const float* gbn_b = (const float*)d_in[18];
    const float* gw2 = (const float*)d_in[19];
    const float* gb2 = (const float*)d_in[20];
    const float* bn_g = (const float*)d_in[21];
    const float* bn_b = (const float*)d_in[22];
    const float* a2c5_w = (const float*)d_in[23];
    const float* a2c5_b = (const float*)d_in[24];
    const float* a2c6_w = (const float*)d_in[25];
    const float* a2c6_b = (const float*)d_in[26];
    const float* c2a5_w = (const float*)d_in[27];
    const float* c2a5_b = (const float*)d_in[28];
    const float* c2a6_w = (const float*)d_in[29];
    const float* c2a6_b = (const float*)d_in[30];
    const float* p5_w = (const float*)d_in[31];
    const float* p5_b = (const float*)d_in[32];
    const float* p6_w = (const float*)d_in[33];
    const float* p6_b = (const float*)d_in[34];
    const float* alw = (const float*)d_in[35];
    const float* alb = (const float*)d_in[36];
    const float* lw = (const float*)d_in[37];
    const float* lb = (const float*)d_in[38];
    float* out = (float*)d_out;

    float* w = (float*)d_ws;
    size_t o = 0;
    auto alloc = [&](size_t nf) {
        float* p = w + o;
        o += (nf + 63) & ~(size_t)63;
        return p;
    };
    auto allocb = [&](size_t nbf) { return (__bf16*)alloc((nbf + 1) / 2); };
    float* x = alloc((size_t)Nn * H);
    float* x5 = alloc((size_t)N5c * 5 * H);
    float* x6 = alloc((size_t)N6c * 6 * H);
    float* agg = alloc((size_t)Nn * H);
    float* stats = alloc(512);
    float* xgsum = alloc((size_t)Gg * H);
    float* gcnt = alloc(Gg);
    float* rscale5 = alloc(Nn);
    float* rscale6 = alloc(Nn);
    int* deg = (int*)alloc(Nn);
    int* rowptr = (int*)alloc(Nn + 1);
    int* rp5c = (int*)alloc(Nn + 1);
    int* rp6c = (int*)alloc(Nn + 1);
    int* woff = (int*)alloc(Nn);
    int* bsum = (int*)alloc(256);
    int* boff = (int*)alloc(256);
    unsigned int* elist = (unsigned int*)alloc(Ee);
    int* cidx5 = (int*)alloc(N5c * 5);
    int* cidx6 = (int*)alloc(N6c * 6);
    float* ebank = alloc(512 * H);
    __bf16 *g1h = allocb(3 * 128 * 256), *g1l = allocb(3 * 128 * 256);
    __bf16 *g2h = allocb(3 * 256 * 128), *g2l = allocb(3 * 256 * 128);
    __bf16 *a5h = allocb(3 * 128 * 128), *a5l = allocb(3 * 128 * 128);
    __bf16 *a6h = allocb(3 * 128 * 128), *a6l = allocb(3 * 128 * 128);
    __bf16 *c5h = allocb(3 * 128 * 128), *c5l = allocb(3 * 128 * 128);
    __bf16 *c6h = allocb(3 * 128 * 128), *c6l = allocb(3 * 128 * 128);
    __bf16 *p5h = allocb(3 * 384 * 128), *p5l = allocb(3 * 384 * 128);
    __bf16 *p6h = allocb(3 * 384 * 128), *p6l = allocb(3 * 384 * 128);

    const int TPB = 256;
    auto cdiv = [](int a, int b) { return (a + b - 1) / b; };
    int nsb = cdiv(Nn, 1024);

    // weight pre-split
    k_split<<<cdiv(3 * 128 * 256, TPB), TPB, 0, stream>>>(gw1, g1h, g1l, 3, 128, 256);
    k_split<<<cdiv(3 * 256 * 128, TPB), TPB, 0, stream>>>(gw2, g2h, g2l, 3, 256, 128);
    k_split<<<cdiv(3 * 128 * 128, TPB), TPB, 0, stream>>>(a2c5_w, a5h, a5l, 3, 128, 128);
    k_split<<<cdiv(3 * 128 * 128, TPB), TPB, 0, stream>>>(a2c6_w, a6h, a6l, 3, 128, 128);
    k_split<<<cdiv(3 * 128 * 128, TPB), TPB, 0, stream>>>(c2a5_w, c5h, c5l, 3, 128, 128);
    k_split<<<cdiv(3 * 128 * 128, TPB), TPB, 0, stream>>>(c2a6_w, c6h, c6l, 3, 128, 128);
    k_split<<<cdiv(3 * 384 * 128, TPB), TPB, 0, stream>>>(p5_w, p5h, p5l, 3, 384, 128);
    k_split<<<cdiv(3 * 384 * 128, TPB), TPB, 0, stream>>>(p6_w, p6h, p6l, 3, 384, 128);

    // edge CSR
    hipMemsetAsync(deg, 0, Nn * 4, stream);
    k_degi<<<cdiv(Ee, TPB), TPB, 0, stream>>>(ei + Ee, deg, Ee);
    k_scan1<<<nsb, 256, 0, stream>>>(deg, rowptr, bsum, Nn);
    k_scan2<<<1, 128, 0, stream>>>(bsum, boff, rowptr, nsb, Nn);
    k_scan3<<<cdiv(Nn, TPB), TPB, 0, stream>>>(rowptr, boff, Nn);
    hipMemcpyAsync(woff, rowptr, Nn * 4, hipMemcpyDeviceToDevice, stream);
    k_fill<<<cdiv(Ee, TPB), TPB, 0, stream>>>(ei, eattr, woff, elist);

    // cycle->atom CSRs + mean scales
    hipMemsetAsync(deg, 0, Nn * 4, stream);
    k_degi<<<cdiv(N5c * 5, TPB), TPB, 0, stream>>>(a2c5_row, deg, N5c * 5);
    k_scan1<<<nsb, 256, 0, stream>>>(deg, rp5c, bsum, Nn);
    k_scan2<<<1, 128, 0, stream>>>(bsum, boff, rp5c, nsb, Nn);
    k_scan3<<<cdiv(Nn, TPB), TPB, 0, stream>>>(rp5c, boff, Nn);
    k_inv_int<<<cdiv(Nn, TPB), TPB, 0, stream>>>(deg, rscale5);
    hipMemcpyAsync(woff, rp5c, Nn * 4, hipMemcpyDeviceToDevice, stream);
    k_fill_idx<<<cdiv(N5c * 5, TPB), TPB, 0, stream>>>(a2c5_row, woff, cidx5, N5c * 5);

    hipMemsetAsync(deg, 0, Nn * 4, stream);
    k_degi<<<cdiv(N6c * 6, TPB), TPB, 0, stream>>>(a2c6_row, deg, N6c * 6);
    k_scan1<<<nsb, 256, 0, stream>>>(deg, rp6c, bsum, Nn);
    k_scan2<<<1, 128, 0, stream>>>(bsum, boff, rp6c, nsb, Nn);
    k_scan3<<<cdiv(Nn, TPB), TPB, 0, stream>>>(rp6c, boff, Nn);
    k_inv_int<<<cdiv(Nn, TPB), TPB, 0, stream>>>(deg, rscale6);
    hipMemcpyAsync(woff, rp6c, Nn * 4, hipMemcpyDeviceToDevice, stream);
    k_fill_idx<<<cdiv(N6c * 6, TPB), TPB, 0, stream>>>(a2c6_row, woff, cidx6, N6c * 6);

    k_atom_enc<<<cdiv(Nn * H, TPB), TPB, 0, stream>>>(x_atom, atom_emb, x);
    k_cyc_init<<<cdiv(N5c * 5 * H, TPB), TPB, 0, stream>>>(xc5, cyc5, x5, N5c * 5);
    k_cyc_init<<<cdiv(N6c * 6 * H, TPB), TPB, 0, stream>>>(xc6, cyc6, x6, N6c * 6);

    for (int i = 0; i < Ll; ++i) {
        // GINE aggregation (gather) -> agg
        k_ebank<<<cdiv(512 * H, TPB), TPB, 0, stream>>>(
            bond_emb + (size_t)i * BF * BV * H, ebank);
        k_agg_csr<<<Nn / 2, 256, 0, stream>>>(x, rowptr, elist, ebank, eps, i, agg);

        // BN1 stats via epi-GEMM
        hipMemsetAsync(stats, 0, 512 * 4, stream);
        k_mgemm<<<dim3(cdiv(Nn, 128), 2), 256, 0, stream>>>(
            agg, g1h + (size_t)i * 128 * 256, g1l + (size_t)i * 128 * 256,
            gb1 + (size_t)i * 256, nullptr, nullptr, nullptr, nullptr, nullptr,
            nullptr, stats, Nn, 128, 256, 0, 128, 0, 1);

        // fused MLP -> x (pre-BN2)
        k_mlp_mfma<<<Nn / 32, 256, 0, stream>>>(
            agg, g1h + (size_t)i * 128 * 256, g1l + (size_t)i * 128 * 256,
            gb1 + (size_t)i * 256, gbn_g + (size_t)i * 256, gbn_b + (size_t)i * 256,
            g2h + (size_t)i * 256 * 128, g2l + (size_t)i * 256 * 128,
            gb2 + (size_t)i * H, stats, x);

        // BN2 + relu
        hipMemsetAsync(stats, 0, 512 * 4, stream);
        k_bn_stats<<<cdiv(Nn, 64), H, 0, stream>>>(x, stats, Nn, H, 64);
        k_bn_apply<<<cdiv(Nn * H, TPB), TPB, 0, stream>>>(
            x, stats, bn_g + (size_t)i * H, bn_b + (size_t)i * H, Nn, H);

        // atoms -> cycles (row-gather GEMM, in-place residual)
        k_mgemm<<<dim3(cdiv(N5c * 5, 128), 1), 256, 0, stream>>>(
            x, a5h + (size_t)i * 128 * 128, a5l + (size_t)i * 128 * 128,
            a2c5_b + (size_t)i * H, x5, x5, a2c5_row, nullptr, nullptr, nullptr,
            nullptr, N5c * 5, 128, 128, 0, 128, 1, 0);
        k_mgemm<<<dim3(cdiv(N6c * 6, 128), 1), 256, 0, stream>>>(
            x, a6h + (size_t)i * 128 * 128, a6l + (size_t)i * 128 * 128,
            a2c6_b + (size_t)i * H, x6, x6, a2c6_row, nullptr, nullptr, nullptr,
            nullptr, N6c * 6, 128, 128, 0, 128, 1, 0);

        // cyclic path blocks: cycle-aligned tiles, fully in-place
        k_mgemm<<<dim3(cdiv(N5c, 25), 1), 256, 0, stream>>>(
            x5, p5h + (size_t)i * 384 * 128, p5l + (size_t)i * 384 * 128,
            p5_b + (size_t)i * H, x5, x5, nullptr, nullptr, nullptr, nullptr,
            nullptr, N5c * 5, 384, 128, 5, 125, 1, 0);
        k_mgemm<<<dim3(cdiv(N6c, 21), 1), 256, 0, stream>>>(
            x6, p6h + (size_t)i * 384 * 128, p6l + (size_t)i * 384 * 128,
            p6_b + (size_t)i * H, x6, x6, nullptr, nullptr, nullptr, nullptr,
            nullptr, N6c * 6, 384, 128, 6, 126, 1, 0);

        // cycles -> atoms (CSR mean-gather fused into GEMM A-stage)
        k_mgemm<<<dim3(cdiv(Nn, 128), 1), 256, 0, stream>>>(
            x5, c5h + (size_t)i * 128 * 128, c5l + (size_t)i * 128 * 128,
            c2a5_b + (size_t)i * H, x, x, nullptr, rp5c, cidx5, rscale5,
            nullptr, Nn, 128, 128, 0, 128, 1, 0);
        k_mgemm<<<dim3(cdiv(Nn, 128), 1), 256, 0, stream>>>(
            x6, c6h + (size_t)i * 128 * 128, c6l + (size_t)i * 128 * 128,
            c2a6_b + (size_t)i * H, x, x, nullptr, rp6c, cidx6, rscale6,
            nullptr, Nn, 128, 128, 0, 128, 1, 0);
    }

    // readout
    hipMemsetAsync(xgsum, 0, (size_t)Gg * H * 4, stream);
    hipMemsetAsync(gcnt, 0, (size_t)Gg * 4, stream);
    k_seg_batch<<<cdiv(Nn, 256), H, 0, stream>>>(x, batch, xgsum, gcnt);
    k_head<<<Gg, H, 0, stream>>>(xgsum, gcnt, alw, alb, lw, lb, out);
}

// Round 9
// 2568.296 us; speedup vs baseline: 1.5679x; 1.0711x over previous
//
#include <hip/hip_runtime.h>

#define H 128
#define Nn 100000
#define Ee 250000
#define N5c 20000
#define N6c 30000
#define Gg 512
#define Ll 3
#define AF 9
#define AV 64
#define BF 3
#define BV 8
#define BN_EPS 1e-5f

typedef __bf16 v8bf __attribute__((ext_vector_type(8)));
typedef float v4f __attribute__((ext_vector_type(4)));

struct bfpair { __bf16 h, l; };
__device__ inline bfpair split2(float v) {
    bfpair r;
    r.h = (__bf16)v;
    r.l = (__bf16)(v - (float)r.h);
    return r;
}

// ---------------- init / embedding kernels ----------------

__global__ void k_atom_enc(const int* __restrict__ xa, const float* __restrict__ emb,
                           float* __restrict__ x) {
    int idx = blockIdx.x * blockDim.x + threadIdx.x;
    if (idx >= Nn * H) return;
    int n = idx >> 7, h = idx & 127;
    float s = 0.f;
#pragma unroll
    for (int f = 0; f < AF; ++f) {
        int a = xa[n * AF + f];
        s += emb[(f * AV + a) * H + h];
    }
    x[idx] = s;
}

__global__ void k_cyc_init(const int* __restrict__ xc, const float* __restrict__ emb,
                           float* __restrict__ xo, int M) {
    int idx = blockIdx.x * blockDim.x + threadIdx.x;
    if (idx >= M * H) return;
    int m = idx >> 7, h = idx & 127;
    xo[idx] = emb[xc[m] * H + h];
}

// weight pre-split: (L,K,N) fp32 row-major -> per-layer transposed [n][k] bf16 hi/lo
__global__ void k_split(const float* __restrict__ src, __bf16* __restrict__ dh,
                        __bf16* __restrict__ dl, int L, int K, int N) {
    int idx = blockIdx.x * blockDim.x + threadIdx.x;
    int tot = L * K * N;
    if (idx >= tot) return;
    int l = idx / (K * N);
    int r = idx - l * (K * N);
    int k = r / N;
    int n = r - k * N;
    bfpair p = split2(src[idx]);
    size_t d = (size_t)l * K * N + (size_t)n * K + k;
    dh[d] = p.h;
    dl[d] = p.l;
}

// ---------------- CSR build helpers (edge + cycle maps; all static) ----------------

__global__ void k_degi(const int* __restrict__ row, int* __restrict__ deg, int M) {
    int m = blockIdx.x * blockDim.x + threadIdx.x;
    if (m >= M) return;
    atomicAdd(&deg[row[m]], 1);
}

__global__ void k_scan1(const int* __restrict__ deg, int* __restrict__ rp,
                        int* __restrict__ bsum, int n) {
    __shared__ int s[256];
    int tid = threadIdx.x;
    int base = blockIdx.x * 1024 + tid * 4;
    int v0 = (base < n) ? deg[base] : 0;
    int v1 = (base + 1 < n) ? deg[base + 1] : 0;
    int v2 = (base + 2 < n) ? deg[base + 2] : 0;
    int v3 = (base + 3 < n) ? deg[base + 3] : 0;
    int tsum = v0 + v1 + v2 + v3;
    s[tid] = tsum;
    __syncthreads();
    for (int off = 1; off < 256; off <<= 1) {
        int u = (tid >= off) ? s[tid - off] : 0;
        __syncthreads();
        s[tid] += u;
        __syncthreads();
    }
    int exc = s[tid] - tsum;
    if (base < n) rp[base] = exc;
    if (base + 1 < n) rp[base + 1] = exc + v0;
    if (base + 2 < n) rp[base + 2] = exc + v0 + v1;
    if (base + 3 < n) rp[base + 3] = exc + v0 + v1 + v2;
    if (tid == 255) bsum[blockIdx.x] = s[255];
}

__global__ void k_scan2(const int* __restrict__ bsum, int* __restrict__ boff,
                        int* __restrict__ rp, int nb, int n) {
    __shared__ int s[128];
    int tid = threadIdx.x;
    int v = (tid < nb) ? bsum[tid] : 0;
    s[tid] = v;
    __syncthreads();
    for (int off = 1; off < 128; off <<= 1) {
        int u = (tid >= off) ? s[tid - off] : 0;
        __syncthreads();
        s[tid] += u;
        __syncthreads();
    }
    if (tid < nb) boff[tid] = s[tid] - v;
    if (tid == 127) rp[n] = s[127];
}

__global__ void k_scan3(int* __restrict__ rp, const int* __restrict__ boff, int n) {
    int idx = blockIdx.x * blockDim.x + threadIdx.x;
    if (idx < n) rp[idx] += boff[idx >> 10];
}

__global__ void k_fill(const int* __restrict__ ei, const int* __restrict__ eattr,
                       int* __restrict__ woff, unsigned int* __restrict__ elist) {
    int e = blockIdx.x * blockDim.x + threadIdx.x;
    if (e >= Ee) return;
    int src = ei[e], dst = ei[Ee + e];
    int code = eattr[e * BF + 0] * 64 + eattr[e * BF + 1] * 8 + eattr[e * BF + 2];
    int p = atomicAdd(&woff[dst], 1);
    elist[p] = ((unsigned int)code << 17) | (unsigned int)src;
}

__global__ void k_fill_idx(const int* __restrict__ row, int* __restrict__ woff,
                           int* __restrict__ cidx, int M) {
    int m = blockIdx.x * blockDim.x + threadIdx.x;
    if (m >= M) return;
    int p = atomicAdd(&woff[row[m]], 1);
    cidx[p] = m;
}

__global__ void k_inv_int(const int* __restrict__ deg, float* __restrict__ rscale) {
    int r = blockIdx.x * blockDim.x + threadIdx.x;
    if (r >= Nn) return;
    rscale[r] = 1.f / fmaxf((float)deg[r], 1.f);
}

__global__ void k_ebank(const float* __restrict__ bemb, float* __restrict__ ebank) {
    int idx = blockIdx.x * blockDim.x + threadIdx.x;
    if (idx >= 512 * H) return;
    int code = idx >> 7, h = idx & 127;
    int f0 = code >> 6, f1 = (code >> 3) & 7, f2 = code & 7;
    ebank[idx] = bemb[(0 * BV + f0) * H + h] + bemb[(1 * BV + f1) * H + h]
               + bemb[(2 * BV + f2) * H + h];
}

// GINE aggregation, gather form
__global__ __launch_bounds__(256) void k_agg_csr(
    const float* __restrict__ x, const int* __restrict__ rowptr,
    const unsigned int* __restrict__ elist, const float* __restrict__ ebank,
    const float* __restrict__ eps, int layer, float* __restrict__ agg)
{
    int a = blockIdx.x * 2 + (threadIdx.x >> 7);
    int h = threadIdx.x & 127;
    float acc = (1.f + eps[layer]) * x[(size_t)a * H + h];
    int j0 = rowptr[a], j1 = rowptr[a + 1];
    for (int j = j0; j < j1; ++j) {
        unsigned int u = elist[j];
        int src = u & 0x1FFFF;
        int code = u >> 17;
        acc += fmaxf(x[(size_t)src * H + h] + ebank[code * H + h], 0.f);
    }
    agg[(size_t)a * H + h] = acc;
}

// ---------------- misc elementwise ----------------

__global__ void k_bn_stats(const float* __restrict__ h, float* __restrict__ stats,
                           int M, int C, int rpb) {
    int c = threadIdx.x;
    int r0 = blockIdx.x * rpb;
    int r1 = min(r0 + rpb, M);
    float s = 0.f, sq = 0.f;
    for (int r = r0; r < r1; ++r) {
        float v = h[(size_t)r * C + c];
        s += v;
        sq += v * v;
    }
    atomicAdd(&stats[c], s);
    atomicAdd(&stats[C + c], sq);
}

__global__ void k_bn_apply(float* __restrict__ h, const float* __restrict__ stats,
                           const float* __restrict__ g, const float* __restrict__ b,
                           int M, int C) {
    int idx = blockIdx.x * blockDim.x + threadIdx.x;
    if (idx >= M * C) return;
    int c = idx & (C - 1);
    float mean = stats[c] / (float)M;
    float var = stats[C + c] / (float)M - mean * mean;
    float v = (h[idx] - mean) * rsqrtf(var + BN_EPS) * g[c] + b[c];
    h[idx] = fmaxf(v, 0.f);
}

// ---------------- generic MFMA GEMM (bf16x2: A hi/lo split, B hi only) ----------------
// A-modes: pathk>0 = cyclic-conv gather (cycle-aligned mtile, in-place safe);
//          grp/gcol/gscale = CSR mean-gather; rowidx = row gather; else direct.
// epi==1 accumulates BN stats instead of writing out.
// LDS ~31.7 KB -> 5 blocks/CU.

__global__ __launch_bounds__(256) void k_mgemm(
    const float* __restrict__ A, const __bf16* __restrict__ Bth,
    const float* __restrict__ bias,
    const float* __restrict__ res, float* __restrict__ out,
    const int* __restrict__ rowidx, const int* __restrict__ grp,
    const int* __restrict__ gcol, const float* __restrict__ gscale,
    float* __restrict__ stats,
    int M, int K, int Ncol, int pathk, int mtile, int relu_flag, int epi)
{
    __shared__ __bf16 Ah[128 * 40], Al[128 * 40];
    __shared__ __bf16 Bh[128 * 40];
    __shared__ float sS[128], sQ[128];

    int t = threadIdx.x;
    int m0 = blockIdx.x * mtile;
    int n0 = blockIdx.y * 128;
    int lane = t & 63;
    int q = lane >> 4;
    int lr = lane & 15;
    int wrow = (t >> 6) * 32;

    v4f acc[2][8] = {};

    int ar = t >> 1;
    int akq = (t & 1) * 16;
    int bn = t & 127;
    int bkb = (t >> 7) * 16;
    int gm = m0 + ar;
    bool av = (ar < mtile) && (gm < M);

    float va[16];
    v8bf vbh0, vbh1;

    auto loadA = [&](int k0) {
#pragma unroll
        for (int i = 0; i < 16; ++i) va[i] = 0.f;
        if (av) {
            int kk = k0 + akq;
            if (grp) {
                int j0 = grp[gm], j1 = grp[gm + 1];
                for (int j = j0; j < j1; ++j) {
                    const float* ap = A + (size_t)gcol[j] * H + kk;
#pragma unroll
                    for (int i = 0; i < 4; ++i) {
                        float4 f = *(const float4*)(ap + i * 4);
                        va[i * 4 + 0] += f.x; va[i * 4 + 1] += f.y;
                        va[i * 4 + 2] += f.z; va[i * 4 + 3] += f.w;
                    }
                }
                float s = gscale[gm];
#pragma unroll
                for (int i = 0; i < 16; ++i) va[i] *= s;
            } else {
                const float* ap;
                if (pathk) {
                    int cyc = gm / pathk;
                    int p = gm - cyc * pathk;
                    int sel = kk >> 7;
                    int pp = p + sel - 1;
                    if (pp < 0) pp += pathk;
                    if (pp >= pathk) pp -= pathk;
                    ap = A + (size_t)(cyc * pathk + pp) * H + (kk & 127);
                } else if (rowidx) {
                    ap = A + (size_t)rowidx[gm] * H + kk;
                } else {
                    ap = A + (size_t)gm * K + kk;
                }
#pragma unroll
                for (int i = 0; i < 4; ++i) {
                    float4 f = *(const float4*)(ap + i * 4);
                    va[i * 4 + 0] = f.x; va[i * 4 + 1] = f.y;
                    va[i * 4 + 2] = f.z; va[i * 4 + 3] = f.w;
                }
            }
        }
    };
    auto loadB = [&](int k0) {
        const __bf16* sh = Bth + (size_t)(n0 + bn) * K + k0 + bkb;
        vbh0 = *(const v8bf*)sh;
        vbh1 = *(const v8bf*)(sh + 8);
    };

    loadA(0);
    loadB(0);
    int nk = K >> 5;
    for (int ki = 0; ki < nk; ++ki) {
        __syncthreads();
        {
            v8bf h0, h1, l0, l1;
#pragma unroll
            for (int i = 0; i < 8; ++i) {
                bfpair p0 = split2(va[i]);
                bfpair p1 = split2(va[8 + i]);
                h0[i] = p0.h; l0[i] = p0.l;
                h1[i] = p1.h; l1[i] = p1.l;
            }
            *(v8bf*)&Ah[ar * 40 + akq] = h0;
            *(v8bf*)&Ah[ar * 40 + akq + 8] = h1;
            *(v8bf*)&Al[ar * 40 + akq] = l0;
            *(v8bf*)&Al[ar * 40 + akq + 8] = l1;
            *(v8bf*)&Bh[bn * 40 + bkb] = vbh0;
            *(v8bf*)&Bh[bn * 40 + bkb + 8] = vbh1;
        }
        __syncthreads();
        if (ki + 1 < nk) {
            loadA((ki + 1) * 32);
            loadB((ki + 1) * 32);
        }
        v8bf ah[2], al2[2];
#pragma unroll
        for (int mt = 0; mt < 2; ++mt) {
            ah[mt] = *(v8bf*)&Ah[(wrow + mt * 16 + lr) * 40 + q * 8];
            al2[mt] = *(v8bf*)&Al[(wrow + mt * 16 + lr) * 40 + q * 8];
        }
#pragma unroll
        for (int nt = 0; nt < 8; ++nt) {
            v8bf bh = *(v8bf*)&Bh[(nt * 16 + lr) * 40 + q * 8];
#pragma unroll
            for (int mt = 0; mt < 2; ++mt) {
                v4f a = acc[mt][nt];
                a = __builtin_amdgcn_mfma_f32_16x16x32_bf16(al2[mt], bh, a, 0, 0, 0);
                a = __builtin_amdgcn_mfma_f32_16x16x32_bf16(ah[mt], bh, a, 0, 0, 0);
                acc[mt][nt] = a;
            }
        }
    }

    if (epi == 0) {
        float bcol[8];
#pragma unroll
        for (int nt = 0; nt < 8; ++nt) bcol[nt] = bias[n0 + nt * 16 + lr];
#pragma unroll
        for (int mt = 0; mt < 2; ++mt)
#pragma unroll
            for (int reg = 0; reg < 4; ++reg) {
                int rloc = wrow + mt * 16 + q * 4 + reg;
                int rm = m0 + rloc;
                if (rloc < mtile && rm < M) {
#pragma unroll
                    for (int nt = 0; nt < 8; ++nt) {
                        int cn = nt * 16 + lr;
                        float v = acc[mt][nt][reg] + bcol[nt];
                        if (relu_flag) v = fmaxf(v, 0.f);
                        if (res) v += res[(size_t)rm * Ncol + n0 + cn];
                        out[(size_t)rm * Ncol + n0 + cn] = v;
                    }
                }
            }
    } else {
        if (t < 128) { sS[t] = 0.f; sQ[t] = 0.f; }
        __syncthreads();
        float bcol[8];
#pragma unroll
        for (int nt = 0; nt < 8; ++nt) bcol[nt] = bias[n0 + nt * 16 + lr];
#pragma unroll
        for (int nt = 0; nt < 8; ++nt) {
            float s = 0.f, q2 = 0.f;
#pragma unroll
            for (int mt = 0; mt < 2; ++mt)
#pragma unroll
                for (int reg = 0; reg < 4; ++reg) {
                    int rloc = wrow + mt * 16 + q * 4 + reg;
                    int rm = m0 + rloc;
                    if (rloc < mtile && rm < M) {
                        float v = acc[mt][nt][reg] + bcol[nt];
                        s += v;
                        q2 += v * v;
                    }
                }
            atomicAdd(&sS[nt * 16 + lr], s);
            atomicAdd(&sQ[nt * 16 + lr], q2);
        }
        __syncthreads();
        if (t < 128) {
            atomicAdd(&stats[n0 + t], sS[t]);
            atomicAdd(&stats[Ncol + n0 + t], sQ[t]);
        }
    }
}

// ---------------- fused GINE MLP via MFMA (bf16x2: A hi, B hi/lo split) ----------------
// LDS ~48.1 KB -> 3 blocks/CU.

__global__ __launch_bounds__(256) void k_mlp_mfma(
    const float* __restrict__ hin,
    const __bf16* __restrict__ g1h, const __bf16* __restrict__ g1l,
    const float* __restrict__ gb1, const float* __restrict__ gbn_g,
    const float* __restrict__ gbn_b,
    const __bf16* __restrict__ g2h, const __bf16* __restrict__ g2l,
    const float* __restrict__ gb2, const float* __restrict__ stats,
    float* __restrict__ xout)
{
    __shared__ __bf16 Ah[32 * 136];
    __shared__ __bf16 Bh[128 * 40], Bl[128 * 40];
    __shared__ __bf16 Th[32 * 264];
    __shared__ float sc[256], sh[256];

    int t = threadIdx.x;
    int r0 = blockIdx.x * 32;
    int lane = t & 63;
    int q = lane >> 4;
    int lr = lane & 15;
    int w = t >> 6;

    {
        float mean = stats[t] * (1.f / (float)Nn);
        float var = stats[256 + t] * (1.f / (float)Nn) - mean * mean;
        float s = gbn_g[t] * rsqrtf(var + BN_EPS);
        sc[t] = s;
        sh[t] = (gb1[t] - mean) * s + gbn_b[t];
    }
    {
        int r = t >> 3;
        int kq = (t & 7) * 16;
        const float* ap = hin + (size_t)(r0 + r) * H + kq;
        v8bf h0, h1;
#pragma unroll
        for (int i = 0; i < 8; ++i) {
            h0[i] = (__bf16)ap[i];
            h1[i] = (__bf16)ap[8 + i];
        }
        *(v8bf*)&Ah[r * 136 + kq] = h0;
        *(v8bf*)&Ah[r * 136 + kq + 8] = h1;
    }

    int bn = t & 127;
    int bkb = (t >> 7) * 16;
    v8bf vbh0, vbh1, vbl0, vbl1;

    auto load1 = [&](int p, int k0) {  // gw1 planes [n=256][k=128]
        const __bf16* shp = g1h + (size_t)(p * 128 + bn) * 128 + k0 + bkb;
        const __bf16* slp = g1l + (size_t)(p * 128 + bn) * 128 + k0 + bkb;
        vbh0 = *(const v8bf*)shp;
        vbh1 = *(const v8bf*)(shp + 8);
        vbl0 = *(const v8bf*)slp;
        vbl1 = *(const v8bf*)(slp + 8);
    };
    auto load2 = [&](int k0) {  // gw2 planes [n=128][k=256]
        const __bf16* shp = g2h + (size_t)bn * 256 + k0 + bkb;
        const __bf16* slp = g2l + (size_t)bn * 256 + k0 + bkb;
        vbh0 = *(const v8bf*)shp;
        vbh1 = *(const v8bf*)(shp + 8);
        vbl0 = *(const v8bf*)slp;
        vbl1 = *(const v8bf*)(slp + 8);
    };
    auto storeB = [&]() {
        *(v8bf*)&Bh[bn * 40 + bkb] = vbh0;
        *(v8bf*)&Bh[bn * 40 + bkb + 8] = vbh1;
        *(v8bf*)&Bl[bn * 40 + bkb] = vbl0;
        *(v8bf*)&Bl[bn * 40 + bkb + 8] = vbl1;
    };

    load1(0, 0);
    // stage 1: T = relu(BN1(hin@gw1)), two 128-col panels
    for (int p = 0; p < 2; ++p) {
        v4f acc[2][2] = {};
        for (int k0 = 0; k0 < 128; k0 += 32) {
            __syncthreads();
            storeB();
            __syncthreads();
            int s = p * 4 + (k0 >> 5) + 1;
            if (s < 8) load1(s >> 2, (s & 3) * 32);
            else load2(0);
            v8bf ah[2], bh[2], bl[2];
#pragma unroll
            for (int mt = 0; mt < 2; ++mt)
                ah[mt] = *(v8bf*)&Ah[(mt * 16 + lr) * 136 + k0 + q * 8];
#pragma unroll
            for (int nt = 0; nt < 2; ++nt) {
                bh[nt] = *(v8bf*)&Bh[(w * 32 + nt * 16 + lr) * 40 + q * 8];
                bl[nt] = *(v8bf*)&Bl[(w * 32 + nt * 16 + lr) * 40 + q * 8];
            }
#pragma unroll
            for (int mt = 0; mt < 2; ++mt)
#pragma unroll
                for (int nt = 0; nt < 2; ++nt) {
                    v4f a = acc[mt][nt];
                    a = __builtin_amdgcn_mfma_f32_16x16x32_bf16(ah[mt], bl[nt], a, 0, 0, 0);
                    a = __builtin_amdgcn_mfma_f32_16x16x32_bf16(ah[mt], bh[nt], a, 0, 0, 0);
                    acc[mt][nt] = a;
                }
        }
#pragma unroll
        for (int mt = 0; mt < 2; ++mt)
#pragma unroll
            for (int nt = 0; nt < 2; ++nt)
#pragma unroll
                for (int reg = 0; reg < 4; ++reg) {
                    int row = mt * 16 + q * 4 + reg;
                    int col = p * 128 + w * 32 + nt * 16 + lr;
                    float v = fmaxf(acc[mt][nt][reg] * sc[col] + sh[col], 0.f);
                    Th[row * 264 + col] = (__bf16)v;
                }
    }

    // stage 2: x = T @ gw2 + gb2
    v4f acc2[2][2] = {};
    for (int k0 = 0; k0 < 256; k0 += 32) {
        __syncthreads();  // also covers T-panel writes on first iter
        storeB();
        __syncthreads();
        if (k0 + 32 < 256) load2(k0 + 32);
        v8bf th[2], bh[2], bl[2];
#pragma unroll
        for (int mt = 0; mt < 2; ++mt)
            th[mt] = *(v8bf*)&Th[(mt * 16 + lr) * 264 + k0 + q * 8];
#pragma unroll
        for (int nt = 0; nt < 2; ++nt) {
            bh[nt] = *(v8bf*)&Bh[(w * 32 + nt * 16 + lr) * 40 + q * 8];
            bl[nt] = *(v8bf*)&Bl[(w * 32 + nt * 16 + lr) * 40 + q * 8];
        }
#pragma unroll
        for (int mt = 0; mt < 2; ++mt)
#pragma unroll
            for (int nt = 0; nt < 2; ++nt) {
                v4f a = acc2[mt][nt];
                a = __builtin_amdgcn_mfma_f32_16x16x32_bf16(th[mt], bl[nt], a, 0, 0, 0);
                a = __builtin_amdgcn_mfma_f32_16x16x32_bf16(th[mt], bh[nt], a, 0, 0, 0);
                acc2[mt][nt] = a;
            }
    }
#pragma unroll
    for (int mt = 0; mt < 2; ++mt)
#pragma unroll
        for (int nt = 0; nt < 2; ++nt)
#pragma unroll
            for (int reg = 0; reg < 4; ++reg) {
                int row = mt * 16 + q * 4 + reg;
                int col = w * 32 + nt * 16 + lr;
                xout[(size_t)(r0 + row) * H + col] = acc2[mt][nt][reg] + gb2[col];
            }
}

// ---------------- readout ----------------

__global__ void k_seg_batch(const float* __restrict__ x, const int* __restrict__ batch,
                            float* __restrict__ xgsum, float* __restrict__ gcnt) {
    int h = threadIdx.x;
    int r0 = blockIdx.x * 256;
    if (r0 >= Nn) return;
    int r1 = min(r0 + 256, Nn);
    int cur = batch[r0];
    float acc = 0.f, c = 0.f;
    for (int r = r0; r < r1; ++r) {
        int b = batch[r];
        if (b != cur) {
            atomicAdd(&xgsum[cur * H + h], acc);
            if (h == 0) atomicAdd(&gcnt[cur], c);
            acc = 0.f;
            c = 0.f;
            cur = b;
        }
        acc += x[r * H + h];
        c += 1.f;
    }
    atomicAdd(&xgsum[cur * H + h], acc);
    if (h == 0) atomicAdd(&gcnt[cur], c);
}

__global__ void k_head(const float* __restrict__ xgsum, const float* __restrict__ gcnt,
                       const float* __restrict__ alw, const float* __restrict__ alb,
                       const float* __restrict__ lw, const float* __restrict__ lb,
                       float* __restrict__ out) {
    __shared__ float mean[H];
    __shared__ float red[H];
    int g = blockIdx.x, j = threadIdx.x;
    mean[j] = xgsum[g * H + j] / fmaxf(gcnt[g], 1.f);
    __syncthreads();
    float acc = alb[j];
    for (int k = 0; k < H; ++k) acc += mean[k] * alw[k * H + j];
    acc = fmaxf(acc, 0.f) * lw[j];
    red[j] = acc;
    __syncthreads();
    for (int s = 64; s > 0; s >>= 1) {
        if (j < s) red[j] += red[j + s];
        __syncthreads();
    }
    if (j == 0) out[g] = red[0] + lb[0];
}

// ---------------- host ----------------

extern "C" void kernel_launch(void* const* d_in, const int* in_sizes, int n_in,
                              void* d_out, int out_size, void* d_ws, size_t ws_size,
                              hipStream_t stream) {
    const int* x_atom = (const int*)d_in[0];
    const int* ei = (const int*)d_in[1];
    const int* eattr = (const int*)d_in[2];
    const int* batch = (const int*)d_in[3];
    const int* xc5 = (const int*)d_in[4];
    const int* xc6 = (const int*)d_in[5];
    const int* a2c5_row = (const int*)d_in[6];
    const int* a2c6_row = (const int*)d_in[8];
    const float* atom_emb = (const float*)d_in[10];
    const float* bond_emb = (const float*)d_in[11];
    const float* cyc5 = (const float*)d_in[12];
    const float* cyc6 = (const float*)d_in[13];
    const float* eps = (const float*)d_in[14];
    const float* gw1 = (const float*)d_in[15];
    const float* gb1 = (const float*)d_in[16];
    const float* gbn_g = (const float*)d_in[17];
    const float* gbn_b = (const float*)d_in[18];
    const float* gw2 = (const float*)d_in[19];
    const float* gb2 = (const float*)d_in[20];
    const float* bn_g = (const float*)d_in[21];
    const float* bn_b = (const float*)d_in[22];
    const float* a2c5_w = (const float*)d_in[23];
    const float* a2c5_b = (const float*)d_in[24];
    const float* a2c6_w = (const float*)d_in[25];
    const float* a2c6_b = (const float*)d_in[26];
    const float* c2a5_w = (const float*)d_in[27];
    const float* c2a5_b = (const float*)d_in[28];
    const float* c2a6_w = (const float*)d_in[29];
    const float* c2a6_b = (const float*)d_in[30];
    const float* p5_w = (const float*)d_in[31];
    const float* p5_b = (const float*)d_in[32];
    const float* p6_w = (const float*)d_in[33];
    const float* p6_b = (const float*)d_in[34];
    const float* alw = (const float*)d_in[35];
    const float* alb = (const float*)d_in[36];
    const float* lw = (const float*)d_in[37];
    const float* lb = (const float*)d_in[38];
    float* out = (float*)d_out;

    float* w = (float*)d_ws;
    size_t o = 0;
    auto alloc = [&](size_t nf) {
        float* p = w + o;
        o += (nf + 63) & ~(size_t)63;
        return p;
    };
    auto allocb = [&](size_t nbf) { return (__bf16*)alloc((nbf + 1) / 2); };
    float* x = alloc((size_t)Nn * H);
    float* x5 = alloc((size_t)N5c * 5 * H);
    float* x6 = alloc((size_t)N6c * 6 * H);
    float* agg = alloc((size_t)Nn * H);
    float* stats = alloc(512);
    float* xgsum = alloc((size_t)Gg * H);
    float* gcnt = alloc(Gg);
    float* rscale5 = alloc(Nn);
    float* rscale6 = alloc(Nn);
    int* deg = (int*)alloc(Nn);
    int* rowptr = (int*)alloc(Nn + 1);
    int* rp5c = (int*)alloc(Nn + 1);
    int* rp6c = (int*)alloc(Nn + 1);
    int* woff = (int*)alloc(Nn);
    int* bsum = (int*)alloc(256);
    int* boff = (int*)alloc(256);
    unsigned int* elist = (unsigned int*)alloc(Ee);
    int* cidx5 = (int*)alloc(N5c * 5);
    int* cidx6 = (int*)alloc(N6c * 6);
    float* ebank = alloc(512 * H);
    __bf16 *g1h = allocb(3 * 128 * 256), *g1l = allocb(3 * 128 * 256);
    __bf16 *g2h = allocb(3 * 256 * 128), *g2l = allocb(3 * 256 * 128);
    __bf16 *a5h = allocb(3 * 128 * 128), *a5l = allocb(3 * 128 * 128);
    __bf16 *a6h = allocb(3 * 128 * 128), *a6l = allocb(3 * 128 * 128);
    __bf16 *c5h = allocb(3 * 128 * 128), *c5l = allocb(3 * 128 * 128);
    __bf16 *c6h = allocb(3 * 128 * 128), *c6l = allocb(3 * 128 * 128);
    __bf16 *p5h = allocb(3 * 384 * 128), *p5l = allocb(3 * 384 * 128);
    __bf16 *p6h = allocb(3 * 384 * 128), *p6l = allocb(3 * 384 * 128);

    const int TPB = 256;
    auto cdiv = [](int a, int b) { return (a + b - 1) / b; };
    int nsb = cdiv(Nn, 1024);

    // weight pre-split (h planes consumed by all GEMMs; l planes only by MLP)
    k_split<<<cdiv(3 * 128 * 256, TPB), TPB, 0, stream>>>(gw1, g1h, g1l, 3, 128, 256);
    k_split<<<cdiv(3 * 256 * 128, TPB), TPB, 0, stream>>>(gw2, g2h, g2l, 3, 256, 128);
    k_split<<<cdiv(3 * 128 * 128, TPB), TPB, 0, stream>>>(a2c5_w, a5h, a5l, 3, 128, 128);
    k_split<<<cdiv(3 * 128 * 128, TPB), TPB, 0, stream>>>(a2c6_w, a6h, a6l, 3, 128, 128);
    k_split<<<cdiv(3 * 128 * 128, TPB), TPB, 0, stream>>>(c2a5_w, c5h, c5l, 3, 128, 128);
    k_split<<<cdiv(3 * 128 * 128, TPB), TPB, 0, stream>>>(c2a6_w, c6h, c6l, 3, 128, 128);
    k_split<<<cdiv(3 * 384 * 128, TPB), TPB, 0, stream>>>(p5_w, p5h, p5l, 3, 384, 128);
    k_split<<<cdiv(3 * 384 * 128, TPB), TPB, 0, stream>>>(p6_w, p6h, p6l, 3, 384, 128);

    // edge CSR
    hipMemsetAsync(deg, 0, Nn * 4, stream);
    k_degi<<<cdiv(Ee, TPB), TPB, 0, stream>>>(ei + Ee, deg, Ee);
    k_scan1<<<nsb, 256, 0, stream>>>(deg, rowptr, bsum, Nn);
    k_scan2<<<1, 128, 0, stream>>>(bsum, boff, rowptr, nsb, Nn);
    k_scan3<<<cdiv(Nn, TPB), TPB, 0, stream>>>(rowptr, boff, Nn);
    hipMemcpyAsync(woff, rowptr, Nn * 4, hipMemcpyDeviceToDevice, stream);
    k_fill<<<cdiv(Ee, TPB), TPB, 0, stream>>>(ei, eattr, woff, elist);

    // cycle->atom CSRs + mean scales
    hipMemsetAsync(deg, 0, Nn * 4, stream);
    k_degi<<<cdiv(N5c * 5, TPB), TPB, 0, stream>>>(a2c5_row, deg, N5c * 5);
    k_scan1<<<nsb, 256, 0, stream>>>(deg, rp5c, bsum, Nn);
    k_scan2<<<1, 128, 0, stream>>>(bsum, boff, rp5c, nsb, Nn);
    k_scan3<<<cdiv(Nn, TPB), TPB, 0, stream>>>(rp5c, boff, Nn);
    k_inv_int<<<cdiv(Nn, TPB), TPB, 0, stream>>>(deg, rscale5);
    hipMemcpyAsync(woff, rp5c, Nn * 4, hipMemcpyDeviceToDevice, stream);
    k_fill_idx<<<cdiv(N5c * 5, TPB), TPB, 0, stream>>>(a2c5_row, woff, cidx5, N5c * 5);

    hipMemsetAsync(deg, 0, Nn * 4, stream);
    k_degi<<<cdiv(N6c * 6, TPB), TPB, 0, stream>>>(a2c6_row, deg, N6c * 6);
    k_scan1<<<nsb, 256, 0, stream>>>(deg, rp6c, bsum, Nn);
    k_scan2<<<1, 128, 0, stream>>>(bsum, boff, rp6c, nsb, Nn);
    k_scan3<<<cdiv(Nn, TPB), TPB, 0, stream>>>(rp6c, boff, Nn);
    k_inv_int<<<cdiv(Nn, TPB), TPB, 0, stream>>>(deg, rscale6);
    hipMemcpyAsync(woff, rp6c, Nn * 4, hipMemcpyDeviceToDevice, stream);
    k_fill_idx<<<cdiv(N6c * 6, TPB), TPB, 0, stream>>>(a2c6_row, woff, cidx6, N6c * 6);

    k_atom_enc<<<cdiv(Nn * H, TPB), TPB, 0, stream>>>(x_atom, atom_emb, x);
    k_cyc_init<<<cdiv(N5c * 5 * H, TPB), TPB, 0, stream>>>(xc5, cyc5, x5, N5c * 5);
    k_cyc_init<<<cdiv(N6c * 6 * H, TPB), TPB, 0, stream>>>(xc6, cyc6, x6, N6c * 6);

    for (int i = 0; i < Ll; ++i) {
        // GINE aggregation (gather) -> agg
        k_ebank<<<cdiv(512 * H, TPB), TPB, 0, stream>>>(
            bond_emb + (size_t)i * BF * BV * H, ebank);
        k_agg_csr<<<Nn / 2, 256, 0, stream>>>(x, rowptr, elist, ebank, eps, i, agg);

        // BN1 stats via epi-GEMM
        hipMemsetAsync(stats, 0, 512 * 4, stream);
        k_mgemm<<<dim3(cdiv(Nn, 128), 2), 256, 0, stream>>>(
            agg, g1h + (size_t)i * 128 * 256,
            gb1 + (size_t)i * 256, nullptr, nullptr, nullptr, nullptr, nullptr,
            nullptr, stats, Nn, 128, 256, 0, 128, 0, 1);

        // fused MLP -> x (pre-BN2)
        k_mlp_mfma<<<Nn / 32, 256, 0, stream>>>(
            agg, g1h + (size_t)i * 128 * 256, g1l + (size_t)i * 128 * 256,
            gb1 + (size_t)i * 256, gbn_g + (size_t)i * 256, gbn_b + (size_t)i * 256,
            g2h + (size_t)i * 256 * 128, g2l + (size_t)i * 256 * 128,
            gb2 + (size_t)i * H, stats, x);

        // BN2 + relu
        hipMemsetAsync(stats, 0, 512 * 4, stream);
        k_bn_stats<<<cdiv(Nn, 64), H, 0, stream>>>(x, stats, Nn, H, 64);
        k_bn_apply<<<cdiv(Nn * H, TPB), TPB, 0, stream>>>(
            x, stats, bn_g + (size_t)i * H, bn_b + (size_t)i * H, Nn, H);

        // atoms -> cycles (row-gather GEMM, in-place residual)
        k_mgemm<<<dim3(cdiv(N5c * 5, 128), 1), 256, 0, stream>>>(
            x, a5h + (size_t)i * 128 * 128,
            a2c5_b + (size_t)i * H, x5, x5, a2c5_row, nullptr, nullptr, nullptr,
            nullptr, N5c * 5, 128, 128, 0, 128, 1, 0);
        k_mgemm<<<dim3(cdiv(N6c * 6, 128), 1), 256, 0, stream>>>(
            x, a6h + (size_t)i * 128 * 128,
            a2c6_b + (size_t)i * H, x6, x6, a2c6_row, nullptr, nullptr, nullptr,
            nullptr, N6c * 6, 128, 128, 0, 128, 1, 0);

        // cyclic path blocks: cycle-aligned tiles, fully in-place
        k_mgemm<<<dim3(cdiv(N5c, 25), 1), 256, 0, stream>>>(
            x5, p5h + (size_t)i * 384 * 128,
            p5_b + (size_t)i * H, x5, x5, nullptr, nullptr, nullptr, nullptr,
            nullptr, N5c * 5, 384, 128, 5, 125, 1, 0);
        k_mgemm<<<dim3(cdiv(N6c, 21), 1), 256, 0, stream>>>(
            x6, p6h + (size_t)i * 384 * 128,
            p6_b + (size_t)i * H, x6, x6, nullptr, nullptr, nullptr, nullptr,
            nullptr, N6c * 6, 384, 128, 6, 126, 1, 0);

        // cycles -> atoms (CSR mean-gather fused into GEMM A-stage)
        k_mgemm<<<dim3(cdiv(Nn, 128), 1), 256, 0, stream>>>(
            x5, c5h + (size_t)i * 128 * 128,
            c2a5_b + (size_t)i * H, x, x, nullptr, rp5c, cidx5, rscale5,
            nullptr, Nn, 128, 128, 0, 128, 1, 0);
        k_mgemm<<<dim3(cdiv(Nn, 128), 1), 256, 0, stream>>>(
            x6, c6h + (size_t)i * 128 * 128,
            c2a6_b + (size_t)i * H, x, x, nullptr, rp6c, cidx6, rscale6,
            nullptr, Nn, 128, 128, 0, 128, 1, 0);
    }

    // readout
    hipMemsetAsync(xgsum, 0, (size_t)Gg * H * 4, stream);
    hipMemsetAsync(gcnt, 0, (size_t)Gg * 4, stream);
    k_seg_batch<<<cdiv(Nn, 256), H, 0, stream>>>(x, batch, xgsum, gcnt);
    k_head<<<Gg, H, 0, stream>>>(xgsum, gcnt, alw, alb, lw, lb, out);
}

// Round 10
// 2545.936 us; speedup vs baseline: 1.5816x; 1.0088x over previous
//
#include <hip/hip_runtime.h>

#define H 128
#define Nn 100000
#define Ee 250000
#define N5c 20000
#define N6c 30000
#define Gg 512
#define Ll 3
#define AF 9
#define AV 64
#define BF 3
#define BV 8
#define BN_EPS 1e-5f

typedef __bf16 v8bf __attribute__((ext_vector_type(8)));
typedef float v4f __attribute__((ext_vector_type(4)));

struct bfpair { __bf16 h, l; };
__device__ inline bfpair split2(float v) {
    bfpair r;
    r.h = (__bf16)v;
    r.l = (__bf16)(v - (float)r.h);
    return r;
}

// ---------------- init / embedding kernels ----------------

__global__ void k_atom_enc(const int* __restrict__ xa, const float* __restrict__ emb,
                           float* __restrict__ x) {
    int idx = blockIdx.x * blockDim.x + threadIdx.x;
    if (idx >= Nn * H) return;
    int n = idx >> 7, h = idx & 127;
    float s = 0.f;
#pragma unroll
    for (int f = 0; f < AF; ++f) {
        int a = xa[n * AF + f];
        s += emb[(f * AV + a) * H + h];
    }
    x[idx] = s;
}

__global__ void k_cyc_init(const int* __restrict__ xc, const float* __restrict__ emb,
                           float* __restrict__ xo, int M) {
    int idx = blockIdx.x * blockDim.x + threadIdx.x;
    if (idx >= M * H) return;
    int m = idx >> 7, h = idx & 127;
    xo[idx] = emb[xc[m] * H + h];
}

// weight pre-split: (L,K,N) fp32 row-major -> per-layer transposed [n][k] bf16 hi
__global__ void k_split(const float* __restrict__ src, __bf16* __restrict__ dh,
                        int L, int K, int N) {
    int idx = blockIdx.x * blockDim.x + threadIdx.x;
    int tot = L * K * N;
    if (idx >= tot) return;
    int l = idx / (K * N);
    int r = idx - l * (K * N);
    int k = r / N;
    int n = r - k * N;
    size_t d = (size_t)l * K * N + (size_t)n * K + k;
    dh[d] = (__bf16)src[idx];
}

// ---------------- CSR build helpers (edge + cycle maps; all static) ----------------

__global__ void k_degi(const int* __restrict__ row, int* __restrict__ deg, int M) {
    int m = blockIdx.x * blockDim.x + threadIdx.x;
    if (m >= M) return;
    atomicAdd(&deg[row[m]], 1);
}

__global__ void k_scan1(const int* __restrict__ deg, int* __restrict__ rp,
                        int* __restrict__ bsum, int n) {
    __shared__ int s[256];
    int tid = threadIdx.x;
    int base = blockIdx.x * 1024 + tid * 4;
    int v0 = (base < n) ? deg[base] : 0;
    int v1 = (base + 1 < n) ? deg[base + 1] : 0;
    int v2 = (base + 2 < n) ? deg[base + 2] : 0;
    int v3 = (base + 3 < n) ? deg[base + 3] : 0;
    int tsum = v0 + v1 + v2 + v3;
    s[tid] = tsum;
    __syncthreads();
    for (int off = 1; off < 256; off <<= 1) {
        int u = (tid >= off) ? s[tid - off] : 0;
        __syncthreads();
        s[tid] += u;
        __syncthreads();
    }
    int exc = s[tid] - tsum;
    if (base < n) rp[base] = exc;
    if (base + 1 < n) rp[base + 1] = exc + v0;
    if (base + 2 < n) rp[base + 2] = exc + v0 + v1;
    if (base + 3 < n) rp[base + 3] = exc + v0 + v1 + v2;
    if (tid == 255) bsum[blockIdx.x] = s[255];
}

__global__ void k_scan2(const int* __restrict__ bsum, int* __restrict__ boff,
                        int* __restrict__ rp, int nb, int n) {
    __shared__ int s[128];
    int tid = threadIdx.x;
    int v = (tid < nb) ? bsum[tid] : 0;
    s[tid] = v;
    __syncthreads();
    for (int off = 1; off < 128; off <<= 1) {
        int u = (tid >= off) ? s[tid - off] : 0;
        __syncthreads();
        s[tid] += u;
        __syncthreads();
    }
    if (tid < nb) boff[tid] = s[tid] - v;
    if (tid == 127) rp[n] = s[127];
}

__global__ void k_scan3(int* __restrict__ rp, const int* __restrict__ boff, int n) {
    int idx = blockIdx.x * blockDim.x + threadIdx.x;
    if (idx < n) rp[idx] += boff[idx >> 10];
}

__global__ void k_fill(const int* __restrict__ ei, const int* __restrict__ eattr,
                       int* __restrict__ woff, unsigned int* __restrict__ elist) {
    int e = blockIdx.x * blockDim.x + threadIdx.x;
    if (e >= Ee) return;
    int src = ei[e], dst = ei[Ee + e];
    int code = eattr[e * BF + 0] * 64 + eattr[e * BF + 1] * 8 + eattr[e * BF + 2];
    int p = atomicAdd(&woff[dst], 1);
    elist[p] = ((unsigned int)code << 17) | (unsigned int)src;
}

__global__ void k_fill_idx(const int* __restrict__ row, int* __restrict__ woff,
                           int* __restrict__ cidx, int M) {
    int m = blockIdx.x * blockDim.x + threadIdx.x;
    if (m >= M) return;
    int p = atomicAdd(&woff[row[m]], 1);
    cidx[p] = m;
}

__global__ void k_inv_int(const int* __restrict__ deg, float* __restrict__ rscale) {
    int r = blockIdx.x * blockDim.x + threadIdx.x;
    if (r >= Nn) return;
    rscale[r] = 1.f / fmaxf((float)deg[r], 1.f);
}

__global__ void k_ebank(const float* __restrict__ bemb, float* __restrict__ ebank) {
    int idx = blockIdx.x * blockDim.x + threadIdx.x;
    if (idx >= 512 * H) return;
    int code = idx >> 7, h = idx & 127;
    int f0 = code >> 6, f1 = (code >> 3) & 7, f2 = code & 7;
    ebank[idx] = bemb[(0 * BV + f0) * H + h] + bemb[(1 * BV + f1) * H + h]
               + bemb[(2 * BV + f2) * H + h];
}

// GINE aggregation, gather form
__global__ __launch_bounds__(256) void k_agg_csr(
    const float* __restrict__ x, const int* __restrict__ rowptr,
    const unsigned int* __restrict__ elist, const float* __restrict__ ebank,
    const float* __restrict__ eps, int layer, float* __restrict__ agg)
{
    int a = blockIdx.x * 2 + (threadIdx.x >> 7);
    int h = threadIdx.x & 127;
    float acc = (1.f + eps[layer]) * x[(size_t)a * H + h];
    int j0 = rowptr[a], j1 = rowptr[a + 1];
    for (int j = j0; j < j1; ++j) {
        unsigned int u = elist[j];
        int src = u & 0x1FFFF;
        int code = u >> 17;
        acc += fmaxf(x[(size_t)src * H + h] + ebank[code * H + h], 0.f);
    }
    agg[(size_t)a * H + h] = acc;
}

// ---------------- misc elementwise ----------------

__global__ void k_bn_apply(float* __restrict__ h, const float* __restrict__ stats,
                           const float* __restrict__ g, const float* __restrict__ b,
                           int M, int C) {
    int idx = blockIdx.x * blockDim.x + threadIdx.x;
    if (idx >= M * C) return;
    int c = idx & (C - 1);
    float mean = stats[c] / (float)M;
    float var = stats[C + c] / (float)M - mean * mean;
    float v = (h[idx] - mean) * rsqrtf(var + BN_EPS) * g[c] + b[c];
    h[idx] = fmaxf(v, 0.f);
}

// ---------------- MFMA GEMM: direct-register A, B chunked in LDS ----------------
// A(hi/lo split in-register) x B(hi). Each wave loads its own rows' A-fragments
// straight from global (no A LDS tile, no per-step barriers).
// A-modes: pathk (cyclic conv, cycle-aligned mtile, in-place safe via pre-epilogue
// barrier); grp/gcol/gscale (CSR mean-gather); rowidx; else direct (stride K).
// epi: 0 = fp32 out (+res/relu); 2 = bf16 out16 write + column stats.

__global__ __launch_bounds__(256) void k_mgemm(
    const float* __restrict__ A, const __bf16* __restrict__ Bth,
    const float* __restrict__ bias, const float* __restrict__ res,
    float* __restrict__ out, __bf16* __restrict__ out16,
    const int* __restrict__ rowidx, const int* __restrict__ grp,
    const int* __restrict__ gcol, const float* __restrict__ gscale,
    float* __restrict__ stats,
    int M, int K, int Ncol, int pathk, int mtile, int relu_flag, int epi)
{
    __shared__ __bf16 Bs[4][128][40];
    __shared__ float sS[128], sQ[128];

    int t = threadIdx.x;
    int m0 = blockIdx.x * mtile;
    int n0 = blockIdx.y * 128;
    int lane = t & 63, q = lane >> 4, lr = lane & 15;
    int wrow = (t >> 6) * 32;

    v4f acc[2][8] = {};

    int bn = t & 127;
    int ks = t >> 7;

    int rowA[2]; bool rv[2];
    const float* baseA[2];
    int gj0[2] = {0, 0}, gj1[2] = {0, 0};
    float gsc[2] = {1.f, 1.f};
    int cycb[2] = {0, 0}, pm[2] = {0, 0};
#pragma unroll
    for (int mt = 0; mt < 2; ++mt) {
        int rloc = wrow + mt * 16 + lr;
        int gm = m0 + rloc;
        rv[mt] = (rloc < mtile) && (gm < M);
        rowA[mt] = gm;
        baseA[mt] = A;
        if (rv[mt]) {
            if (grp) {
                gj0[mt] = grp[gm];
                gj1[mt] = grp[gm + 1];
                gsc[mt] = gscale[gm];
            } else if (pathk) {
                int cyc = gm / pathk;
                cycb[mt] = cyc * pathk;
                pm[mt] = gm - cycb[mt];
            } else if (rowidx) {
                baseA[mt] = A + (size_t)rowidx[gm] * H;
            } else {
                baseA[mt] = A + (size_t)gm * K;
            }
        }
    }

    auto loadA = [&](int c, int s, float (*dst)[8]) {
        int kq = (c << 7) + s * 32 + q * 8;
#pragma unroll
        for (int mt = 0; mt < 2; ++mt) {
#pragma unroll
            for (int i = 0; i < 8; ++i) dst[mt][i] = 0.f;
            if (!rv[mt]) continue;
            if (grp) {
                for (int j = gj0[mt]; j < gj1[mt]; ++j) {
                    const float* ap = A + (size_t)gcol[j] * H + kq;
                    float4 f0 = *(const float4*)ap;
                    float4 f1 = *(const float4*)(ap + 4);
                    dst[mt][0] += f0.x; dst[mt][1] += f0.y;
                    dst[mt][2] += f0.z; dst[mt][3] += f0.w;
                    dst[mt][4] += f1.x; dst[mt][5] += f1.y;
                    dst[mt][6] += f1.z; dst[mt][7] += f1.w;
                }
#pragma unroll
                for (int i = 0; i < 8; ++i) dst[mt][i] *= gsc[mt];
            } else if (pathk) {
                int pp = pm[mt] + c - 1;
                if (pp < 0) pp += pathk;
                if (pp >= pathk) pp -= pathk;
                const float* ap = A + (size_t)(cycb[mt] + pp) * H + (kq & 127);
                float4 f0 = *(const float4*)ap;
                float4 f1 = *(const float4*)(ap + 4);
                dst[mt][0] = f0.x; dst[mt][1] = f0.y;
                dst[mt][2] = f0.z; dst[mt][3] = f0.w;
                dst[mt][4] = f1.x; dst[mt][5] = f1.y;
                dst[mt][6] = f1.z; dst[mt][7] = f1.w;
            } else {
                const float* ap = baseA[mt] + kq;
                float4 f0 = *(const float4*)ap;
                float4 f1 = *(const float4*)(ap + 4);
                dst[mt][0] = f0.x; dst[mt][1] = f0.y;
                dst[mt][2] = f0.z; dst[mt][3] = f0.w;
                dst[mt][4] = f1.x; dst[mt][5] = f1.y;
                dst[mt][6] = f1.z; dst[mt][7] = f1.w;
            }
        }
    };

    float cur[2][8], nxt[2][8];
    loadA(0, 0, cur);
    int nchunk = K >> 7;
    for (int c = 0; c < nchunk; ++c) {
        __syncthreads();
        {
            int kc = c << 7;
#pragma unroll
            for (int s2 = 0; s2 < 4; ++s2) {
                const __bf16* bp = Bth + (size_t)(n0 + bn) * K + kc + s2 * 32 + ks * 16;
                *(v8bf*)&Bs[s2][bn][ks * 16] = *(const v8bf*)bp;
                *(v8bf*)&Bs[s2][bn][ks * 16 + 8] = *(const v8bf*)(bp + 8);
            }
        }
        __syncthreads();
#pragma unroll
        for (int s = 0; s < 4; ++s) {
            bool more = (s < 3) || (c + 1 < nchunk);
            if (s < 3) loadA(c, s + 1, nxt);
            else if (c + 1 < nchunk) loadA(c + 1, 0, nxt);
            v8bf ah[2], al[2];
#pragma unroll
            for (int mt = 0; mt < 2; ++mt)
#pragma unroll
                for (int i = 0; i < 8; ++i) {
                    bfpair p = split2(cur[mt][i]);
                    ah[mt][i] = p.h;
                    al[mt][i] = p.l;
                }
#pragma unroll
            for (int nt = 0; nt < 8; ++nt) {
                v8bf bh = *(v8bf*)&Bs[s][nt * 16 + lr][q * 8];
#pragma unroll
                for (int mt = 0; mt < 2; ++mt) {
                    v4f a = acc[mt][nt];
                    a = __builtin_amdgcn_mfma_f32_16x16x32_bf16(al[mt], bh, a, 0, 0, 0);
                    a = __builtin_amdgcn_mfma_f32_16x16x32_bf16(ah[mt], bh, a, 0, 0, 0);
                    acc[mt][nt] = a;
                }
            }
            if (more) {
#pragma unroll
                for (int mt = 0; mt < 2; ++mt)
#pragma unroll
                    for (int i = 0; i < 8; ++i) cur[mt][i] = nxt[mt][i];
            }
        }
    }

    if (epi == 2 && t < 128) { sS[t] = 0.f; sQ[t] = 0.f; }
    if (pathk || epi == 2) __syncthreads();

    float bcol[8];
#pragma unroll
    for (int nt = 0; nt < 8; ++nt) bcol[nt] = bias[n0 + nt * 16 + lr];

    if (epi == 0) {
#pragma unroll
        for (int mt = 0; mt < 2; ++mt)
#pragma unroll
            for (int reg = 0; reg < 4; ++reg) {
                int rloc = wrow + mt * 16 + q * 4 + reg;
                int rm = m0 + rloc;
                if (rloc < mtile && rm < M) {
#pragma unroll
                    for (int nt = 0; nt < 8; ++nt) {
                        int cn = nt * 16 + lr;
                        float v = acc[mt][nt][reg] + bcol[nt];
                        if (relu_flag) v = fmaxf(v, 0.f);
                        if (res) v += res[(size_t)rm * Ncol + n0 + cn];
                        out[(size_t)rm * Ncol + n0 + cn] = v;
                    }
                }
            }
    } else {  // epi == 2: bf16 write + stats
#pragma unroll
        for (int nt = 0; nt < 8; ++nt) {
            int cn = nt * 16 + lr;
            float s = 0.f, q2 = 0.f;
#pragma unroll
            for (int mt = 0; mt < 2; ++mt)
#pragma unroll
                for (int reg = 0; reg < 4; ++reg) {
                    int rloc = wrow + mt * 16 + q * 4 + reg;
                    int rm = m0 + rloc;
                    if (rloc < mtile && rm < M) {
                        float v = acc[mt][nt][reg] + bcol[nt];
                        out16[(size_t)rm * Ncol + n0 + cn] = (__bf16)v;
                        s += v;
                        q2 += v * v;
                    }
                }
            atomicAdd(&sS[cn], s);
            atomicAdd(&sQ[cn], q2);
        }
        __syncthreads();
        if (t < 128) {
            atomicAdd(&stats[n0 + t], sS[t]);
            atomicAdd(&stats[Ncol + n0 + t], sQ[t]);
        }
    }
}

// ---------------- MLP pass B: x = relu(BN1(h1')) @ gw2 + gb2, + BN2 stats ----------
// A16 = h1' bf16 [M][256] (biased, pre-BN); BN1 fold (sc/sh) applied in-register.
// In-place safe on x: each wave reads/writes only its own 32 rows.

__global__ __launch_bounds__(256) void k_mgemm_bn(
    const __bf16* __restrict__ A16, const __bf16* __restrict__ Bth,
    const float* __restrict__ gb2, const float* __restrict__ statsIn,
    const float* __restrict__ gbn_g, const float* __restrict__ gbn_b,
    float* __restrict__ outx, float* __restrict__ stats2, int M)
{
    __shared__ __bf16 Bs[4][128][40];
    __shared__ float scS[256], shS[256];
    __shared__ float sS[128], sQ[128];

    int t = threadIdx.x;
    int m0 = blockIdx.x * 128;
    int lane = t & 63, q = lane >> 4, lr = lane & 15;
    int wrow = (t >> 6) * 32;

    {
        float mean = statsIn[t] * (1.f / (float)Nn);
        float var = statsIn[256 + t] * (1.f / (float)Nn) - mean * mean;
        float s = gbn_g[t] * rsqrtf(var + BN_EPS);
        scS[t] = s;
        shS[t] = gbn_b[t] - mean * s;
    }
    if (t < 128) { sS[t] = 0.f; sQ[t] = 0.f; }

    v4f acc[2][8] = {};
    int bn = t & 127;
    int ks = t >> 7;

    int rowA[2]; bool rv[2];
#pragma unroll
    for (int mt = 0; mt < 2; ++mt) {
        int gm = m0 + wrow + mt * 16 + lr;
        rv[mt] = (gm < M);
        rowA[mt] = gm;
    }

    for (int c = 0; c < 2; ++c) {
        int kc = c << 7;
        __syncthreads();  // covers scS/shS on c==0, Bs reuse on c==1
#pragma unroll
        for (int s2 = 0; s2 < 4; ++s2) {
            const __bf16* bp = Bth + (size_t)bn * 256 + kc + s2 * 32 + ks * 16;
            *(v8bf*)&Bs[s2][bn][ks * 16] = *(const v8bf*)bp;
            *(v8bf*)&Bs[s2][bn][ks * 16 + 8] = *(const v8bf*)(bp + 8);
        }
        __syncthreads();
#pragma unroll
        for (int s = 0; s < 4; ++s) {
            int kq = kc + s * 32 + q * 8;
            v8bf ah[2], al[2];
#pragma unroll
            for (int mt = 0; mt < 2; ++mt) {
                float tv[8];
                if (rv[mt]) {
                    v8bf hv = *(const v8bf*)(A16 + (size_t)rowA[mt] * 256 + kq);
                    float4 c0 = *(float4*)&scS[kq];
                    float4 c1 = *(float4*)&scS[kq + 4];
                    float4 h0 = *(float4*)&shS[kq];
                    float4 h1 = *(float4*)&shS[kq + 4];
                    tv[0] = fmaxf((float)hv[0] * c0.x + h0.x, 0.f);
                    tv[1] = fmaxf((float)hv[1] * c0.y + h0.y, 0.f);
                    tv[2] = fmaxf((float)hv[2] * c0.z + h0.z, 0.f);
                    tv[3] = fmaxf((float)hv[3] * c0.w + h0.w, 0.f);
                    tv[4] = fmaxf((float)hv[4] * c1.x + h1.x, 0.f);
                    tv[5] = fmaxf((float)hv[5] * c1.y + h1.y, 0.f);
                    tv[6] = fmaxf((float)hv[6] * c1.z + h1.z, 0.f);
                    tv[7] = fmaxf((float)hv[7] * c1.w + h1.w, 0.f);
                } else {
#pragma unroll
                    for (int i = 0; i < 8; ++i) tv[i] = 0.f;
                }
#pragma unroll
                for (int i = 0; i < 8; ++i) {
                    bfpair p = split2(tv[i]);
                    ah[mt][i] = p.h;
                    al[mt][i] = p.l;
                }
            }
#pragma unroll
            for (int nt = 0; nt < 8; ++nt) {
                v8bf bh = *(v8bf*)&Bs[s][nt * 16 + lr][q * 8];
#pragma unroll
                for (int mt = 0; mt < 2; ++mt) {
                    v4f a = acc[mt][nt];
                    a = __builtin_amdgcn_mfma_f32_16x16x32_bf16(al[mt], bh, a, 0, 0, 0);
                    a = __builtin_amdgcn_mfma_f32_16x16x32_bf16(ah[mt], bh, a, 0, 0, 0);
                    acc[mt][nt] = a;
                }
            }
        }
    }

    __syncthreads();  // sS/sQ init visible; all A16 reads complete
    float bcol[8];
#pragma unroll
    for (int nt = 0; nt < 8; ++nt) bcol[nt] = gb2[nt * 16 + lr];
#pragma unroll
    for (int nt = 0; nt < 8; ++nt) {
        int cn = nt * 16 + lr;
        float s = 0.f, q2 = 0.f;
#pragma unroll
        for (int mt = 0; mt < 2; ++mt)
#pragma unroll
            for (int reg = 0; reg < 4; ++reg) {
                int rm = m0 + wrow + mt * 16 + q * 4 + reg;
                if (rm < M) {
                    float v = acc[mt][nt][reg] + bcol[nt];
                    outx[(size_t)rm * H + cn] = v;
                    s += v;
                    q2 += v * v;
                }
            }
        atomicAdd(&sS[cn], s);
        atomicAdd(&sQ[cn], q2);
    }
    __syncthreads();
    if (t < 128) {
        atomicAdd(&stats2[t], sS[t]);
        atomicAdd(&stats2[128 + t], sQ[t]);
    }
}

// ---------------- readout ----------------

__global__ void k_seg_batch(const float* __restrict__ x, const int* __restrict__ batch,
                            float* __restrict__ xgsum, float* __restrict__ gcnt) {
    int h = threadIdx.x;
    int r0 = blockIdx.x * 256;
    if (r0 >= Nn) return;
    int r1 = min(r0 + 256, Nn);
    int cur = batch[r0];
    float acc = 0.f, c = 0.f;
    for (int r = r0; r < r1; ++r) {
        int b = batch[r];
        if (b != cur) {
            atomicAdd(&xgsum[cur * H + h], acc);
            if (h == 0) atomicAdd(&gcnt[cur], c);
            acc = 0.f;
            c = 0.f;
            cur = b;
        }
        acc += x[r * H + h];
        c += 1.f;
    }
    atomicAdd(&xgsum[cur * H + h], acc);
    if (h == 0) atomicAdd(&gcnt[cur], c);
}

__global__ void k_head(const float* __restrict__ xgsum, const float* __restrict__ gcnt,
                       const float* __restrict__ alw, const float* __restrict__ alb,
                       const float* __restrict__ lw, const float* __restrict__ lb,
                       float* __restrict__ out) {
    __shared__ float mean[H];
    __shared__ float red[H];
    int g = blockIdx.x, j = threadIdx.x;
    mean[j] = xgsum[g * H + j] / fmaxf(gcnt[g], 1.f);
    __syncthreads();
    float acc = alb[j];
    for (int k = 0; k < H; ++k) acc += mean[k] * alw[k * H + j];
    acc = fmaxf(acc, 0.f) * lw[j];
    red[j] = acc;
    __syncthreads();
    for (int s = 64; s > 0; s >>= 1) {
        if (j < s) red[j] += red[j + s];
        __syncthreads();
    }
    if (j == 0) out[g] = red[0] + lb[0];
}

// ---------------- host ----------------

extern "C" void kernel_launch(void* const* d_in, const int* in_sizes, int n_in,
                              void* d_out, int out_size, void* d_ws, size_t ws_size,
                              hipStream_t stream) {
    const int* x_atom = (const int*)d_in[0];
    const int* ei = (const int*)d_in[1];
    const int* eattr = (const int*)d_in[2];
    const int* batch = (const int*)d_in[3];
    const int* xc5 = (const int*)d_in[4];
    const int* xc6 = (const int*)d_in[5];
    const int* a2c5_row = (const int*)d_in[6];
    const int* a2c6_row = (const int*)d_in[8];
    const float* atom_emb = (const float*)d_in[10];
    const float* bond_emb = (const float*)d_in[11];
    const float* cyc5 = (const float*)d_in[12];
    const float* cyc6 = (const float*)d_in[13];
    const float* eps = (const float*)d_in[14];
    const float* gw1 = (const float*)d_in[15];
    const float* gb1 = (const float*)d_in[16];
    const float* gbn_g = (const float*)d_in[17];
    const float* gbn_b = (const float*)d_in[18];
    const float* gw2 = (const float*)d_in[19];
    const float* gb2 = (const float*)d_in[20];
    const float* bn_g = (const float*)d_in[21];
    const float* bn_b = (const float*)d_in[22];
    const float* a2c5_w = (const float*)d_in[23];
    const float* a2c5_b = (const float*)d_in[24];
    const float* a2c6_w = (const float*)d_in[25];
    const float* a2c6_b = (const float*)d_in[26];
    const float* c2a5_w = (const float*)d_in[27];
    const float* c2a5_b = (const float*)d_in[28];
    const float* c2a6_w = (const float*)d_in[29];
    const float* c2a6_b = (const float*)d_in[30];
    const float* p5_w = (const float*)d_in[31];
    const float* p5_b = (const float*)d_in[32];
    const float* p6_w = (const float*)d_in[33];
    const float* p6_b = (const float*)d_in[34];
    const float* alw = (const float*)d_in[35];
    const float* alb = (const float*)d_in[36];
    const float* lw = (const float*)d_in[37];
    const float* lb = (const float*)d_in[38];
    float* out = (float*)d_out;

    float* w = (float*)d_ws;
    size_t o = 0;
    auto alloc = [&](size_t nf) {
        float* p = w + o;
        o += (nf + 63) & ~(size_t)63;
        return p;
    };
    auto allocb = [&](size_t nbf) { return (__bf16*)alloc((nbf + 1) / 2); };
    float* x = alloc((size_t)Nn * H);   // also holds h1' bf16 (Nn x 256) during MLP
    float* x5 = alloc((size_t)N5c * 5 * H);
    float* x6 = alloc((size_t)N6c * 6 * H);
    float* agg = alloc((size_t)Nn * H);
    float* stats = alloc(512);
    float* stats2 = alloc(256);
    float* xgsum = alloc((size_t)Gg * H);
    float* gcnt = alloc(Gg);
    float* rscale5 = alloc(Nn);
    float* rscale6 = alloc(Nn);
    int* deg = (int*)alloc(Nn);
    int* rowptr = (int*)alloc(Nn + 1);
    int* rp5c = (int*)alloc(Nn + 1);
    int* rp6c = (int*)alloc(Nn + 1);
    int* woff = (int*)alloc(Nn);
    int* bsum = (int*)alloc(256);
    int* boff = (int*)alloc(256);
    unsigned int* elist = (unsigned int*)alloc(Ee);
    int* cidx5 = (int*)alloc(N5c * 5);
    int* cidx6 = (int*)alloc(N6c * 6);
    float* ebank = alloc(512 * H);
    __bf16* g1h = allocb(3 * 128 * 256);
    __bf16* g2h = allocb(3 * 256 * 128);
    __bf16* a5h = allocb(3 * 128 * 128);
    __bf16* a6h = allocb(3 * 128 * 128);
    __bf16* c5h = allocb(3 * 128 * 128);
    __bf16* c6h = allocb(3 * 128 * 128);
    __bf16* p5h = allocb(3 * 384 * 128);
    __bf16* p6h = allocb(3 * 384 * 128);

    const int TPB = 256;
    auto cdiv = [](int a, int b) { return (a + b - 1) / b; };
    int nsb = cdiv(Nn, 1024);

    // weight pre-split (transposed bf16 hi planes)
    k_split<<<cdiv(3 * 128 * 256, TPB), TPB, 0, stream>>>(gw1, g1h, 3, 128, 256);
    k_split<<<cdiv(3 * 256 * 128, TPB), TPB, 0, stream>>>(gw2, g2h, 3, 256, 128);
    k_split<<<cdiv(3 * 128 * 128, TPB), TPB, 0, stream>>>(a2c5_w, a5h, 3, 128, 128);
    k_split<<<cdiv(3 * 128 * 128, TPB), TPB, 0, stream>>>(a2c6_w, a6h, 3, 128, 128);
    k_split<<<cdiv(3 * 128 * 128, TPB), TPB, 0, stream>>>(c2a5_w, c5h, 3, 128, 128);
    k_split<<<cdiv(3 * 128 * 128, TPB), TPB, 0, stream>>>(c2a6_w, c6h, 3, 128, 128);
    k_split<<<cdiv(3 * 384 * 128, TPB), TPB, 0, stream>>>(p5_w, p5h, 3, 384, 128);
    k_split<<<cdiv(3 * 384 * 128, TPB), TPB, 0, stream>>>(p6_w, p6h, 3, 384, 128);

    // edge CSR
    hipMemsetAsync(deg, 0, Nn * 4, stream);
    k_degi<<<cdiv(Ee, TPB), TPB, 0, stream>>>(ei + Ee, deg, Ee);
    k_scan1<<<nsb, 256, 0, stream>>>(deg, rowptr, bsum, Nn);
    k_scan2<<<1, 128, 0, stream>>>(bsum, boff, rowptr, nsb, Nn);
    k_scan3<<<cdiv(Nn, TPB), TPB, 0, stream>>>(rowptr, boff, Nn);
    hipMemcpyAsync(woff, rowptr, Nn * 4, hipMemcpyDeviceToDevice, stream);
    k_fill<<<cdiv(Ee, TPB), TPB, 0, stream>>>(ei, eattr, woff, elist);

    // cycle->atom CSRs + mean scales
    hipMemsetAsync(deg, 0, Nn * 4, stream);
    k_degi<<<cdiv(N5c * 5, TPB), TPB, 0, stream>>>(a2c5_row, deg, N5c * 5);
    k_scan1<<<nsb, 256, 0, stream>>>(deg, rp5c, bsum, Nn);
    k_scan2<<<1, 128, 0, stream>>>(bsum, boff, rp5c, nsb, Nn);
    k_scan3<<<cdiv(Nn, TPB), TPB, 0, stream>>>(rp5c, boff, Nn);
    k_inv_int<<<cdiv(Nn, TPB), TPB, 0, stream>>>(deg, rscale5);
    hipMemcpyAsync(woff, rp5c, Nn * 4, hipMemcpyDeviceToDevice, stream);
    k_fill_idx<<<cdiv(N5c * 5, TPB), TPB, 0, stream>>>(a2c5_row, woff, cidx5, N5c * 5);

    hipMemsetAsync(deg, 0, Nn * 4, stream);
    k_degi<<<cdiv(N6c * 6, TPB), TPB, 0, stream>>>(a2c6_row, deg, N6c * 6);
    k_scan1<<<nsb, 256, 0, stream>>>(deg, rp6c, bsum, Nn);
    k_scan2<<<1, 128, 0, stream>>>(bsum, boff, rp6c, nsb, Nn);
    k_scan3<<<cdiv(Nn, TPB), TPB, 0, stream>>>(rp6c, boff, Nn);
    k_inv_int<<<cdiv(Nn, TPB), TPB, 0, stream>>>(deg, rscale6);
    hipMemcpyAsync(woff, rp6c, Nn * 4, hipMemcpyDeviceToDevice, stream);
    k_fill_idx<<<cdiv(N6c * 6, TPB), TPB, 0, stream>>>(a2c6_row, woff, cidx6, N6c * 6);

    k_atom_enc<<<cdiv(Nn * H, TPB), TPB, 0, stream>>>(x_atom, atom_emb, x);
    k_cyc_init<<<cdiv(N5c * 5 * H, TPB), TPB, 0, stream>>>(xc5, cyc5, x5, N5c * 5);
    k_cyc_init<<<cdiv(N6c * 6 * H, TPB), TPB, 0, stream>>>(xc6, cyc6, x6, N6c * 6);

    for (int i = 0; i < Ll; ++i) {
        // GINE aggregation (gather) -> agg
        k_ebank<<<cdiv(512 * H, TPB), TPB, 0, stream>>>(
            bond_emb + (size_t)i * BF * BV * H, ebank);
        k_agg_csr<<<Nn / 2, 256, 0, stream>>>(x, rowptr, elist, ebank, eps, i, agg);

        // MLP pass A: h1' = agg@gw1 + gb1 -> bf16 into x (dead), + BN1 stats
        hipMemsetAsync(stats, 0, 512 * 4, stream);
        k_mgemm<<<dim3(cdiv(Nn, 128), 2), 256, 0, stream>>>(
            agg, g1h + (size_t)i * 128 * 256, gb1 + (size_t)i * 256,
            nullptr, nullptr, (__bf16*)x, nullptr, nullptr, nullptr, nullptr,
            stats, Nn, 128, 256, 0, 128, 0, 2);

        // MLP pass B: x = relu(BN1(h1')) @ gw2 + gb2 (pre-BN2), + BN2 stats
        hipMemsetAsync(stats2, 0, 256 * 4, stream);
        k_mgemm_bn<<<cdiv(Nn, 128), 256, 0, stream>>>(
            (const __bf16*)x, g2h + (size_t)i * 256 * 128, gb2 + (size_t)i * H,
            stats, gbn_g + (size_t)i * 256, gbn_b + (size_t)i * 256,
            x, stats2, Nn);

        // BN2 + relu
        k_bn_apply<<<cdiv(Nn * H, TPB), TPB, 0, stream>>>(
            x, stats2, bn_g + (size_t)i * H, bn_b + (size_t)i * H, Nn, H);

        // atoms -> cycles (row-gather GEMM, in-place residual)
        k_mgemm<<<dim3(cdiv(N5c * 5, 128), 1), 256, 0, stream>>>(
            x, a5h + (size_t)i * 128 * 128, a2c5_b + (size_t)i * H,
            x5, x5, nullptr, a2c5_row, nullptr, nullptr, nullptr,
            nullptr, N5c * 5, 128, 128, 0, 128, 1, 0);
        k_mgemm<<<dim3(cdiv(N6c * 6, 128), 1), 256, 0, stream>>>(
            x, a6h + (size_t)i * 128 * 128, a2c6_b + (size_t)i * H,
            x6, x6, nullptr, a2c6_row, nullptr, nullptr, nullptr,
            nullptr, N6c * 6, 128, 128, 0, 128, 1, 0);

        // cyclic path blocks: cycle-aligned tiles, fully in-place
        k_mgemm<<<dim3(cdiv(N5c, 25), 1), 256, 0, stream>>>(
            x5, p5h + (size_t)i * 384 * 128, p5_b + (size_t)i * H,
            x5, x5, nullptr, nullptr, nullptr, nullptr, nullptr,
            nullptr, N5c * 5, 384, 128, 5, 125, 1, 0);
        k_mgemm<<<dim3(cdiv(N6c, 21), 1), 256, 0, stream>>>(
            x6, p6h + (size_t)i * 384 * 128, p6_b + (size_t)i * H,
            x6, x6, nullptr, nullptr, nullptr, nullptr, nullptr,
            nullptr, N6c * 6, 384, 128, 6, 126, 1, 0);

        // cycles -> atoms (CSR mean-gather fused into A-load)
        k_mgemm<<<dim3(cdiv(Nn, 128), 1), 256, 0, stream>>>(
            x5, c5h + (size_t)i * 128 * 128, c2a5_b + (size_t)i * H,
            x, x, nullptr, nullptr, rp5c, cidx5, rscale5,
            nullptr, Nn, 128, 128, 0, 128, 1, 0);
        k_mgemm<<<dim3(cdiv(Nn, 128), 1), 256, 0, stream>>>(
            x6, c6h + (size_t)i * 128 * 128, c2a6_b + (size_t)i * H,
            x, x, nullptr, nullptr, rp6c, cidx6, rscale6,
            nullptr, Nn, 128, 128, 0, 128, 1, 0);
    }

    // readout
    hipMemsetAsync(xgsum, 0, (size_t)Gg * H * 4, stream);
    hipMemsetAsync(gcnt, 0, (size_t)Gg * 4, stream);
    k_seg_batch<<<cdiv(Nn, 256), H, 0, stream>>>(x, batch, xgsum, gcnt);
    k_head<<<Gg, H, 0, stream>>>(xgsum, gcnt, alw, alb, lw, lb, out);
}

// Round 11
// 2520.594 us; speedup vs baseline: 1.5975x; 1.0101x over previous
//
#include <hip/hip_runtime.h>

#define H 128
#define Nn 100000
#define Ee 250000
#define N5c 20000
#define N6c 30000
#define Gg 512
#define Ll 3
#define AF 9
#define AV 64
#define BF 3
#define BV 8
#define BN_EPS 1e-5f

typedef __bf16 v8bf __attribute__((ext_vector_type(8)));
typedef float v4f __attribute__((ext_vector_type(4)));

struct bfpair { __bf16 h, l; };
__device__ inline bfpair split2(float v) {
    bfpair r;
    r.h = (__bf16)v;
    r.l = (__bf16)(v - (float)r.h);
    return r;
}

// ---------------- init / embedding kernels ----------------

__global__ void k_atom_enc(const int* __restrict__ xa, const float* __restrict__ emb,
                           float* __restrict__ x) {
    int idx = blockIdx.x * blockDim.x + threadIdx.x;
    if (idx >= Nn * H) return;
    int n = idx >> 7, h = idx & 127;
    float s = 0.f;
#pragma unroll
    for (int f = 0; f < AF; ++f) {
        int a = xa[n * AF + f];
        s += emb[(f * AV + a) * H + h];
    }
    x[idx] = s;
}

__global__ void k_cyc_init(const int* __restrict__ xc, const float* __restrict__ emb,
                           float* __restrict__ xo, int M) {
    int idx = blockIdx.x * blockDim.x + threadIdx.x;
    if (idx >= M * H) return;
    int m = idx >> 7, h = idx & 127;
    xo[idx] = emb[xc[m] * H + h];
}

// weight pre-split: (L,K,N) fp32 row-major -> per-layer transposed [n][k] bf16 hi
__global__ void k_split(const float* __restrict__ src, __bf16* __restrict__ dh,
                        int L, int K, int N) {
    int idx = blockIdx.x * blockDim.x + threadIdx.x;
    int tot = L * K * N;
    if (idx >= tot) return;
    int l = idx / (K * N);
    int r = idx - l * (K * N);
    int k = r / N;
    int n = r - k * N;
    size_t d = (size_t)l * K * N + (size_t)n * K + k;
    dh[d] = (__bf16)src[idx];
}

// ---------------- CSR build helpers (edge + cycle maps; all static) ----------------

__global__ void k_degi(const int* __restrict__ row, int* __restrict__ deg, int M) {
    int m = blockIdx.x * blockDim.x + threadIdx.x;
    if (m >= M) return;
    atomicAdd(&deg[row[m]], 1);
}

__global__ void k_scan1(const int* __restrict__ deg, int* __restrict__ rp,
                        int* __restrict__ bsum, int n) {
    __shared__ int s[256];
    int tid = threadIdx.x;
    int base = blockIdx.x * 1024 + tid * 4;
    int v0 = (base < n) ? deg[base] : 0;
    int v1 = (base + 1 < n) ? deg[base + 1] : 0;
    int v2 = (base + 2 < n) ? deg[base + 2] : 0;
    int v3 = (base + 3 < n) ? deg[base + 3] : 0;
    int tsum = v0 + v1 + v2 + v3;
    s[tid] = tsum;
    __syncthreads();
    for (int off = 1; off < 256; off <<= 1) {
        int u = (tid >= off) ? s[tid - off] : 0;
        __syncthreads();
        s[tid] += u;
        __syncthreads();
    }
    int exc = s[tid] - tsum;
    if (base < n) rp[base] = exc;
    if (base + 1 < n) rp[base + 1] = exc + v0;
    if (base + 2 < n) rp[base + 2] = exc + v0 + v1;
    if (base + 3 < n) rp[base + 3] = exc + v0 + v1 + v2;
    if (tid == 255) bsum[blockIdx.x] = s[255];
}

__global__ void k_scan2(const int* __restrict__ bsum, int* __restrict__ boff,
                        int* __restrict__ rp, int nb, int n) {
    __shared__ int s[128];
    int tid = threadIdx.x;
    int v = (tid < nb) ? bsum[tid] : 0;
    s[tid] = v;
    __syncthreads();
    for (int off = 1; off < 128; off <<= 1) {
        int u = (tid >= off) ? s[tid - off] : 0;
        __syncthreads();
        s[tid] += u;
        __syncthreads();
    }
    if (tid < nb) boff[tid] = s[tid] - v;
    if (tid == 127) rp[n] = s[127];
}

__global__ void k_scan3(int* __restrict__ rp, const int* __restrict__ boff, int n) {
    int idx = blockIdx.x * blockDim.x + threadIdx.x;
    if (idx < n) rp[idx] += boff[idx >> 10];
}

__global__ void k_fill(const int* __restrict__ ei, const int* __restrict__ eattr,
                       int* __restrict__ woff, unsigned int* __restrict__ elist) {
    int e = blockIdx.x * blockDim.x + threadIdx.x;
    if (e >= Ee) return;
    int src = ei[e], dst = ei[Ee + e];
    int code = eattr[e * BF + 0] * 64 + eattr[e * BF + 1] * 8 + eattr[e * BF + 2];
    int p = atomicAdd(&woff[dst], 1);
    elist[p] = ((unsigned int)code << 17) | (unsigned int)src;
}

__global__ void k_fill_idx(const int* __restrict__ row, int* __restrict__ woff,
                           int* __restrict__ cidx, int M) {
    int m = blockIdx.x * blockDim.x + threadIdx.x;
    if (m >= M) return;
    int p = atomicAdd(&woff[row[m]], 1);
    cidx[p] = m;
}

__global__ void k_inv_int(const int* __restrict__ deg, float* __restrict__ rscale) {
    int r = blockIdx.x * blockDim.x + threadIdx.x;
    if (r >= Nn) return;
    rscale[r] = 1.f / fmaxf((float)deg[r], 1.f);
}

__global__ void k_ebank(const float* __restrict__ bemb, float* __restrict__ ebank) {
    int idx = blockIdx.x * blockDim.x + threadIdx.x;
    if (idx >= 512 * H) return;
    int code = idx >> 7, h = idx & 127;
    int f0 = code >> 6, f1 = (code >> 3) & 7, f2 = code & 7;
    ebank[idx] = bemb[(0 * BV + f0) * H + h] + bemb[(1 * BV + f1) * H + h]
               + bemb[(2 * BV + f2) * H + h];
}

// GINE aggregation, gather form
__global__ __launch_bounds__(256) void k_agg_csr(
    const float* __restrict__ x, const int* __restrict__ rowptr,
    const unsigned int* __restrict__ elist, const float* __restrict__ ebank,
    const float* __restrict__ eps, int layer, float* __restrict__ agg)
{
    int a = blockIdx.x * 2 + (threadIdx.x >> 7);
    int h = threadIdx.x & 127;
    float acc = (1.f + eps[layer]) * x[(size_t)a * H + h];
    int j0 = rowptr[a], j1 = rowptr[a + 1];
    for (int j = j0; j < j1; ++j) {
        unsigned int u = elist[j];
        int src = u & 0x1FFFF;
        int code = u >> 17;
        acc += fmaxf(x[(size_t)src * H + h] + ebank[code * H + h], 0.f);
    }
    agg[(size_t)a * H + h] = acc;
}

// ---------------- MFMA GEMM: direct-register A + B, 64-K LDS chunks ----------------
// A(hi/lo split in-register) x B(hi). A and B both register-prefetched one step
// ahead; between barriers only LDS stores remain. LDS ~22.5 KB -> 5+ blocks/CU.
// A-modes: pathk (cyclic conv, cycle-aligned mtile, in-place safe via pre-epilogue
// barrier); grp/gcol/gscale (CSR mean-gather); rowidx; else direct (stride K).
// epi: 0 = fp32 out (+res/relu); 2 = bf16 out16 write + column stats.
// bnmode: 1 = folded BN+relu on A-loads (K==128); 2 = folded BN+relu on res read.

__global__ __launch_bounds__(256) void k_mgemm(
    const float* __restrict__ A, const __bf16* __restrict__ Bth,
    const float* __restrict__ bias, const float* __restrict__ res,
    float* __restrict__ out, __bf16* __restrict__ out16,
    const int* __restrict__ rowidx, const int* __restrict__ grp,
    const int* __restrict__ gcol, const float* __restrict__ gscale,
    float* __restrict__ stats,
    const float* __restrict__ bnstats, const float* __restrict__ bng,
    const float* __restrict__ bnb,
    int M, int K, int Ncol, int pathk, int mtile, int relu_flag, int epi, int bnmode)
{
    __shared__ __bf16 Bs[2][128][40];
    __shared__ float sS[128], sQ[128];
    __shared__ float scB[128], shB[128];

    int t = threadIdx.x;
    int m0 = blockIdx.x * mtile;
    int n0 = blockIdx.y * 128;
    int lane = t & 63, q = lane >> 4, lr = lane & 15;
    int wrow = (t >> 6) * 32;

    if (bnmode) {
        if (t < 128) {
            float mean = bnstats[t] * (1.f / (float)Nn);
            float var = bnstats[128 + t] * (1.f / (float)Nn) - mean * mean;
            float s = bng[t] * rsqrtf(var + BN_EPS);
            scB[t] = s;
            shB[t] = bnb[t] - mean * s;
        }
        if (bnmode == 1) __syncthreads();  // A-loads (prefetched below) need scB
    }

    v4f acc[2][8] = {};

    int bn = t & 127;
    int ks = t >> 7;  // 0/1

    bool rv[2];
    const float* baseA[2];
    int gj0[2] = {0, 0}, gj1[2] = {0, 0};
    float gsc[2] = {1.f, 1.f};
    int cycb[2] = {0, 0}, pm[2] = {0, 0};
#pragma unroll
    for (int mt = 0; mt < 2; ++mt) {
        int rloc = wrow + mt * 16 + lr;
        int gm = m0 + rloc;
        rv[mt] = (rloc < mtile) && (gm < M);
        baseA[mt] = A;
        if (rv[mt]) {
            if (grp) {
                gj0[mt] = grp[gm];
                gj1[mt] = grp[gm + 1];
                gsc[mt] = gscale[gm];
            } else if (pathk) {
                int cyc = gm / pathk;
                cycb[mt] = cyc * pathk;
                pm[mt] = gm - cycb[mt];
            } else if (rowidx) {
                baseA[mt] = A + (size_t)rowidx[gm] * H;
            } else {
                baseA[mt] = A + (size_t)gm * K;
            }
        }
    }

    auto loadA = [&](int c, int s, float (*dst)[8]) {
        int kq = (c << 6) + s * 32 + q * 8;
#pragma unroll
        for (int mt = 0; mt < 2; ++mt) {
#pragma unroll
            for (int i = 0; i < 8; ++i) dst[mt][i] = 0.f;
            if (!rv[mt]) continue;
            if (grp) {
                for (int j = gj0[mt]; j < gj1[mt]; ++j) {
                    const float* ap = A + (size_t)gcol[j] * H + kq;
                    float4 f0 = *(const float4*)ap;
                    float4 f1 = *(const float4*)(ap + 4);
                    dst[mt][0] += f0.x; dst[mt][1] += f0.y;
                    dst[mt][2] += f0.z; dst[mt][3] += f0.w;
                    dst[mt][4] += f1.x; dst[mt][5] += f1.y;
                    dst[mt][6] += f1.z; dst[mt][7] += f1.w;
                }
#pragma unroll
                for (int i = 0; i < 8; ++i) dst[mt][i] *= gsc[mt];
            } else if (pathk) {
                int pp = pm[mt] + (kq >> 7) - 1;
                if (pp < 0) pp += pathk;
                if (pp >= pathk) pp -= pathk;
                const float* ap = A + (size_t)(cycb[mt] + pp) * H + (kq & 127);
                float4 f0 = *(const float4*)ap;
                float4 f1 = *(const float4*)(ap + 4);
                dst[mt][0] = f0.x; dst[mt][1] = f0.y;
                dst[mt][2] = f0.z; dst[mt][3] = f0.w;
                dst[mt][4] = f1.x; dst[mt][5] = f1.y;
                dst[mt][6] = f1.z; dst[mt][7] = f1.w;
            } else {
                const float* ap = baseA[mt] + kq;
                float4 f0 = *(const float4*)ap;
                float4 f1 = *(const float4*)(ap + 4);
                dst[mt][0] = f0.x; dst[mt][1] = f0.y;
                dst[mt][2] = f0.z; dst[mt][3] = f0.w;
                dst[mt][4] = f1.x; dst[mt][5] = f1.y;
                dst[mt][6] = f1.z; dst[mt][7] = f1.w;
            }
            if (bnmode == 1) {
#pragma unroll
                for (int i = 0; i < 8; ++i)
                    dst[mt][i] = fmaxf(dst[mt][i] * scB[kq + i] + shB[kq + i], 0.f);
            }
        }
    };

    v8bf vb[2][2];
    auto loadBreg = [&](int c) {
#pragma unroll
        for (int s2 = 0; s2 < 2; ++s2) {
            const __bf16* bp = Bth + (size_t)(n0 + bn) * K + (c << 6) + s2 * 32 + ks * 16;
            vb[s2][0] = *(const v8bf*)bp;
            vb[s2][1] = *(const v8bf*)(bp + 8);
        }
    };

    float cur[2][8], nxt[2][8];
    loadBreg(0);
    loadA(0, 0, cur);
    int nchunk = K >> 6;
    for (int c = 0; c < nchunk; ++c) {
        __syncthreads();
#pragma unroll
        for (int s2 = 0; s2 < 2; ++s2) {
            *(v8bf*)&Bs[s2][bn][ks * 16] = vb[s2][0];
            *(v8bf*)&Bs[s2][bn][ks * 16 + 8] = vb[s2][1];
        }
        __syncthreads();
        if (c + 1 < nchunk) loadBreg(c + 1);
#pragma unroll
        for (int s = 0; s < 2; ++s) {
            bool more = (s < 1) || (c + 1 < nchunk);
            if (s < 1) loadA(c, 1, nxt);
            else if (c + 1 < nchunk) loadA(c + 1, 0, nxt);
            v8bf ah[2], al[2];
#pragma unroll
            for (int mt = 0; mt < 2; ++mt)
#pragma unroll
                for (int i = 0; i < 8; ++i) {
                    bfpair p = split2(cur[mt][i]);
                    ah[mt][i] = p.h;
                    al[mt][i] = p.l;
                }
#pragma unroll
            for (int nt = 0; nt < 8; ++nt) {
                v8bf bh = *(v8bf*)&Bs[s][nt * 16 + lr][q * 8];
#pragma unroll
                for (int mt = 0; mt < 2; ++mt) {
                    v4f a = acc[mt][nt];
                    a = __builtin_amdgcn_mfma_f32_16x16x32_bf16(al[mt], bh, a, 0, 0, 0);
                    a = __builtin_amdgcn_mfma_f32_16x16x32_bf16(ah[mt], bh, a, 0, 0, 0);
                    acc[mt][nt] = a;
                }
            }
            if (more) {
#pragma unroll
                for (int mt = 0; mt < 2; ++mt)
#pragma unroll
                    for (int i = 0; i < 8; ++i) cur[mt][i] = nxt[mt][i];
            }
        }
    }

    if (epi == 2 && t < 128) { sS[t] = 0.f; sQ[t] = 0.f; }
    if (pathk || epi == 2) __syncthreads();

    float bcol[8];
#pragma unroll
    for (int nt = 0; nt < 8; ++nt) bcol[nt] = bias[n0 + nt * 16 + lr];

    if (epi == 0) {
#pragma unroll
        for (int mt = 0; mt < 2; ++mt)
#pragma unroll
            for (int reg = 0; reg < 4; ++reg) {
                int rloc = wrow + mt * 16 + q * 4 + reg;
                int rm = m0 + rloc;
                if (rloc < mtile && rm < M) {
#pragma unroll
                    for (int nt = 0; nt < 8; ++nt) {
                        int cn = nt * 16 + lr;
                        float v = acc[mt][nt][reg] + bcol[nt];
                        if (relu_flag) v = fmaxf(v, 0.f);
                        if (res) {
                            float rvl = res[(size_t)rm * Ncol + n0 + cn];
                            if (bnmode == 2)
                                rvl = fmaxf(rvl * scB[cn] + shB[cn], 0.f);
                            v += rvl;
                        }
                        out[(size_t)rm * Ncol + n0 + cn] = v;
                    }
                }
            }
    } else {  // epi == 2: bf16 write + stats
#pragma unroll
        for (int nt = 0; nt < 8; ++nt) {
            int cn = nt * 16 + lr;
            float s = 0.f, q2 = 0.f;
#pragma unroll
            for (int mt = 0; mt < 2; ++mt)
#pragma unroll
                for (int reg = 0; reg < 4; ++reg) {
                    int rloc = wrow + mt * 16 + q * 4 + reg;
                    int rm = m0 + rloc;
                    if (rloc < mtile && rm < M) {
                        float v = acc[mt][nt][reg] + bcol[nt];
                        out16[(size_t)rm * Ncol + n0 + cn] = (__bf16)v;
                        s += v;
                        q2 += v * v;
                    }
                }
            atomicAdd(&sS[cn], s);
            atomicAdd(&sQ[cn], q2);
        }
        __syncthreads();
        if (t < 128) {
            atomicAdd(&stats[n0 + t], sS[t]);
            atomicAdd(&stats[Ncol + n0 + t], sQ[t]);
        }
    }
}

// ---------------- MLP pass B: x = relu(BN1(h1')) @ gw2 + gb2, + BN2 stats ----------
// A16 = h1' bf16 [M][256] (biased, pre-BN); BN1 fold applied in-register.
// B register-prefetched; 64-K chunks.

__global__ __launch_bounds__(256) void k_mgemm_bn(
    const __bf16* __restrict__ A16, const __bf16* __restrict__ Bth,
    const float* __restrict__ gb2, const float* __restrict__ statsIn,
    const float* __restrict__ gbn_g, const float* __restrict__ gbn_b,
    float* __restrict__ outx, float* __restrict__ stats2, int M)
{
    __shared__ __bf16 Bs[2][128][40];
    __shared__ float scS[256], shS[256];
    __shared__ float sS[128], sQ[128];

    int t = threadIdx.x;
    int m0 = blockIdx.x * 128;
    int lane = t & 63, q = lane >> 4, lr = lane & 15;
    int wrow = (t >> 6) * 32;

    {
        float mean = statsIn[t] * (1.f / (float)Nn);
        float var = statsIn[256 + t] * (1.f / (float)Nn) - mean * mean;
        float s = gbn_g[t] * rsqrtf(var + BN_EPS);
        scS[t] = s;
        shS[t] = gbn_b[t] - mean * s;
    }
    if (t < 128) { sS[t] = 0.f; sQ[t] = 0.f; }

    v4f acc[2][8] = {};
    int bn = t & 127;
    int ks = t >> 7;

    int rowA[2]; bool rv[2];
#pragma unroll
    for (int mt = 0; mt < 2; ++mt) {
        int gm = m0 + wrow + mt * 16 + lr;
        rv[mt] = (gm < M);
        rowA[mt] = gm;
    }

    v8bf vb[2][2];
    auto loadBreg = [&](int c) {
#pragma unroll
        for (int s2 = 0; s2 < 2; ++s2) {
            const __bf16* bp = Bth + (size_t)bn * 256 + (c << 6) + s2 * 32 + ks * 16;
            vb[s2][0] = *(const v8bf*)bp;
            vb[s2][1] = *(const v8bf*)(bp + 8);
        }
    };
    loadBreg(0);

    for (int c = 0; c < 4; ++c) {
        __syncthreads();  // also covers scS/shS on first iter
#pragma unroll
        for (int s2 = 0; s2 < 2; ++s2) {
            *(v8bf*)&Bs[s2][bn][ks * 16] = vb[s2][0];
            *(v8bf*)&Bs[s2][bn][ks * 16 + 8] = vb[s2][1];
        }
        __syncthreads();
        if (c + 1 < 4) loadBreg(c + 1);
#pragma unroll
        for (int s = 0; s < 2; ++s) {
            int kq = (c << 6) + s * 32 + q * 8;
            v8bf ah[2], al[2];
#pragma unroll
            for (int mt = 0; mt < 2; ++mt) {
                float tv[8];
                if (rv[mt]) {
                    v8bf hv = *(const v8bf*)(A16 + (size_t)rowA[mt] * 256 + kq);
#pragma unroll
                    for (int i = 0; i < 8; ++i)
                        tv[i] = fmaxf((float)hv[i] * scS[kq + i] + shS[kq + i], 0.f);
                } else {
#pragma unroll
                    for (int i = 0; i < 8; ++i) tv[i] = 0.f;
                }
#pragma unroll
                for (int i = 0; i < 8; ++i) {
                    bfpair p = split2(tv[i]);
                    ah[mt][i] = p.h;
                    al[mt][i] = p.l;
                }
            }
#pragma unroll
            for (int nt = 0; nt < 8; ++nt) {
                v8bf bh = *(v8bf*)&Bs[s][nt * 16 + lr][q * 8];
#pragma unroll
                for (int mt = 0; mt < 2; ++mt) {
                    v4f a = acc[mt][nt];
                    a = __builtin_amdgcn_mfma_f32_16x16x32_bf16(al[mt], bh, a, 0, 0, 0);
                    a = __builtin_amdgcn_mfma_f32_16x16x32_bf16(ah[mt], bh, a, 0, 0, 0);
                    acc[mt][nt] = a;
                }
            }
        }
    }

    __syncthreads();
    float bcol[8];
#pragma unroll
    for (int nt = 0; nt < 8; ++nt) bcol[nt] = gb2[nt * 16 + lr];
#pragma unroll
    for (int nt = 0; nt < 8; ++nt) {
        int cn = nt * 16 + lr;
        float s = 0.f, q2 = 0.f;
#pragma unroll
        for (int mt = 0; mt < 2; ++mt)
#pragma unroll
            for (int reg = 0; reg < 4; ++reg) {
                int rm = m0 + wrow + mt * 16 + q * 4 + reg;
                if (rm < M) {
                    float v = acc[mt][nt][reg] + bcol[nt];
                    outx[(size_t)rm * H + cn] = v;
                    s += v;
                    q2 += v * v;
                }
            }
        atomicAdd(&sS[cn], s);
        atomicAdd(&sQ[cn], q2);
    }
    __syncthreads();
    if (t < 128) {
        atomicAdd(&stats2[t], sS[t]);
        atomicAdd(&stats2[128 + t], sQ[t]);
    }
}

// ---------------- readout ----------------

__global__ void k_seg_batch(const float* __restrict__ x, const int* __restrict__ batch,
                            float* __restrict__ xgsum, float* __restrict__ gcnt) {
    int h = threadIdx.x;
    int r0 = blockIdx.x * 256;
    if (r0 >= Nn) return;
    int r1 = min(r0 + 256, Nn);
    int cur = batch[r0];
    float acc = 0.f, c = 0.f;
    for (int r = r0; r < r1; ++r) {
        int b = batch[r];
        if (b != cur) {
            atomicAdd(&xgsum[cur * H + h], acc);
            if (h == 0) atomicAdd(&gcnt[cur], c);
            acc = 0.f;
            c = 0.f;
            cur = b;
        }
        acc += x[r * H + h];
        c += 1.f;
    }
    atomicAdd(&xgsum[cur * H + h], acc);
    if (h == 0) atomicAdd(&gcnt[cur], c);
}

__global__ void k_head(const float* __restrict__ xgsum, const float* __restrict__ gcnt,
                       const float* __restrict__ alw, const float* __restrict__ alb,
                       const float* __restrict__ lw, const float* __restrict__ lb,
                       float* __restrict__ out) {
    __shared__ float mean[H];
    __shared__ float red[H];
    int g = blockIdx.x, j = threadIdx.x;
    mean[j] = xgsum[g * H + j] / fmaxf(gcnt[g], 1.f);
    __syncthreads();
    float acc = alb[j];
    for (int k = 0; k < H; ++k) acc += mean[k] * alw[k * H + j];
    acc = fmaxf(acc, 0.f) * lw[j];
    red[j] = acc;
    __syncthreads();
    for (int s = 64; s > 0; s >>= 1) {
        if (j < s) red[j] += red[j + s];
        __syncthreads();
    }
    if (j == 0) out[g] = red[0] + lb[0];
}

// ---------------- host ----------------

extern "C" void kernel_launch(void* const* d_in, const int* in_sizes, int n_in,
                              void* d_out, int out_size, void* d_ws, size_t ws_size,
                              hipStream_t stream) {
    const int* x_atom = (const int*)d_in[0];
    const int* ei = (const int*)d_in[1];
    const int* eattr = (const int*)d_in[2];
    const int* batch = (const int*)d_in[3];
    const int* xc5 = (const int*)d_in[4];
    const int* xc6 = (const int*)d_in[5];
    const int* a2c5_row = (const int*)d_in[6];
    const int* a2c6_row = (const int*)d_in[8];
    const float* atom_emb = (const float*)d_in[10];
    const float* bond_emb = (const float*)d_in[11];
    const float* cyc5 = (const float*)d_in[12];
    const float* cyc6 = (const float*)d_in[13];
    const float* eps = (const float*)d_in[14];
    const float* gw1 = (const float*)d_in[15];
    const float* gb1 = (const float*)d_in[16];
    const float* gbn_g = (const float*)d_in[17];
    const float* gbn_b = (const float*)d_in[18];
    const float* gw2 = (const float*)d_in[19];
    const float* gb2 = (const float*)d_in[20];
    const float* bn_g = (const float*)d_in[21];
    const float* bn_b = (const float*)d_in[22];
    const float* a2c5_w = (const float*)d_in[23];
    const float* a2c5_b = (const float*)d_in[24];
    const float* a2c6_w = (const float*)d_in[25];
    const float* a2c6_b = (const float*)d_in[26];
    const float* c2a5_w = (const float*)d_in[27];
    const float* c2a5_b = (const float*)d_in[28];
    const float* c2a6_w = (const float*)d_in[29];
    const float* c2a6_b = (const float*)d_in[30];
    const float* p5_w = (const float*)d_in[31];
    const float* p5_b = (const float*)d_in[32];
    const float* p6_w = (const float*)d_in[33];
    const float* p6_b = (const float*)d_in[34];
    const float* alw = (const float*)d_in[35];
    const float* alb = (const float*)d_in[36];
    const float* lw = (const float*)d_in[37];
    const float* lb = (const float*)d_in[38];
    float* out = (float*)d_out;

    float* w = (float*)d_ws;
    size_t o = 0;
    auto alloc = [&](size_t nf) {
        float* p = w + o;
        o += (nf + 63) & ~(size_t)63;
        return p;
    };
    auto allocb = [&](size_t nbf) { return (__bf16*)alloc((nbf + 1) / 2); };
    float* x = alloc((size_t)Nn * H);   // also holds h1' bf16 (Nn x 256) during MLP
    float* x5 = alloc((size_t)N5c * 5 * H);
    float* x6 = alloc((size_t)N6c * 6 * H);
    float* agg = alloc((size_t)Nn * H);
    float* stats = alloc(512);
    float* stats2 = alloc(256);
    float* xgsum = alloc((size_t)Gg * H);
    float* gcnt = alloc(Gg);
    float* rscale5 = alloc(Nn);
    float* rscale6 = alloc(Nn);
    int* deg = (int*)alloc(Nn);
    int* rowptr = (int*)alloc(Nn + 1);
    int* rp5c = (int*)alloc(Nn + 1);
    int* rp6c = (int*)alloc(Nn + 1);
    int* woff = (int*)alloc(Nn);
    int* bsum = (int*)alloc(256);
    int* boff = (int*)alloc(256);
    unsigned int* elist = (unsigned int*)alloc(Ee);
    int* cidx5 = (int*)alloc(N5c * 5);
    int* cidx6 = (int*)alloc(N6c * 6);
    float* ebank = alloc(512 * H);
    __bf16* g1h = allocb(3 * 128 * 256);
    __bf16* g2h = allocb(3 * 256 * 128);
    __bf16* a5h = allocb(3 * 128 * 128);
    __bf16* a6h = allocb(3 * 128 * 128);
    __bf16* c5h = allocb(3 * 128 * 128);
    __bf16* c6h = allocb(3 * 128 * 128);
    __bf16* p5h = allocb(3 * 384 * 128);
    __bf16* p6h = allocb(3 * 384 * 128);

    const int TPB = 256;
    auto cdiv = [](int a, int b) { return (a + b - 1) / b; };
    int nsb = cdiv(Nn, 1024);

    // weight pre-split (transposed bf16 hi planes)
    k_split<<<cdiv(3 * 128 * 256, TPB), TPB, 0, stream>>>(gw1, g1h, 3, 128, 256);
    k_split<<<cdiv(3 * 256 * 128, TPB), TPB, 0, stream>>>(gw2, g2h, 3, 256, 128);
    k_split<<<cdiv(3 * 128 * 128, TPB), TPB, 0, stream>>>(a2c5_w, a5h, 3, 128, 128);
    k_split<<<cdiv(3 * 128 * 128, TPB), TPB, 0, stream>>>(a2c6_w, a6h, 3, 128, 128);
    k_split<<<cdiv(3 * 128 * 128, TPB), TPB, 0, stream>>>(c2a5_w, c5h, 3, 128, 128);
    k_split<<<cdiv(3 * 128 * 128, TPB), TPB, 0, stream>>>(c2a6_w, c6h, 3, 128, 128);
    k_split<<<cdiv(3 * 384 * 128, TPB), TPB, 0, stream>>>(p5_w, p5h, 3, 384, 128);
    k_split<<<cdiv(3 * 384 * 128, TPB), TPB, 0, stream>>>(p6_w, p6h, 3, 384, 128);

    // edge CSR
    hipMemsetAsync(deg, 0, Nn * 4, stream);
    k_degi<<<cdiv(Ee, TPB), TPB, 0, stream>>>(ei + Ee, deg, Ee);
    k_scan1<<<nsb, 256, 0, stream>>>(deg, rowptr, bsum, Nn);
    k_scan2<<<1, 128, 0, stream>>>(bsum, boff, rowptr, nsb, Nn);
    k_scan3<<<cdiv(Nn, TPB), TPB, 0, stream>>>(rowptr, boff, Nn);
    hipMemcpyAsync(woff, rowptr, Nn * 4, hipMemcpyDeviceToDevice, stream);
    k_fill<<<cdiv(Ee, TPB), TPB, 0, stream>>>(ei, eattr, woff, elist);

    // cycle->atom CSRs + mean scales
    hipMemsetAsync(deg, 0, Nn * 4, stream);
    k_degi<<<cdiv(N5c * 5, TPB), TPB, 0, stream>>>(a2c5_row, deg, N5c * 5);
    k_scan1<<<nsb, 256, 0, stream>>>(deg, rp5c, bsum, Nn);
    k_scan2<<<1, 128, 0, stream>>>(bsum, boff, rp5c, nsb, Nn);
    k_scan3<<<cdiv(Nn, TPB), TPB, 0, stream>>>(rp5c, boff, Nn);
    k_inv_int<<<cdiv(Nn, TPB), TPB, 0, stream>>>(deg, rscale5);
    hipMemcpyAsync(woff, rp5c, Nn * 4, hipMemcpyDeviceToDevice, stream);
    k_fill_idx<<<cdiv(N5c * 5, TPB), TPB, 0, stream>>>(a2c5_row, woff, cidx5, N5c * 5);

    hipMemsetAsync(deg, 0, Nn * 4, stream);
    k_degi<<<cdiv(N6c * 6, TPB), TPB, 0, stream>>>(a2c6_row, deg, N6c * 6);
    k_scan1<<<nsb, 256, 0, stream>>>(deg, rp6c, bsum, Nn);
    k_scan2<<<1, 128, 0, stream>>>(bsum, boff, rp6c, nsb, Nn);
    k_scan3<<<cdiv(Nn, TPB), TPB, 0, stream>>>(rp6c, boff, Nn);
    k_inv_int<<<cdiv(Nn, TPB), TPB, 0, stream>>>(deg, rscale6);
    hipMemcpyAsync(woff, rp6c, Nn * 4, hipMemcpyDeviceToDevice, stream);
    k_fill_idx<<<cdiv(N6c * 6, TPB), TPB, 0, stream>>>(a2c6_row, woff, cidx6, N6c * 6);

    k_atom_enc<<<cdiv(Nn * H, TPB), TPB, 0, stream>>>(x_atom, atom_emb, x);
    k_cyc_init<<<cdiv(N5c * 5 * H, TPB), TPB, 0, stream>>>(xc5, cyc5, x5, N5c * 5);
    k_cyc_init<<<cdiv(N6c * 6 * H, TPB), TPB, 0, stream>>>(xc6, cyc6, x6, N6c * 6);

    for (int i = 0; i < Ll; ++i) {
        // GINE aggregation (gather) -> agg  (x is post-BN-materialized here)
        k_ebank<<<cdiv(512 * H, TPB), TPB, 0, stream>>>(
            bond_emb + (size_t)i * BF * BV * H, ebank);
        k_agg_csr<<<Nn / 2, 256, 0, stream>>>(x, rowptr, elist, ebank, eps, i, agg);

        // MLP pass A: h1' = agg@gw1 + gb1 -> bf16 into x (dead), + BN1 stats
        hipMemsetAsync(stats, 0, 512 * 4, stream);
        k_mgemm<<<dim3(cdiv(Nn, 128), 2), 256, 0, stream>>>(
            agg, g1h + (size_t)i * 128 * 256, gb1 + (size_t)i * 256,
            nullptr, nullptr, (__bf16*)x, nullptr, nullptr, nullptr, nullptr,
            stats, nullptr, nullptr, nullptr, Nn, 128, 256, 0, 128, 0, 2, 0);

        // MLP pass B: x_raw = relu(BN1(h1')) @ gw2 + gb2 (pre-BN2), + BN2 stats
        hipMemsetAsync(stats2, 0, 256 * 4, stream);
        k_mgemm_bn<<<cdiv(Nn, 128), 256, 0, stream>>>(
            (const __bf16*)x, g2h + (size_t)i * 256 * 128, gb2 + (size_t)i * H,
            stats, gbn_g + (size_t)i * 256, gbn_b + (size_t)i * 256,
            x, stats2, Nn);

        // atoms -> cycles (row-gather GEMM with folded BN2+relu on A, in-place res)
        k_mgemm<<<dim3(cdiv(N5c * 5, 128), 1), 256, 0, stream>>>(
            x, a5h + (size_t)i * 128 * 128, a2c5_b + (size_t)i * H,
            x5, x5, nullptr, a2c5_row, nullptr, nullptr, nullptr,
            nullptr, stats2, bn_g + (size_t)i * H, bn_b + (size_t)i * H,
            N5c * 5, 128, 128, 0, 128, 1, 0, 1);
        k_mgemm<<<dim3(cdiv(N6c * 6, 128), 1), 256, 0, stream>>>(
            x, a6h + (size_t)i * 128 * 128, a2c6_b + (size_t)i * H,
            x6, x6, nullptr, a2c6_row, nullptr, nullptr, nullptr,
            nullptr, stats2, bn_g + (size_t)i * H, bn_b + (size_t)i * H,
            N6c * 6, 128, 128, 0, 128, 1, 0, 1);

        // cyclic path blocks: cycle-aligned tiles, fully in-place
        k_mgemm<<<dim3(cdiv(N5c, 25), 1), 256, 0, stream>>>(
            x5, p5h + (size_t)i * 384 * 128, p5_b + (size_t)i * H,
            x5, x5, nullptr, nullptr, nullptr, nullptr, nullptr,
            nullptr, nullptr, nullptr, nullptr,
            N5c * 5, 384, 128, 5, 125, 1, 0, 0);
        k_mgemm<<<dim3(cdiv(N6c, 21), 1), 256, 0, stream>>>(
            x6, p6h + (size_t)i * 384 * 128, p6_b + (size_t)i * H,
            x6, x6, nullptr, nullptr, nullptr, nullptr, nullptr,
            nullptr, nullptr, nullptr, nullptr,
            N6c * 6, 384, 128, 6, 126, 1, 0, 0);

        // cycles -> atoms; c2a5 materializes x = relu(BN2(x_raw)) + relu(gemm)
        k_mgemm<<<dim3(cdiv(Nn, 128), 1), 256, 0, stream>>>(
            x5, c5h + (size_t)i * 128 * 128, c2a5_b + (size_t)i * H,
            x, x, nullptr, nullptr, rp5c, cidx5, rscale5,
            nullptr, stats2, bn_g + (size_t)i * H, bn_b + (size_t)i * H,
            Nn, 128, 128, 0, 128, 1, 0, 2);
        k_mgemm<<<dim3(cdiv(Nn, 128), 1), 256, 0, stream>>>(
            x6, c6h + (size_t)i * 128 * 128, c2a6_b + (size_t)i * H,
            x, x, nullptr, nullptr, rp6c, cidx6, rscale6,
            nullptr, nullptr, nullptr, nullptr,
            Nn, 128, 128, 0, 128, 1, 0, 0);
    }

    // readout
    hipMemsetAsync(xgsum, 0, (size_t)Gg * H * 4, stream);
    hipMemsetAsync(gcnt, 0, (size_t)Gg * 4, stream);
    k_seg_batch<<<cdiv(Nn, 256), H, 0, stream>>>(x, batch, xgsum, gcnt);
    k_head<<<Gg, H, 0, stream>>>(xgsum, gcnt, alw, alb, lw, lb, out);
}

// Round 12
// 2087.875 us; speedup vs baseline: 1.9286x; 1.2073x over previous
//
#include <hip/hip_runtime.h>

#define H 128
#define Nn 100000
#define Ee 250000
#define N5c 20000
#define N6c 30000
#define Gg 512
#define Ll 3
#define AF 9
#define AV 64
#define BF 3
#define BV 8
#define BN_EPS 1e-5f

typedef __bf16 v8bf __attribute__((ext_vector_type(8)));
typedef float v4f __attribute__((ext_vector_type(4)));

struct bfpair { __bf16 h, l; };
__device__ inline bfpair split2(float v) {
    bfpair r;
    r.h = (__bf16)v;
    r.l = (__bf16)(v - (float)r.h);
    return r;
}

// ---------------- init / embedding kernels ----------------

__global__ void k_atom_enc(const int* __restrict__ xa, const float* __restrict__ emb,
                           __bf16* __restrict__ x) {
    int idx = blockIdx.x * blockDim.x + threadIdx.x;
    if (idx >= Nn * H) return;
    int n = idx >> 7, h = idx & 127;
    float s = 0.f;
#pragma unroll
    for (int f = 0; f < AF; ++f) {
        int a = xa[n * AF + f];
        s += emb[(f * AV + a) * H + h];
    }
    x[idx] = (__bf16)s;
}

__global__ void k_cyc_init(const int* __restrict__ xc, const float* __restrict__ emb,
                           __bf16* __restrict__ xo, int M) {
    int idx = blockIdx.x * blockDim.x + threadIdx.x;
    if (idx >= M * H) return;
    int m = idx >> 7, h = idx & 127;
    xo[idx] = (__bf16)emb[xc[m] * H + h];
}

// weight pre-split: (L,K,N) fp32 row-major -> per-layer transposed [n][k] bf16 hi
__global__ void k_split(const float* __restrict__ src, __bf16* __restrict__ dh,
                        int L, int K, int N) {
    int idx = blockIdx.x * blockDim.x + threadIdx.x;
    int tot = L * K * N;
    if (idx >= tot) return;
    int l = idx / (K * N);
    int r = idx - l * (K * N);
    int k = r / N;
    int n = r - k * N;
    size_t d = (size_t)l * K * N + (size_t)n * K + k;
    dh[d] = (__bf16)src[idx];
}

// ---------------- CSR build helpers (edge + cycle maps; all static) ----------------

__global__ void k_degi(const int* __restrict__ row, int* __restrict__ deg, int M) {
    int m = blockIdx.x * blockDim.x + threadIdx.x;
    if (m >= M) return;
    atomicAdd(&deg[row[m]], 1);
}

__global__ void k_scan1(const int* __restrict__ deg, int* __restrict__ rp,
                        int* __restrict__ bsum, int n) {
    __shared__ int s[256];
    int tid = threadIdx.x;
    int base = blockIdx.x * 1024 + tid * 4;
    int v0 = (base < n) ? deg[base] : 0;
    int v1 = (base + 1 < n) ? deg[base + 1] : 0;
    int v2 = (base + 2 < n) ? deg[base + 2] : 0;
    int v3 = (base + 3 < n) ? deg[base + 3] : 0;
    int tsum = v0 + v1 + v2 + v3;
    s[tid] = tsum;
    __syncthreads();
    for (int off = 1; off < 256; off <<= 1) {
        int u = (tid >= off) ? s[tid - off] : 0;
        __syncthreads();
        s[tid] += u;
        __syncthreads();
    }
    int exc = s[tid] - tsum;
    if (base < n) rp[base] = exc;
    if (base + 1 < n) rp[base + 1] = exc + v0;
    if (base + 2 < n) rp[base + 2] = exc + v0 + v1;
    if (base + 3 < n) rp[base + 3] = exc + v0 + v1 + v2;
    if (tid == 255) bsum[blockIdx.x] = s[255];
}

__global__ void k_scan2(const int* __restrict__ bsum, int* __restrict__ boff,
                        int* __restrict__ rp, int nb, int n) {
    __shared__ int s[128];
    int tid = threadIdx.x;
    int v = (tid < nb) ? bsum[tid] : 0;
    s[tid] = v;
    __syncthreads();
    for (int off = 1; off < 128; off <<= 1) {
        int u = (tid >= off) ? s[tid - off] : 0;
        __syncthreads();
        s[tid] += u;
        __syncthreads();
    }
    if (tid < nb) boff[tid] = s[tid] - v;
    if (tid == 127) rp[n] = s[127];
}

__global__ void k_scan3(int* __restrict__ rp, const int* __restrict__ boff, int n) {
    int idx = blockIdx.x * blockDim.x + threadIdx.x;
    if (idx < n) rp[idx] += boff[idx >> 10];
}

__global__ void k_fill(const int* __restrict__ ei, const int* __restrict__ eattr,
                       int* __restrict__ woff, unsigned int* __restrict__ elist) {
    int e = blockIdx.x * blockDim.x + threadIdx.x;
    if (e >= Ee) return;
    int src = ei[e], dst = ei[Ee + e];
    int code = eattr[e * BF + 0] * 64 + eattr[e * BF + 1] * 8 + eattr[e * BF + 2];
    int p = atomicAdd(&woff[dst], 1);
    elist[p] = ((unsigned int)code << 17) | (unsigned int)src;
}

__global__ void k_fill_idx(const int* __restrict__ row, int* __restrict__ woff,
                           int* __restrict__ cidx, int M) {
    int m = blockIdx.x * blockDim.x + threadIdx.x;
    if (m >= M) return;
    int p = atomicAdd(&woff[row[m]], 1);
    cidx[p] = m;
}

__global__ void k_inv_int(const int* __restrict__ deg, float* __restrict__ rscale) {
    int r = blockIdx.x * blockDim.x + threadIdx.x;
    if (r >= Nn) return;
    rscale[r] = 1.f / fmaxf((float)deg[r], 1.f);
}

__global__ void k_ebank(const float* __restrict__ bemb, float* __restrict__ ebank) {
    int idx = blockIdx.x * blockDim.x + threadIdx.x;
    if (idx >= 512 * H) return;
    int code = idx >> 7, h = idx & 127;
    int f0 = code >> 6, f1 = (code >> 3) & 7, f2 = code & 7;
    ebank[idx] = bemb[(0 * BV + f0) * H + h] + bemb[(1 * BV + f1) * H + h]
               + bemb[(2 * BV + f2) * H + h];
}

// GINE aggregation, gather form (bf16 activations, fp32 accumulate)
__global__ __launch_bounds__(256) void k_agg_csr(
    const __bf16* __restrict__ x, const int* __restrict__ rowptr,
    const unsigned int* __restrict__ elist, const float* __restrict__ ebank,
    const float* __restrict__ eps, int layer, __bf16* __restrict__ agg)
{
    int a = blockIdx.x * 2 + (threadIdx.x >> 7);
    int h = threadIdx.x & 127;
    float acc = (1.f + eps[layer]) * (float)x[(size_t)a * H + h];
    int j0 = rowptr[a], j1 = rowptr[a + 1];
    for (int j = j0; j < j1; ++j) {
        unsigned int u = elist[j];
        int src = u & 0x1FFFF;
        int code = u >> 17;
        acc += fmaxf((float)x[(size_t)src * H + h] + ebank[code * H + h], 0.f);
    }
    agg[(size_t)a * H + h] = (__bf16)acc;
}

// ---------------- MFMA GEMM: bf16 activations, direct-register A + B ----------------
// Single MFMA per 32-K tile (A bf16, B bf16-hi). A and B register-prefetched.
// A-modes: pathk (cyclic conv, cycle-aligned mtile, in-place safe); grp/gcol/gscale
// (CSR mean-gather, fp32 accum); rowidx; else direct (stride K bf16).
// epi: 0 = bf16 out (+bf16 res/relu); 2 = bf16 out write + column stats.
// bnmode: 1 = folded BN+relu on A-loads (K==128); 2 = folded BN+relu on res read.

__global__ __launch_bounds__(256) void k_mgemm(
    const __bf16* __restrict__ A, const __bf16* __restrict__ Bth,
    const float* __restrict__ bias, const __bf16* __restrict__ res,
    __bf16* __restrict__ out,
    const int* __restrict__ rowidx, const int* __restrict__ grp,
    const int* __restrict__ gcol, const float* __restrict__ gscale,
    float* __restrict__ stats,
    const float* __restrict__ bnstats, const float* __restrict__ bng,
    const float* __restrict__ bnb,
    int M, int K, int Ncol, int pathk, int mtile, int relu_flag, int epi, int bnmode)
{
    __shared__ __bf16 Bs[2][128][40];
    __shared__ float sS[128], sQ[128];
    __shared__ float scB[128], shB[128];

    int t = threadIdx.x;
    int m0 = blockIdx.x * mtile;
    int n0 = blockIdx.y * 128;
    int lane = t & 63, q = lane >> 4, lr = lane & 15;
    int wrow = (t >> 6) * 32;

    if (bnmode) {
        if (t < 128) {
            float mean = bnstats[t] * (1.f / (float)Nn);
            float var = bnstats[128 + t] * (1.f / (float)Nn) - mean * mean;
            float s = bng[t] * rsqrtf(var + BN_EPS);
            scB[t] = s;
            shB[t] = bnb[t] - mean * s;
        }
        if (bnmode == 1) __syncthreads();  // A-loads below need scB
    }

    v4f acc[2][8] = {};

    int bn = t & 127;
    int ks = t >> 7;  // 0/1

    bool rv[2];
    const __bf16* baseA[2];
    int gj0[2] = {0, 0}, gj1[2] = {0, 0};
    float gsc[2] = {1.f, 1.f};
    int cycb[2] = {0, 0}, pm[2] = {0, 0};
#pragma unroll
    for (int mt = 0; mt < 2; ++mt) {
        int rloc = wrow + mt * 16 + lr;
        int gm = m0 + rloc;
        rv[mt] = (rloc < mtile) && (gm < M);
        baseA[mt] = A;
        if (rv[mt]) {
            if (grp) {
                gj0[mt] = grp[gm];
                gj1[mt] = grp[gm + 1];
                gsc[mt] = gscale[gm];
            } else if (pathk) {
                int cyc = gm / pathk;
                cycb[mt] = cyc * pathk;
                pm[mt] = gm - cycb[mt];
            } else if (rowidx) {
                baseA[mt] = A + (size_t)rowidx[gm] * H;
            } else {
                baseA[mt] = A + (size_t)gm * K;
            }
        }
    }

    auto loadA = [&](int c, int s, v8bf* dst) {
        int kq = (c << 6) + s * 32 + q * 8;
#pragma unroll
        for (int mt = 0; mt < 2; ++mt) {
            v8bf hv = {};
            if (rv[mt]) {
                if (grp) {
                    float a8[8] = {0.f, 0.f, 0.f, 0.f, 0.f, 0.f, 0.f, 0.f};
                    for (int j = gj0[mt]; j < gj1[mt]; ++j) {
                        v8bf g = *(const v8bf*)(A + (size_t)gcol[j] * H + kq);
#pragma unroll
                        for (int i = 0; i < 8; ++i) a8[i] += (float)g[i];
                    }
#pragma unroll
                    for (int i = 0; i < 8; ++i) hv[i] = (__bf16)(a8[i] * gsc[mt]);
                } else if (pathk) {
                    int pp = pm[mt] + (kq >> 7) - 1;
                    if (pp < 0) pp += pathk;
                    if (pp >= pathk) pp -= pathk;
                    hv = *(const v8bf*)(A + (size_t)(cycb[mt] + pp) * H + (kq & 127));
                } else {
                    hv = *(const v8bf*)(baseA[mt] + kq);
                }
                if (bnmode == 1) {
#pragma unroll
                    for (int i = 0; i < 8; ++i)
                        hv[i] = (__bf16)fmaxf((float)hv[i] * scB[kq + i] + shB[kq + i], 0.f);
                }
            }
            dst[mt] = hv;
        }
    };

    v8bf vb[2][2];
    auto loadBreg = [&](int c) {
#pragma unroll
        for (int s2 = 0; s2 < 2; ++s2) {
            const __bf16* bp = Bth + (size_t)(n0 + bn) * K + (c << 6) + s2 * 32 + ks * 16;
            vb[s2][0] = *(const v8bf*)bp;
            vb[s2][1] = *(const v8bf*)(bp + 8);
        }
    };

    v8bf cur[2], nxt[2];
    loadBreg(0);
    loadA(0, 0, cur);
    int nchunk = K >> 6;
    for (int c = 0; c < nchunk; ++c) {
        __syncthreads();
#pragma unroll
        for (int s2 = 0; s2 < 2; ++s2) {
            *(v8bf*)&Bs[s2][bn][ks * 16] = vb[s2][0];
            *(v8bf*)&Bs[s2][bn][ks * 16 + 8] = vb[s2][1];
        }
        __syncthreads();
        if (c + 1 < nchunk) loadBreg(c + 1);
#pragma unroll
        for (int s = 0; s < 2; ++s) {
            bool more = (s < 1) || (c + 1 < nchunk);
            if (s < 1) loadA(c, 1, nxt);
            else if (c + 1 < nchunk) loadA(c + 1, 0, nxt);
#pragma unroll
            for (int nt = 0; nt < 8; ++nt) {
                v8bf bh = *(v8bf*)&Bs[s][nt * 16 + lr][q * 8];
#pragma unroll
                for (int mt = 0; mt < 2; ++mt)
                    acc[mt][nt] = __builtin_amdgcn_mfma_f32_16x16x32_bf16(
                        cur[mt], bh, acc[mt][nt], 0, 0, 0);
            }
            if (more) {
                cur[0] = nxt[0];
                cur[1] = nxt[1];
            }
        }
    }

    if (epi == 2 && t < 128) { sS[t] = 0.f; sQ[t] = 0.f; }
    if (pathk || epi == 2) __syncthreads();

    float bcol[8];
#pragma unroll
    for (int nt = 0; nt < 8; ++nt) bcol[nt] = bias[n0 + nt * 16 + lr];

    if (epi == 0) {
#pragma unroll
        for (int mt = 0; mt < 2; ++mt)
#pragma unroll
            for (int reg = 0; reg < 4; ++reg) {
                int rloc = wrow + mt * 16 + q * 4 + reg;
                int rm = m0 + rloc;
                if (rloc < mtile && rm < M) {
#pragma unroll
                    for (int nt = 0; nt < 8; ++nt) {
                        int cn = nt * 16 + lr;
                        float v = acc[mt][nt][reg] + bcol[nt];
                        if (relu_flag) v = fmaxf(v, 0.f);
                        if (res) {
                            float rvl = (float)res[(size_t)rm * Ncol + n0 + cn];
                            if (bnmode == 2)
                                rvl = fmaxf(rvl * scB[cn] + shB[cn], 0.f);
                            v += rvl;
                        }
                        out[(size_t)rm * Ncol + n0 + cn] = (__bf16)v;
                    }
                }
            }
    } else {  // epi == 2: bf16 write + stats
#pragma unroll
        for (int nt = 0; nt < 8; ++nt) {
            int cn = nt * 16 + lr;
            float s = 0.f, q2 = 0.f;
#pragma unroll
            for (int mt = 0; mt < 2; ++mt)
#pragma unroll
                for (int reg = 0; reg < 4; ++reg) {
                    int rloc = wrow + mt * 16 + q * 4 + reg;
                    int rm = m0 + rloc;
                    if (rloc < mtile && rm < M) {
                        float v = acc[mt][nt][reg] + bcol[nt];
                        out[(size_t)rm * Ncol + n0 + cn] = (__bf16)v;
                        s += v;
                        q2 += v * v;
                    }
                }
            atomicAdd(&sS[cn], s);
            atomicAdd(&sQ[cn], q2);
        }
        __syncthreads();
        if (t < 128) {
            atomicAdd(&stats[n0 + t], sS[t]);
            atomicAdd(&stats[Ncol + n0 + t], sQ[t]);
        }
    }
}

// ---------------- MLP pass B: x = relu(BN1(h1')) @ gw2 + gb2, + BN2 stats ----------
// A16 = h1' bf16 [M][256]; BN1 fold in-register; T kept hi/lo (2 MFMAs, no extra
// loads). Writes bf16 x_raw (pre-BN2) + BN2 stats.

__global__ __launch_bounds__(256) void k_mgemm_bn(
    const __bf16* __restrict__ A16, const __bf16* __restrict__ Bth,
    const float* __restrict__ gb2, const float* __restrict__ statsIn,
    const float* __restrict__ gbn_g, const float* __restrict__ gbn_b,
    __bf16* __restrict__ outx, float* __restrict__ stats2, int M)
{
    __shared__ __bf16 Bs[2][128][40];
    __shared__ float scS[256], shS[256];
    __shared__ float sS[128], sQ[128];

    int t = threadIdx.x;
    int m0 = blockIdx.x * 128;
    int lane = t & 63, q = lane >> 4, lr = lane & 15;
    int wrow = (t >> 6) * 32;

    {
        float mean = statsIn[t] * (1.f / (float)Nn);
        float var = statsIn[256 + t] * (1.f / (float)Nn) - mean * mean;
        float s = gbn_g[t] * rsqrtf(var + BN_EPS);
        scS[t] = s;
        shS[t] = gbn_b[t] - mean * s;
    }
    if (t < 128) { sS[t] = 0.f; sQ[t] = 0.f; }

    v4f acc[2][8] = {};
    int bn = t & 127;
    int ks = t >> 7;

    int rowA[2]; bool rv[2];
#pragma unroll
    for (int mt = 0; mt < 2; ++mt) {
        int gm = m0 + wrow + mt * 16 + lr;
        rv[mt] = (gm < M);
        rowA[mt] = gm;
    }

    v8bf vb[2][2];
    auto loadBreg = [&](int c) {
#pragma unroll
        for (int s2 = 0; s2 < 2; ++s2) {
            const __bf16* bp = Bth + (size_t)bn * 256 + (c << 6) + s2 * 32 + ks * 16;
            vb[s2][0] = *(const v8bf*)bp;
            vb[s2][1] = *(const v8bf*)(bp + 8);
        }
    };
    loadBreg(0);

    for (int c = 0; c < 4; ++c) {
        __syncthreads();  // also covers scS/shS on first iter
#pragma unroll
        for (int s2 = 0; s2 < 2; ++s2) {
            *(v8bf*)&Bs[s2][bn][ks * 16] = vb[s2][0];
            *(v8bf*)&Bs[s2][bn][ks * 16 + 8] = vb[s2][1];
        }
        __syncthreads();
        if (c + 1 < 4) loadBreg(c + 1);
#pragma unroll
        for (int s = 0; s < 2; ++s) {
            int kq = (c << 6) + s * 32 + q * 8;
            v8bf ah[2], al[2];
#pragma unroll
            for (int mt = 0; mt < 2; ++mt) {
                float tv[8];
                if (rv[mt]) {
                    v8bf hv = *(const v8bf*)(A16 + (size_t)rowA[mt] * 256 + kq);
#pragma unroll
                    for (int i = 0; i < 8; ++i)
                        tv[i] = fmaxf((float)hv[i] * scS[kq + i] + shS[kq + i], 0.f);
                } else {
#pragma unroll
                    for (int i = 0; i < 8; ++i) tv[i] = 0.f;
                }
#pragma unroll
                for (int i = 0; i < 8; ++i) {
                    bfpair p = split2(tv[i]);
                    ah[mt][i] = p.h;
                    al[mt][i] = p.l;
                }
            }
#pragma unroll
            for (int nt = 0; nt < 8; ++nt) {
                v8bf bh = *(v8bf*)&Bs[s][nt * 16 + lr][q * 8];
#pragma unroll
                for (int mt = 0; mt < 2; ++mt) {
                    v4f a = acc[mt][nt];
                    a = __builtin_amdgcn_mfma_f32_16x16x32_bf16(al[mt], bh, a, 0, 0, 0);
                    a = __builtin_amdgcn_mfma_f32_16x16x32_bf16(ah[mt], bh, a, 0, 0, 0);
                    acc[mt][nt] = a;
                }
            }
        }
    }

    __syncthreads();
    float bcol[8];
#pragma unroll
    for (int nt = 0; nt < 8; ++nt) bcol[nt] = gb2[nt * 16 + lr];
#pragma unroll
    for (int nt = 0; nt < 8; ++nt) {
        int cn = nt * 16 + lr;
        float s = 0.f, q2 = 0.f;
#pragma unroll
        for (int mt = 0; mt < 2; ++mt)
#pragma unroll
            for (int reg = 0; reg < 4; ++reg) {
                int rm = m0 + wrow + mt * 16 + q * 4 + reg;
                if (rm < M) {
                    float v = acc[mt][nt][reg] + bcol[nt];
                    outx[(size_t)rm * H + cn] = (__bf16)v;
                    s += v;
                    q2 += v * v;
                }
            }
        atomicAdd(&sS[cn], s);
        atomicAdd(&sQ[cn], q2);
    }
    __syncthreads();
    if (t < 128) {
        atomicAdd(&stats2[t], sS[t]);
        atomicAdd(&stats2[128 + t], sQ[t]);
    }
}

// ---------------- readout ----------------

__global__ void k_seg_batch(const __bf16* __restrict__ x, const int* __restrict__ batch,
                            float* __restrict__ xgsum, float* __restrict__ gcnt) {
    int h = threadIdx.x;
    int r0 = blockIdx.x * 256;
    if (r0 >= Nn) return;
    int r1 = min(r0 + 256, Nn);
    int cur = batch[r0];
    float acc = 0.f, c = 0.f;
    for (int r = r0; r < r1; ++r) {
        int b = batch[r];
        if (b != cur) {
            atomicAdd(&xgsum[cur * H + h], acc);
            if (h == 0) atomicAdd(&gcnt[cur], c);
            acc = 0.f;
            c = 0.f;
            cur = b;
        }
        acc += (float)x[(size_t)r * H + h];
        c += 1.f;
    }
    atomicAdd(&xgsum[cur * H + h], acc);
    if (h == 0) atomicAdd(&gcnt[cur], c);
}

__global__ void k_head(const float* __restrict__ xgsum, const float* __restrict__ gcnt,
                       const float* __restrict__ alw, const float* __restrict__ alb,
                       const float* __restrict__ lw, const float* __restrict__ lb,
                       float* __restrict__ out) {
    __shared__ float mean[H];
    __shared__ float red[H];
    int g = blockIdx.x, j = threadIdx.x;
    mean[j] = xgsum[g * H + j] / fmaxf(gcnt[g], 1.f);
    __syncthreads();
    float acc = alb[j];
    for (int k = 0; k < H; ++k) acc += mean[k] * alw[k * H + j];
    acc = fmaxf(acc, 0.f) * lw[j];
    red[j] = acc;
    __syncthreads();
    for (int s = 64; s > 0; s >>= 1) {
        if (j < s) red[j] += red[j + s];
        __syncthreads();
    }
    if (j == 0) out[g] = red[0] + lb[0];
}

// ---------------- host ----------------

extern "C" void kernel_launch(void* const* d_in, const int* in_sizes, int n_in,
                              void* d_out, int out_size, void* d_ws, size_t ws_size,
                              hipStream_t stream) {
    const int* x_atom = (const int*)d_in[0];
    const int* ei = (const int*)d_in[1];
    const int* eattr = (const int*)d_in[2];
    const int* batch = (const int*)d_in[3];
    const int* xc5 = (const int*)d_in[4];
    const int* xc6 = (const int*)d_in[5];
    const int* a2c5_row = (const int*)d_in[6];
    const int* a2c6_row = (const int*)d_in[8];
    const float* atom_emb = (const float*)d_in[10];
    const float* bond_emb = (const float*)d_in[11];
    const float* cyc5 = (const float*)d_in[12];
    const float* cyc6 = (const float*)d_in[13];
    const float* eps = (const float*)d_in[14];
    const float* gw1 = (const float*)d_in[15];
    const float* gb1 = (const float*)d_in[16];
    const float* gbn_g = (const float*)d_in[17];
    const float* gbn_b = (const float*)d_in[18];
    const float* gw2 = (const float*)d_in[19];
    const float* gb2 = (const float*)d_in[20];
    const float* bn_g = (const float*)d_in[21];
    const float* bn_b = (const float*)d_in[22];
    const float* a2c5_w = (const float*)d_in[23];
    const float* a2c5_b = (const float*)d_in[24];
    const float* a2c6_w = (const float*)d_in[25];
    const float* a2c6_b = (const float*)d_in[26];
    const float* c2a5_w = (const float*)d_in[27];
    const float* c2a5_b = (const float*)d_in[28];
    const float* c2a6_w = (const float*)d_in[29];
    const float* c2a6_b = (const float*)d_in[30];
    const float* p5_w = (const float*)d_in[31];
    const float* p5_b = (const float*)d_in[32];
    const float* p6_w = (const float*)d_in[33];
    const float* p6_b = (const float*)d_in[34];
    const float* alw = (const float*)d_in[35];
    const float* alb = (const float*)d_in[36];
    const float* lw = (const float*)d_in[37];
    const float* lb = (const float*)d_in[38];
    float* out = (float*)d_out;

    float* w = (float*)d_ws;
    size_t o = 0;
    auto alloc = [&](size_t nf) {
        float* p = w + o;
        o += (nf + 63) & ~(size_t)63;
        return p;
    };
    auto allocb = [&](size_t nbf) { return (__bf16*)alloc((nbf + 1) / 2); };
    __bf16* x = allocb((size_t)Nn * H);
    __bf16* x5 = allocb((size_t)N5c * 5 * H);
    __bf16* x6 = allocb((size_t)N6c * 6 * H);
    __bf16* agg = allocb((size_t)Nn * H);
    __bf16* h1b = allocb((size_t)Nn * 256);
    float* stats = alloc(512);
    float* stats2 = alloc(256);
    float* xgsum = alloc((size_t)Gg * H);
    float* gcnt = alloc(Gg);
    float* rscale5 = alloc(Nn);
    float* rscale6 = alloc(Nn);
    int* deg = (int*)alloc(Nn);
    int* rowptr = (int*)alloc(Nn + 1);
    int* rp5c = (int*)alloc(Nn + 1);
    int* rp6c = (int*)alloc(Nn + 1);
    int* woff = (int*)alloc(Nn);
    int* bsum = (int*)alloc(256);
    int* boff = (int*)alloc(256);
    unsigned int* elist = (unsigned int*)alloc(Ee);
    int* cidx5 = (int*)alloc(N5c * 5);
    int* cidx6 = (int*)alloc(N6c * 6);
    float* ebank = alloc(512 * H);
    __bf16* g1h = allocb(3 * 128 * 256);
    __bf16* g2h = allocb(3 * 256 * 128);
    __bf16* a5h = allocb(3 * 128 * 128);
    __bf16* a6h = allocb(3 * 128 * 128);
    __bf16* c5h = allocb(3 * 128 * 128);
    __bf16* c6h = allocb(3 * 128 * 128);
    __bf16* p5h = allocb(3 * 384 * 128);
    __bf16* p6h = allocb(3 * 384 * 128);

    const int TPB = 256;
    auto cdiv = [](int a, int b) { return (a + b - 1) / b; };
    int nsb = cdiv(Nn, 1024);

    // weight pre-split (transposed bf16 hi planes)
    k_split<<<cdiv(3 * 128 * 256, TPB), TPB, 0, stream>>>(gw1, g1h, 3, 128, 256);
    k_split<<<cdiv(3 * 256 * 128, TPB), TPB, 0, stream>>>(gw2, g2h, 3, 256, 128);
    k_split<<<cdiv(3 * 128 * 128, TPB), TPB, 0, stream>>>(a2c5_w, a5h, 3, 128, 128);
    k_split<<<cdiv(3 * 128 * 128, TPB), TPB, 0, stream>>>(a2c6_w, a6h, 3, 128, 128);
    k_split<<<cdiv(3 * 128 * 128, TPB), TPB, 0, stream>>>(c2a5_w, c5h, 3, 128, 128);
    k_split<<<cdiv(3 * 128 * 128, TPB), TPB, 0, stream>>>(c2a6_w, c6h, 3, 128, 128);
    k_split<<<cdiv(3 * 384 * 128, TPB), TPB, 0, stream>>>(p5_w, p5h, 3, 384, 128);
    k_split<<<cdiv(3 * 384 * 128, TPB), TPB, 0, stream>>>(p6_w, p6h, 3, 384, 128);

    // edge CSR
    hipMemsetAsync(deg, 0, Nn * 4, stream);
    k_degi<<<cdiv(Ee, TPB), TPB, 0, stream>>>(ei + Ee, deg, Ee);
    k_scan1<<<nsb, 256, 0, stream>>>(deg, rowptr, bsum, Nn);
    k_scan2<<<1, 128, 0, stream>>>(bsum, boff, rowptr, nsb, Nn);
    k_scan3<<<cdiv(Nn, TPB), TPB, 0, stream>>>(rowptr, boff, Nn);
    hipMemcpyAsync(woff, rowptr, Nn * 4, hipMemcpyDeviceToDevice, stream);
    k_fill<<<cdiv(Ee, TPB), TPB, 0, stream>>>(ei, eattr, woff, elist);

    // cycle->atom CSRs + mean scales
    hipMemsetAsync(deg, 0, Nn * 4, stream);
    k_degi<<<cdiv(N5c * 5, TPB), TPB, 0, stream>>>(a2c5_row, deg, N5c * 5);
    k_scan1<<<nsb, 256, 0, stream>>>(deg, rp5c, bsum, Nn);
    k_scan2<<<1, 128, 0, stream>>>(bsum, boff, rp5c, nsb, Nn);
    k_scan3<<<cdiv(Nn, TPB), TPB, 0, stream>>>(rp5c, boff, Nn);
    k_inv_int<<<cdiv(Nn, TPB), TPB, 0, stream>>>(deg, rscale5);
    hipMemcpyAsync(woff, rp5c, Nn * 4, hipMemcpyDeviceToDevice, stream);
    k_fill_idx<<<cdiv(N5c * 5, TPB), TPB, 0, stream>>>(a2c5_row, woff, cidx5, N5c * 5);

    hipMemsetAsync(deg, 0, Nn * 4, stream);
    k_degi<<<cdiv(N6c * 6, TPB), TPB, 0, stream>>>(a2c6_row, deg, N6c * 6);
    k_scan1<<<nsb, 256, 0, stream>>>(deg, rp6c, bsum, Nn);
    k_scan2<<<1, 128, 0, stream>>>(bsum, boff, rp6c, nsb, Nn);
    k_scan3<<<cdiv(Nn, TPB), TPB, 0, stream>>>(rp6c, boff, Nn);
    k_inv_int<<<cdiv(Nn, TPB), TPB, 0, stream>>>(deg, rscale6);
    hipMemcpyAsync(woff, rp6c, Nn * 4, hipMemcpyDeviceToDevice, stream);
    k_fill_idx<<<cdiv(N6c * 6, TPB), TPB, 0, stream>>>(a2c6_row, woff, cidx6, N6c * 6);

    k_atom_enc<<<cdiv(Nn * H, TPB), TPB, 0, stream>>>(x_atom, atom_emb, x);
    k_cyc_init<<<cdiv(N5c * 5 * H, TPB), TPB, 0, stream>>>(xc5, cyc5, x5, N5c * 5);
    k_cyc_init<<<cdiv(N6c * 6 * H, TPB), TPB, 0, stream>>>(xc6, cyc6, x6, N6c * 6);

    for (int i = 0; i < Ll; ++i) {
        // GINE aggregation (gather) -> agg
        k_ebank<<<cdiv(512 * H, TPB), TPB, 0, stream>>>(
            bond_emb + (size_t)i * BF * BV * H, ebank);
        k_agg_csr<<<Nn / 2, 256, 0, stream>>>(x, rowptr, elist, ebank, eps, i, agg);

        // MLP pass A: h1' = agg@gw1 + gb1 -> bf16 h1b, + BN1 stats
        hipMemsetAsync(stats, 0, 512 * 4, stream);
        k_mgemm<<<dim3(cdiv(Nn, 128), 2), 256, 0, stream>>>(
            agg, g1h + (size_t)i * 128 * 256, gb1 + (size_t)i * 256,
            nullptr, h1b, nullptr, nullptr, nullptr, nullptr,
            stats, nullptr, nullptr, nullptr, Nn, 128, 256, 0, 128, 0, 2, 0);

        // MLP pass B: x_raw = relu(BN1(h1')) @ gw2 + gb2 (pre-BN2), + BN2 stats
        hipMemsetAsync(stats2, 0, 256 * 4, stream);
        k_mgemm_bn<<<cdiv(Nn, 128), 256, 0, stream>>>(
            h1b, g2h + (size_t)i * 256 * 128, gb2 + (size_t)i * H,
            stats, gbn_g + (size_t)i * 256, gbn_b + (size_t)i * 256,
            x, stats2, Nn);

        // atoms -> cycles (row-gather GEMM with folded BN2+relu on A, in-place res)
        k_mgemm<<<dim3(cdiv(N5c * 5, 128), 1), 256, 0, stream>>>(
            x, a5h + (size_t)i * 128 * 128, a2c5_b + (size_t)i * H,
            x5, x5, a2c5_row, nullptr, nullptr, nullptr,
            nullptr, stats2, bn_g + (size_t)i * H, bn_b + (size_t)i * H,
            N5c * 5, 128, 128, 0, 128, 1, 0, 1);
        k_mgemm<<<dim3(cdiv(N6c * 6, 128), 1), 256, 0, stream>>>(
            x, a6h + (size_t)i * 128 * 128, a2c6_b + (size_t)i * H,
            x6, x6, a2c6_row, nullptr, nullptr, nullptr,
            nullptr, stats2, bn_g + (size_t)i * H, bn_b + (size_t)i * H,
            N6c * 6, 128, 128, 0, 128, 1, 0, 1);

        // cyclic path blocks: cycle-aligned tiles, fully in-place
        k_mgemm<<<dim3(cdiv(N5c, 25), 1), 256, 0, stream>>>(
            x5, p5h + (size_t)i * 384 * 128, p5_b + (size_t)i * H,
            x5, x5, nullptr, nullptr, nullptr, nullptr,
            nullptr, nullptr, nullptr, nullptr,
            N5c * 5, 384, 128, 5, 125, 1, 0, 0);
        k_mgemm<<<dim3(cdiv(N6c, 21), 1), 256, 0, stream>>>(
            x6, p6h + (size_t)i * 384 * 128, p6_b + (size_t)i * H,
            x6, x6, nullptr, nullptr, nullptr, nullptr,
            nullptr, nullptr, nullptr, nullptr,
            N6c * 6, 384, 128, 6, 126, 1, 0, 0);

        // cycles -> atoms; c2a5 materializes x = relu(BN2(x_raw)) + relu(gemm)
        k_mgemm<<<dim3(cdiv(Nn, 128), 1), 256, 0, stream>>>(
            x5, c5h + (size_t)i * 128 * 128, c2a5_b + (size_t)i * H,
            x, x, nullptr, rp5c, cidx5, rscale5,
            nullptr, stats2, bn_g + (size_t)i * H, bn_b + (size_t)i * H,
            Nn, 128, 128, 0, 128, 1, 0, 2);
        k_mgemm<<<dim3(cdiv(Nn, 128), 1), 256, 0, stream>>>(
            x6, c6h + (size_t)i * 128 * 128, c2a6_b + (size_t)i * H,
            x, x, nullptr, rp6c, cidx6, rscale6,
            nullptr, nullptr, nullptr, nullptr,
            Nn, 128, 128, 0, 128, 1, 0, 0);
    }

    // readout
    hipMemsetAsync(xgsum, 0, (size_t)Gg * H * 4, stream);
    hipMemsetAsync(gcnt, 0, (size_t)Gg * 4, stream);
    k_seg_batch<<<cdiv(Nn, 256), H, 0, stream>>>(x, batch, xgsum, gcnt);
    k_head<<<Gg, H, 0, stream>>>(xgsum, gcnt, alw, alb, lw, lb, out);
}